// Round 2
// baseline (6369.470 us; speedup 1.0000x reference)
//
#include <hip/hip_runtime.h>
#include <hip/hip_bf16.h>
#include <math.h>

// ---------------- degree: deg[col[e]] += ew[e] ----------------
__global__ __launch_bounds__(256) void deg_kernel(
    const int* __restrict__ ei, const float* __restrict__ ea,
    float* __restrict__ deg, int E)
{
    int e = blockIdx.x * 256 + threadIdx.x;
    if (e >= E) return;
    int c = ei[(size_t)E + e];
    atomicAdd(&deg[c], ea[e]);
}

// ---------------- norm[e] = dinv[row]*ew*dinv[col] ----------------
__global__ __launch_bounds__(256) void norm_kernel(
    const int* __restrict__ ei, const float* __restrict__ ea,
    const float* __restrict__ deg, float* __restrict__ nrm, int E)
{
    int e = blockIdx.x * 256 + threadIdx.x;
    if (e >= E) return;
    int r = ei[e];
    int c = ei[(size_t)E + e];
    float dr = deg[r], dc = deg[c];
    float ir = dr > 0.f ? rsqrtf(dr) : 0.f;
    float ic = dc > 0.f ? rsqrtf(dc) : 0.f;
    nrm[e] = ir * ea[e] * ic;
}

// ---------------- dual GEMM: outP = A@Wi ; outR = A@Wr + bias ----------------
// A: M x K (row-major), Wi/Wr: K x 128, out: M x 128
// Block: 256 thr, tile 32 rows x 128 cols, KT=32.
// NOTE: safe for outR == A (each block reads only its own 32 rows; all reads
// happen in the k0 loop before the epilogue writes).
__global__ __launch_bounds__(256) void gemm_dual(
    const float* __restrict__ A, const float* __restrict__ Wi,
    const float* __restrict__ Wr, const float* __restrict__ bias,
    float* __restrict__ outP, float* __restrict__ outR, int M, int K)
{
    __shared__ float As[32 * 36];      // transposed: As[k][r], pitch 36
    __shared__ float Wis[32 * 128];
    __shared__ float Wrs[32 * 128];

    const int t = threadIdx.x;
    const int m0 = blockIdx.x * 32;
    const int c0 = (t & 31) * 4;       // 4 consecutive cols
    const int r0 = (t >> 5) * 4;       // 4 consecutive rows
    const int lr = t >> 3;             // A-load row 0..31
    const int lc = (t & 7) * 4;        // A-load col (within tile)

    float acc_i[4][4] = {{0.f}};
    float acc_r[4][4] = {{0.f}};

    for (int k0 = 0; k0 < K; k0 += 32) {
        if (m0 + lr < M) {
            const float4 v = *(const float4*)&A[(size_t)(m0 + lr) * K + k0 + lc];
            As[(lc + 0) * 36 + lr] = v.x;
            As[(lc + 1) * 36 + lr] = v.y;
            As[(lc + 2) * 36 + lr] = v.z;
            As[(lc + 3) * 36 + lr] = v.w;
        }
        {
            const float4* srcI = (const float4*)(Wi + (size_t)k0 * 128);
            const float4* srcR = (const float4*)(Wr + (size_t)k0 * 128);
            float4* dI = (float4*)Wis;
            float4* dR = (float4*)Wrs;
#pragma unroll
            for (int i = 0; i < 4; ++i) {
                dI[t + i * 256] = srcI[t + i * 256];
                dR[t + i * 256] = srcR[t + i * 256];
            }
        }
        __syncthreads();
#pragma unroll
        for (int k = 0; k < 32; ++k) {
            const float4 av = *(const float4*)&As[k * 36 + r0];
            const float4 wi = *(const float4*)&Wis[k * 128 + c0];
            const float4 wr = *(const float4*)&Wrs[k * 128 + c0];
            const float a[4] = {av.x, av.y, av.z, av.w};
            const float bi[4] = {wi.x, wi.y, wi.z, wi.w};
            const float br[4] = {wr.x, wr.y, wr.z, wr.w};
#pragma unroll
            for (int i = 0; i < 4; ++i)
#pragma unroll
                for (int j = 0; j < 4; ++j) {
                    acc_i[i][j] = fmaf(a[i], bi[j], acc_i[i][j]);
                    acc_r[i][j] = fmaf(a[i], br[j], acc_r[i][j]);
                }
        }
        __syncthreads();
    }

    float b[4];
#pragma unroll
    for (int j = 0; j < 4; ++j) b[j] = bias[c0 + j];
#pragma unroll
    for (int i = 0; i < 4; ++i) {
        int m = m0 + r0 + i;
        if (m < M) {
            float4 vp, vr;
            vp.x = acc_i[i][0]; vp.y = acc_i[i][1]; vp.z = acc_i[i][2]; vp.w = acc_i[i][3];
            vr.x = acc_r[i][0] + b[0]; vr.y = acc_r[i][1] + b[1];
            vr.z = acc_r[i][2] + b[2]; vr.w = acc_r[i][3] + b[3];
            *(float4*)&outP[(size_t)m * 128 + c0] = vp;
            *(float4*)&outR[(size_t)m * 128 + c0] = vr;
        }
    }
}

// ---------------- scatter aggregation: dst[col] += src[row]*norm ----------------
// dst already holds (A@Wr + b); 32 lanes per edge, float4 each.
__global__ __launch_bounds__(256) void agg_scatter(
    const float* __restrict__ src, const int* __restrict__ ei,
    const float* __restrict__ nrm, float* __restrict__ dst, int E)
{
    int tid = blockIdx.x * 256 + threadIdx.x;
    int e = tid >> 5;
    if (e >= E) return;
    int c = (tid & 31) << 2;
    int r = ei[e];
    int d = ei[(size_t)E + e];
    float nm = nrm[e];
    const float4 v = *(const float4*)&src[(size_t)r * 128 + c];
    float* dp = &dst[(size_t)d * 128 + c];
    atomicAdd(dp + 0, v.x * nm);
    atomicAdd(dp + 1, v.y * nm);
    atomicAdd(dp + 2, v.z * nm);
    atomicAdd(dp + 3, v.w * nm);
}

// ---------------- elementwise in-place relu ----------------
__global__ __launch_bounds__(256) void relu_inplace(
    float* __restrict__ a, int n4)
{
    int i = blockIdx.x * 256 + threadIdx.x;
    if (i >= n4) return;
    float4 x = ((float4*)a)[i];
    x.x = fmaxf(x.x, 0.f);
    x.y = fmaxf(x.y, 0.f);
    x.z = fmaxf(x.z, 0.f);
    x.w = fmaxf(x.w, 0.f);
    ((float4*)a)[i] = x;
}

// ---------------- pooling: gsum[batch[i]] += node_x[i]; gcnt[batch[i]]++ ----------------
__global__ __launch_bounds__(256) void pool_kernel(
    const float* __restrict__ nx, const int* __restrict__ batch,
    float* __restrict__ gsum, float* __restrict__ gcnt, int N)
{
    int tid = blockIdx.x * 256 + threadIdx.x;
    int i = tid >> 5;
    if (i >= N) return;
    int c = (tid & 31) << 2;
    int g = batch[i];
    const float4 v = *(const float4*)&nx[(size_t)i * 128 + c];
    float* dp = &gsum[(size_t)g * 128 + c];
    atomicAdd(dp + 0, v.x);
    atomicAdd(dp + 1, v.y);
    atomicAdd(dp + 2, v.z);
    atomicAdd(dp + 3, v.w);
    if ((tid & 31) == 0) atomicAdd(&gcnt[g], 1.0f);
}

// ---------------- head MLP: pred = elu(gx@Wl1+bl1)@Wl2+bl2 ----------------
__global__ __launch_bounds__(128) void mlp_kernel(
    const float* __restrict__ gsum, const float* __restrict__ gcnt,
    const float* __restrict__ Wl1, const float* __restrict__ bl1,
    const float* __restrict__ Wl2, const float* __restrict__ bl2,
    float* __restrict__ out, int G)
{
    __shared__ float gx[128];
    __shared__ float hid[32];
    int g = blockIdx.x;
    int t = threadIdx.x;
    float inv = 1.0f / fmaxf(gcnt[g], 1.0f);
    gx[t] = gsum[(size_t)g * 128 + t] * inv;
    __syncthreads();
    if (t < 32) {
        float a = bl1[t];
#pragma unroll 8
        for (int k = 0; k < 128; ++k) a = fmaf(gx[k], Wl1[k * 32 + t], a);
        hid[t] = a > 0.f ? a : expm1f(a);
    }
    __syncthreads();
    if (t < 2) {
        float a = bl2[t];
#pragma unroll
        for (int k = 0; k < 32; ++k) a = fmaf(hid[k], Wl2[k * 2 + t], a);
        out[(size_t)g * 2 + t] = a;
    }
}

extern "C" void kernel_launch(void* const* d_in, const int* in_sizes, int n_in,
                              void* d_out, int out_size, void* d_ws, size_t ws_size,
                              hipStream_t stream)
{
    const float* x     = (const float*)d_in[0];
    const int*   ei    = (const int*)d_in[1];     // int32! (2,E) row-major
    const float* ea    = (const float*)d_in[2];
    const int*   batch = (const int*)d_in[3];     // int32!
    const float* W1i   = (const float*)d_in[5];
    const float* W1r   = (const float*)d_in[6];
    const float* b1    = (const float*)d_in[7];
    const float* W2i   = (const float*)d_in[8];
    const float* W2r   = (const float*)d_in[9];
    const float* b2    = (const float*)d_in[10];
    const float* Wl1   = (const float*)d_in[11];
    const float* bl1   = (const float*)d_in[12];
    const float* Wl2   = (const float*)d_in[13];
    const float* bl2   = (const float*)d_in[14];

    const int N = in_sizes[0] / 768;
    const int E = in_sizes[2];
    const int G = out_size / 2;

    char* ws = (char*)d_ws;
    size_t off = 0;
    auto alloc = [&](size_t bytes) -> char* {
        char* p = ws + off;
        off = (off + bytes + 255) & ~(size_t)255;
        return p;
    };
    float* deg  = (float*)alloc((size_t)N * 4);
    float* nrm  = (float*)alloc((size_t)E * 4);
    float* bufA = (float*)alloc((size_t)N * 128 * 4);   // P (propagated) buffer
    float* bufB = (float*)alloc((size_t)N * 128 * 4);   // R / accumulator buffer
    float* gsum = (float*)alloc((size_t)G * 128 * 4);
    float* gcnt = (float*)alloc((size_t)G * 4);

    const int eBlocks = (E + 255) / 256;
    const int mBlocks = (N + 31) / 32;
    const int n4      = N * 128 / 4;

    hipMemsetAsync(deg, 0, (size_t)N * 4, stream);
    deg_kernel<<<eBlocks, 256, 0, stream>>>(ei, ea, deg, E);
    norm_kernel<<<eBlocks, 256, 0, stream>>>(ei, ea, deg, nrm, E);

    // ---- layer 1: bufA = x@W1i ; bufB = x@W1r + b1 ----
    gemm_dual<<<mBlocks, 256, 0, stream>>>(x, W1i, W1r, b1, bufA, bufB, N, 768);
    // bufB += scatter(bufA[row]*nrm -> col)
    agg_scatter<<<(E * 32 + 255) / 256, 256, 0, stream>>>(bufA, ei, nrm, bufB, E);
    // h = elu(relu(.)) == relu(.)
    relu_inplace<<<(n4 + 255) / 256, 256, 0, stream>>>(bufB, n4);

    // ---- layer 2 (in-place on bufB for R) ----
    gemm_dual<<<mBlocks, 256, 0, stream>>>(bufB, W2i, W2r, b2, bufA, bufB, N, 128);
    agg_scatter<<<(E * 32 + 255) / 256, 256, 0, stream>>>(bufA, ei, nrm, bufB, E);
    relu_inplace<<<(n4 + 255) / 256, 256, 0, stream>>>(bufB, n4);

    // ---- pool + head ----
    hipMemsetAsync(gsum, 0, (size_t)G * 128 * 4, stream);
    hipMemsetAsync(gcnt, 0, (size_t)G * 4, stream);
    pool_kernel<<<(N * 32 + 255) / 256, 256, 0, stream>>>(bufB, batch, gsum, gcnt, N);
    mlp_kernel<<<G, 128, 0, stream>>>(gsum, gcnt, Wl1, bl1, Wl2, bl2, (float*)d_out, G);
}

// Round 3
// 1414.718 us; speedup vs baseline: 4.5023x; 4.5023x over previous
//
#include <hip/hip_runtime.h>
#include <hip/hip_bf16.h>
#include <math.h>

// ============ degree + histogram: deg[col]+=ew, cnt[col]++ ============
__global__ __launch_bounds__(256) void deg_hist_kernel(
    const int* __restrict__ ei, const float* __restrict__ ea,
    float* __restrict__ deg, int* __restrict__ cnt, int E)
{
    int e = blockIdx.x * 256 + threadIdx.x;
    if (e >= E) return;
    int c = ei[(size_t)E + e];
    atomicAdd(&deg[c], ea[e]);
    atomicAdd(&cnt[c], 1);
}

// ============ hierarchical exclusive scan (1024 items / block) ============
__global__ __launch_bounds__(256) void scan1_kernel(
    const int* __restrict__ in, int* __restrict__ out, int* __restrict__ blksum, int n)
{
    __shared__ int part[256];
    const int t = threadIdx.x;
    const int base = blockIdx.x * 1024 + t * 4;
    int v[4];
#pragma unroll
    for (int q = 0; q < 4; ++q) v[q] = (base + q < n) ? in[base + q] : 0;
    const int s = v[0] + v[1] + v[2] + v[3];
    part[t] = s;
    __syncthreads();
    for (int off = 1; off < 256; off <<= 1) {
        int x = (t >= off) ? part[t - off] : 0;
        __syncthreads();
        part[t] += x;
        __syncthreads();
    }
    if (t == 255) blksum[blockIdx.x] = part[255];
    int run = part[t] - s;   // exclusive prefix for this thread's chunk
#pragma unroll
    for (int q = 0; q < 4; ++q) {
        if (base + q < n) out[base + q] = run;
        run += v[q];
    }
}

__global__ __launch_bounds__(256) void scan3_kernel(
    int* __restrict__ rowptr, const int* __restrict__ blkoff,
    int* __restrict__ wp, int n, int Etot)
{
    int i = blockIdx.x * 256 + threadIdx.x;
    if (i == 0) rowptr[n] = Etot;
    if (i >= n) return;
    int v = rowptr[i] + blkoff[i >> 10];
    rowptr[i] = v;
    wp[i] = v;
}

// ============ edge placement: csr[p] = (row, norm) bucketed by col ============
__global__ __launch_bounds__(256) void place_kernel(
    const int* __restrict__ ei, const float* __restrict__ ea,
    const float* __restrict__ deg, int* __restrict__ wp,
    int* __restrict__ csr_row, float* __restrict__ csr_nrm, int E)
{
    int e = blockIdx.x * 256 + threadIdx.x;
    if (e >= E) return;
    int r = ei[e];
    int c = ei[(size_t)E + e];
    float dr = deg[r], dc = deg[c];
    float nm = (dr > 0.f ? rsqrtf(dr) : 0.f) * ea[e] * (dc > 0.f ? rsqrtf(dc) : 0.f);
    int p = atomicAdd(&wp[c], 1);
    csr_row[p] = r;
    csr_nrm[p] = nm;
}

// ============ dual GEMM: outP = A@Wi ; outR = A@Wr + bias ============
// A: M x K row-major, Wi/Wr: K x 128. Safe for outR == A (block reads only
// its own 32 rows, all before the epilogue writes).
__global__ __launch_bounds__(256) void gemm_dual(
    const float* __restrict__ A, const float* __restrict__ Wi,
    const float* __restrict__ Wr, const float* __restrict__ bias,
    float* __restrict__ outP, float* __restrict__ outR, int M, int K)
{
    __shared__ float As[32 * 36];
    __shared__ float Wis[32 * 128];
    __shared__ float Wrs[32 * 128];

    const int t = threadIdx.x;
    const int m0 = blockIdx.x * 32;
    const int c0 = (t & 31) * 4;
    const int r0 = (t >> 5) * 4;
    const int lr = t >> 3;
    const int lc = (t & 7) * 4;

    float acc_i[4][4] = {{0.f}};
    float acc_r[4][4] = {{0.f}};

    for (int k0 = 0; k0 < K; k0 += 32) {
        if (m0 + lr < M) {
            const float4 v = *(const float4*)&A[(size_t)(m0 + lr) * K + k0 + lc];
            As[(lc + 0) * 36 + lr] = v.x;
            As[(lc + 1) * 36 + lr] = v.y;
            As[(lc + 2) * 36 + lr] = v.z;
            As[(lc + 3) * 36 + lr] = v.w;
        }
        {
            const float4* srcI = (const float4*)(Wi + (size_t)k0 * 128);
            const float4* srcR = (const float4*)(Wr + (size_t)k0 * 128);
            float4* dI = (float4*)Wis;
            float4* dR = (float4*)Wrs;
#pragma unroll
            for (int i = 0; i < 4; ++i) {
                dI[t + i * 256] = srcI[t + i * 256];
                dR[t + i * 256] = srcR[t + i * 256];
            }
        }
        __syncthreads();
#pragma unroll
        for (int k = 0; k < 32; ++k) {
            const float4 av = *(const float4*)&As[k * 36 + r0];
            const float4 wi = *(const float4*)&Wis[k * 128 + c0];
            const float4 wr = *(const float4*)&Wrs[k * 128 + c0];
            const float a[4] = {av.x, av.y, av.z, av.w};
            const float bi[4] = {wi.x, wi.y, wi.z, wi.w};
            const float br[4] = {wr.x, wr.y, wr.z, wr.w};
#pragma unroll
            for (int i = 0; i < 4; ++i)
#pragma unroll
                for (int j = 0; j < 4; ++j) {
                    acc_i[i][j] = fmaf(a[i], bi[j], acc_i[i][j]);
                    acc_r[i][j] = fmaf(a[i], br[j], acc_r[i][j]);
                }
        }
        __syncthreads();
    }

    float b[4];
#pragma unroll
    for (int j = 0; j < 4; ++j) b[j] = bias[c0 + j];
#pragma unroll
    for (int i = 0; i < 4; ++i) {
        int m = m0 + r0 + i;
        if (m < M) {
            float4 vp, vr;
            vp.x = acc_i[i][0]; vp.y = acc_i[i][1]; vp.z = acc_i[i][2]; vp.w = acc_i[i][3];
            vr.x = acc_r[i][0] + b[0]; vr.y = acc_r[i][1] + b[1];
            vr.z = acc_r[i][2] + b[2]; vr.w = acc_r[i][3] + b[3];
            *(float4*)&outP[(size_t)m * 128 + c0] = vp;
            *(float4*)&outR[(size_t)m * 128 + c0] = vr;
        }
    }
}

// ============ gather aggregation (CSR) + fused add-bias-residual + ReLU ============
// dst[i] = relu(rbuf[i] + sum_{j in in(i)} nrm_j * src[row_j])
// One 64-lane wave per node; lane handles float2 (col = lane*2).
// Safe for dst == rbuf (wave reads only row i of rbuf, writes only row i).
__global__ __launch_bounds__(256) void agg_gather(
    const float* __restrict__ src, const float* __restrict__ rbuf,
    const int* __restrict__ rowptr, const int* __restrict__ csr_row,
    const float* __restrict__ csr_nrm, float* __restrict__ dst, int N)
{
    const int wave = (blockIdx.x * 256 + threadIdx.x) >> 6;
    const int lane = threadIdx.x & 63;
    if (wave >= N) return;
    const int i = wave;
    const int beg = rowptr[i];
    const int end = rowptr[i + 1];
    const int c = lane * 2;

    float2 acc0 = {0.f, 0.f}, acc1 = {0.f, 0.f};
    int j = beg;
    for (; j + 1 < end; j += 2) {
        const int   r0 = csr_row[j];
        const int   r1 = csr_row[j + 1];
        const float n0 = csr_nrm[j];
        const float n1 = csr_nrm[j + 1];
        const float2 v0 = *(const float2*)&src[(size_t)r0 * 128 + c];
        const float2 v1 = *(const float2*)&src[(size_t)r1 * 128 + c];
        acc0.x = fmaf(v0.x, n0, acc0.x);
        acc0.y = fmaf(v0.y, n0, acc0.y);
        acc1.x = fmaf(v1.x, n1, acc1.x);
        acc1.y = fmaf(v1.y, n1, acc1.y);
    }
    if (j < end) {
        const int   r0 = csr_row[j];
        const float n0 = csr_nrm[j];
        const float2 v0 = *(const float2*)&src[(size_t)r0 * 128 + c];
        acc0.x = fmaf(v0.x, n0, acc0.x);
        acc0.y = fmaf(v0.y, n0, acc0.y);
    }
    const float2 r = *(const float2*)&rbuf[(size_t)i * 128 + c];
    float2 o;
    o.x = fmaxf(acc0.x + acc1.x + r.x, 0.f);
    o.y = fmaxf(acc0.y + acc1.y + r.y, 0.f);
    *(float2*)&dst[(size_t)i * 128 + c] = o;
}

// ============ pooling ============
__global__ __launch_bounds__(256) void pool_kernel(
    const float* __restrict__ nx, const int* __restrict__ batch,
    float* __restrict__ gsum, float* __restrict__ gcnt, int N)
{
    int tid = blockIdx.x * 256 + threadIdx.x;
    int i = tid >> 5;
    if (i >= N) return;
    int c = (tid & 31) << 2;
    int g = batch[i];
    const float4 v = *(const float4*)&nx[(size_t)i * 128 + c];
    float* dp = &gsum[(size_t)g * 128 + c];
    atomicAdd(dp + 0, v.x);
    atomicAdd(dp + 1, v.y);
    atomicAdd(dp + 2, v.z);
    atomicAdd(dp + 3, v.w);
    if ((tid & 31) == 0) atomicAdd(&gcnt[g], 1.0f);
}

// ============ head MLP ============
__global__ __launch_bounds__(128) void mlp_kernel(
    const float* __restrict__ gsum, const float* __restrict__ gcnt,
    const float* __restrict__ Wl1, const float* __restrict__ bl1,
    const float* __restrict__ Wl2, const float* __restrict__ bl2,
    float* __restrict__ out, int G)
{
    __shared__ float gx[128];
    __shared__ float hid[32];
    int g = blockIdx.x;
    int t = threadIdx.x;
    float inv = 1.0f / fmaxf(gcnt[g], 1.0f);
    gx[t] = gsum[(size_t)g * 128 + t] * inv;
    __syncthreads();
    if (t < 32) {
        float a = bl1[t];
#pragma unroll 8
        for (int k = 0; k < 128; ++k) a = fmaf(gx[k], Wl1[k * 32 + t], a);
        hid[t] = a > 0.f ? a : expm1f(a);
    }
    __syncthreads();
    if (t < 2) {
        float a = bl2[t];
#pragma unroll
        for (int k = 0; k < 32; ++k) a = fmaf(hid[k], Wl2[k * 2 + t], a);
        out[(size_t)g * 2 + t] = a;
    }
}

extern "C" void kernel_launch(void* const* d_in, const int* in_sizes, int n_in,
                              void* d_out, int out_size, void* d_ws, size_t ws_size,
                              hipStream_t stream)
{
    const float* x     = (const float*)d_in[0];
    const int*   ei    = (const int*)d_in[1];
    const float* ea    = (const float*)d_in[2];
    const int*   batch = (const int*)d_in[3];
    const float* W1i   = (const float*)d_in[5];
    const float* W1r   = (const float*)d_in[6];
    const float* b1    = (const float*)d_in[7];
    const float* W2i   = (const float*)d_in[8];
    const float* W2r   = (const float*)d_in[9];
    const float* b2    = (const float*)d_in[10];
    const float* Wl1   = (const float*)d_in[11];
    const float* bl1   = (const float*)d_in[12];
    const float* Wl2   = (const float*)d_in[13];
    const float* bl2   = (const float*)d_in[14];

    const int N = in_sizes[0] / 768;
    const int E = in_sizes[2];
    const int G = out_size / 2;

    char* ws = (char*)d_ws;
    size_t off = 0;
    auto alloc = [&](size_t bytes) -> char* {
        char* p = ws + off;
        off = (off + bytes + 255) & ~(size_t)255;
        return p;
    };
    float* deg     = (float*)alloc((size_t)N * 4);
    int*   cnt     = (int*)alloc((size_t)N * 4);
    int*   rowptr  = (int*)alloc((size_t)(N + 1) * 4);
    int*   wp      = (int*)alloc((size_t)N * 4);
    int*   blkoff  = (int*)alloc((size_t)1056 * 4);
    int*   blkdum  = (int*)alloc((size_t)4 * 4);
    int*   csr_row = (int*)alloc((size_t)E * 4);
    float* csr_nrm = (float*)alloc((size_t)E * 4);
    float* bufA    = (float*)alloc((size_t)N * 128 * 4);
    float* bufB    = (float*)alloc((size_t)N * 128 * 4);
    float* gsum    = (float*)alloc((size_t)G * 128 * 4);
    float* gcnt    = (float*)alloc((size_t)G * 4);

    const int eBlocks = (E + 255) / 256;
    const int mBlocks = (N + 31) / 32;
    const int nb      = (N + 1023) / 1024;     // scan blocks (<=1024 assumed)
    const int nBlocks = (N + 255) / 256;

    // ---- CSR build ----
    hipMemsetAsync(deg, 0, (size_t)N * 4, stream);
    hipMemsetAsync(cnt, 0, (size_t)N * 4, stream);
    deg_hist_kernel<<<eBlocks, 256, 0, stream>>>(ei, ea, deg, cnt, E);
    scan1_kernel<<<nb, 256, 0, stream>>>(cnt, rowptr, blkoff, N);
    scan1_kernel<<<1, 256, 0, stream>>>(blkoff, blkoff, blkdum, nb);
    scan3_kernel<<<nBlocks, 256, 0, stream>>>(rowptr, blkoff, wp, N, E);
    place_kernel<<<eBlocks, 256, 0, stream>>>(ei, ea, deg, wp, csr_row, csr_nrm, E);

    // ---- layer 1: bufA = x@W1i ; bufB = x@W1r + b1 ----
    gemm_dual<<<mBlocks, 256, 0, stream>>>(x, W1i, W1r, b1, bufA, bufB, N, 768);
    // bufB = relu(bufB + gather(bufA)) ; elu(relu(.)) == relu(.)
    agg_gather<<<(N * 64 + 255) / 256, 256, 0, stream>>>(
        bufA, bufB, rowptr, csr_row, csr_nrm, bufB, N);

    // ---- layer 2 ----
    gemm_dual<<<mBlocks, 256, 0, stream>>>(bufB, W2i, W2r, b2, bufA, bufB, N, 128);
    agg_gather<<<(N * 64 + 255) / 256, 256, 0, stream>>>(
        bufA, bufB, rowptr, csr_row, csr_nrm, bufB, N);

    // ---- pool + head ----
    hipMemsetAsync(gsum, 0, (size_t)G * 128 * 4, stream);
    hipMemsetAsync(gcnt, 0, (size_t)G * 4, stream);
    pool_kernel<<<(N * 32 + 255) / 256, 256, 0, stream>>>(bufB, batch, gsum, gcnt, N);
    mlp_kernel<<<G, 128, 0, stream>>>(gsum, gcnt, Wl1, bl1, Wl2, bl2, (float*)d_out, G);
}

// Round 4
// 756.834 us; speedup vs baseline: 8.4159x; 1.8693x over previous
//
#include <hip/hip_runtime.h>
#include <hip/hip_bf16.h>
#include <math.h>

typedef __attribute__((ext_vector_type(8))) short short8;
typedef __attribute__((ext_vector_type(4))) float f32x4;

__device__ __forceinline__ unsigned short f2bf(float f) {
    unsigned int u = __builtin_bit_cast(unsigned int, f);
    return (unsigned short)((u + 0x7fffu + ((u >> 16) & 1u)) >> 16);   // RNE
}

// ============ degree + histogram ============
__global__ __launch_bounds__(256) void deg_hist_kernel(
    const int* __restrict__ ei, const float* __restrict__ ea,
    float* __restrict__ deg, int* __restrict__ cnt, int E)
{
    int e = blockIdx.x * 256 + threadIdx.x;
    if (e >= E) return;
    int c = ei[(size_t)E + e];
    atomicAdd(&deg[c], ea[e]);
    atomicAdd(&cnt[c], 1);
}

// ============ hierarchical exclusive scan ============
__global__ __launch_bounds__(256) void scan1_kernel(
    const int* __restrict__ in, int* __restrict__ out, int* __restrict__ blksum, int n)
{
    __shared__ int part[256];
    const int t = threadIdx.x;
    const int base = blockIdx.x * 1024 + t * 4;
    int v[4];
#pragma unroll
    for (int q = 0; q < 4; ++q) v[q] = (base + q < n) ? in[base + q] : 0;
    const int s = v[0] + v[1] + v[2] + v[3];
    part[t] = s;
    __syncthreads();
    for (int off = 1; off < 256; off <<= 1) {
        int x = (t >= off) ? part[t - off] : 0;
        __syncthreads();
        part[t] += x;
        __syncthreads();
    }
    if (t == 255) blksum[blockIdx.x] = part[255];
    int run = part[t] - s;
#pragma unroll
    for (int q = 0; q < 4; ++q) {
        if (base + q < n) out[base + q] = run;
        run += v[q];
    }
}

__global__ __launch_bounds__(256) void scan3_kernel(
    int* __restrict__ rowptr, const int* __restrict__ blkoff,
    int* __restrict__ wp, int n, int Etot)
{
    int i = blockIdx.x * 256 + threadIdx.x;
    if (i == 0) rowptr[n] = Etot;
    if (i >= n) return;
    int v = rowptr[i] + blkoff[i >> 10];
    rowptr[i] = v;
    wp[i] = v;
}

// ============ edge placement ============
__global__ __launch_bounds__(256) void place_kernel(
    const int* __restrict__ ei, const float* __restrict__ ea,
    const float* __restrict__ deg, int* __restrict__ wp,
    int* __restrict__ csr_row, float* __restrict__ csr_nrm, int E)
{
    int e = blockIdx.x * 256 + threadIdx.x;
    if (e >= E) return;
    int r = ei[e];
    int c = ei[(size_t)E + e];
    float dr = deg[r], dc = deg[c];
    float nm = (dr > 0.f ? rsqrtf(dr) : 0.f) * ea[e] * (dc > 0.f ? rsqrtf(dc) : 0.f);
    int p = atomicAdd(&wp[c], 1);
    csr_row[p] = r;
    csr_nrm[p] = nm;
}

// ============ weight pre-convert: Wt[n][k] = bf16(W[k][n]), dual-packed ============
__global__ __launch_bounds__(256) void conv_weights(
    const float* __restrict__ W1i, const float* __restrict__ W1r,
    const float* __restrict__ W2i, const float* __restrict__ W2r,
    unsigned short* __restrict__ W1t, unsigned short* __restrict__ W2t)
{
    int id = blockIdx.x * 256 + threadIdx.x;
    if (id < 256 * 768) {
        int n = id / 768, k = id % 768;
        float v = (n < 128) ? W1i[k * 128 + n] : W1r[k * 128 + (n - 128)];
        W1t[id] = f2bf(v);
    } else {
        int id2 = id - 256 * 768;
        if (id2 < 256 * 128) {
            int n = id2 / 128, k = id2 % 128;
            float v = (n < 128) ? W2i[k * 128 + n] : W2r[k * 128 + (n - 128)];
            W2t[id2] = f2bf(v);
        }
    }
}

// ============ MFMA dual GEMM ============
// A: M x K fp32 row-major. Wt: 256 x K bf16 (Wt[n][k] = W[k][n]; n<128 -> Wi, else Wr).
// outP[m][n] = (A@Wi)[m][n] ; outR[m][n] = (A@Wr)[m][n] + bias[n].
// Block: 512 thr (8 waves, 2M x 4N), tile 64(M) x 256(N), BK=64.
// LDS XOR-swizzle (row&7)<<4 on both write and read (G4: 128B-pitch conflict fix).
// Safe for outR == A: block reads only its own 64 A-rows, all before epilogue.
__global__ __launch_bounds__(512) void gemm_mfma_dual(
    const float* __restrict__ A, const unsigned short* __restrict__ Wt,
    const float* __restrict__ bias, float* __restrict__ outP,
    float* __restrict__ outR, int M, int K)
{
    __shared__ __align__(16) unsigned char As[64 * 128];    // 64 rows x 64 bf16
    __shared__ __align__(16) unsigned char Bs[256 * 128];   // 256 n  x 64 bf16

    const int t = threadIdx.x;
    const int m0 = blockIdx.x * 64;
    const int lane = t & 63;
    const int wid = t >> 6;
    const int wm = wid >> 2;            // 0..1
    const int wn = wid & 3;             // 0..3
    const int lr = lane & 15;
    const int lk = (lane >> 4) * 8;

    f32x4 acc[2][4] = {};

    // A-staging indices: thread -> (row, 8-col chunk)
    const int sr = t >> 3;
    const int sk = (t & 7) * 8;
    const int aRow = m0 + sr;
    const bool aOk = (aRow < M);
    const float* aSrc = A + (size_t)(aOk ? aRow : 0) * K + sk;
    const int aDst = sr * 128 + ((sk * 2) ^ ((sr & 7) << 4));

    for (int k0 = 0; k0 < K; k0 += 64) {
        // ---- stage A: fp32 -> bf16 ----
        short8 av = {};
        if (aOk) {
            const float4 f0 = *(const float4*)(aSrc + k0);
            const float4 f1 = *(const float4*)(aSrc + k0 + 4);
            av[0] = (short)f2bf(f0.x); av[1] = (short)f2bf(f0.y);
            av[2] = (short)f2bf(f0.z); av[3] = (short)f2bf(f0.w);
            av[4] = (short)f2bf(f1.x); av[5] = (short)f2bf(f1.y);
            av[6] = (short)f2bf(f1.z); av[7] = (short)f2bf(f1.w);
        }
        *(short8*)(As + aDst) = av;
        // ---- stage B: bf16 copy (L2-resident weights) ----
#pragma unroll
        for (int i = 0; i < 4; ++i) {
            const int idx = t + i * 512;
            const int n = idx >> 3, kk = (idx & 7) * 8;
            const short8 bv = *(const short8*)(Wt + (size_t)n * K + k0 + kk);
            *(short8*)(Bs + n * 128 + ((kk * 2) ^ ((n & 7) << 4))) = bv;
        }
        __syncthreads();
        // ---- compute: 2 K=32 sub-steps, 8 MFMA each ----
#pragma unroll
        for (int ks = 0; ks < 2; ++ks) {
            short8 a[2], b[4];
#pragma unroll
            for (int mf = 0; mf < 2; ++mf) {
                const int r = wm * 32 + mf * 16 + lr;
                a[mf] = *(const short8*)(As + r * 128 + (((ks * 32 + lk) * 2) ^ ((r & 7) << 4)));
            }
#pragma unroll
            for (int nf = 0; nf < 4; ++nf) {
                const int n = wn * 64 + nf * 16 + lr;
                b[nf] = *(const short8*)(Bs + n * 128 + (((ks * 32 + lk) * 2) ^ ((n & 7) << 4)));
            }
#pragma unroll
            for (int mf = 0; mf < 2; ++mf)
#pragma unroll
                for (int nf = 0; nf < 4; ++nf)
                    acc[mf][nf] = __builtin_amdgcn_mfma_f32_16x16x32_bf16(
                        a[mf], b[nf], acc[mf][nf], 0, 0, 0);
        }
        __syncthreads();
    }

    // ---- epilogue: C/D layout col=lane&15, row=(lane>>4)*4+j (m89/m91) ----
#pragma unroll
    for (int mf = 0; mf < 2; ++mf) {
#pragma unroll
        for (int nf = 0; nf < 4; ++nf) {
            const int n = wn * 64 + nf * 16 + lr;
            float badd;
            float* dst;
            int nl;
            if (n < 128) { dst = outP; nl = n; badd = 0.f; }
            else         { dst = outR; nl = n - 128; badd = bias[nl]; }
            const f32x4 v = acc[mf][nf];
#pragma unroll
            for (int j = 0; j < 4; ++j) {
                const int m = m0 + wm * 32 + mf * 16 + (lane >> 4) * 4 + j;
                if (m < M) dst[(size_t)m * 128 + nl] = v[j] + badd;
            }
        }
    }
}

// ============ gather aggregation (CSR) + fused residual + ReLU ============
__global__ __launch_bounds__(256) void agg_gather(
    const float* __restrict__ src, const float* __restrict__ rbuf,
    const int* __restrict__ rowptr, const int* __restrict__ csr_row,
    const float* __restrict__ csr_nrm, float* __restrict__ dst, int N)
{
    const int wave = (blockIdx.x * 256 + threadIdx.x) >> 6;
    const int lane = threadIdx.x & 63;
    if (wave >= N) return;
    const int i = wave;
    const int beg = rowptr[i];
    const int end = rowptr[i + 1];
    const int c = lane * 2;

    float2 acc0 = {0.f, 0.f}, acc1 = {0.f, 0.f};
    int j = beg;
    for (; j + 1 < end; j += 2) {
        const int   r0 = csr_row[j];
        const int   r1 = csr_row[j + 1];
        const float n0 = csr_nrm[j];
        const float n1 = csr_nrm[j + 1];
        const float2 v0 = *(const float2*)&src[(size_t)r0 * 128 + c];
        const float2 v1 = *(const float2*)&src[(size_t)r1 * 128 + c];
        acc0.x = fmaf(v0.x, n0, acc0.x);
        acc0.y = fmaf(v0.y, n0, acc0.y);
        acc1.x = fmaf(v1.x, n1, acc1.x);
        acc1.y = fmaf(v1.y, n1, acc1.y);
    }
    if (j < end) {
        const int   r0 = csr_row[j];
        const float n0 = csr_nrm[j];
        const float2 v0 = *(const float2*)&src[(size_t)r0 * 128 + c];
        acc0.x = fmaf(v0.x, n0, acc0.x);
        acc0.y = fmaf(v0.y, n0, acc0.y);
    }
    const float2 r = *(const float2*)&rbuf[(size_t)i * 128 + c];
    float2 o;
    o.x = fmaxf(acc0.x + acc1.x + r.x, 0.f);
    o.y = fmaxf(acc0.y + acc1.y + r.y, 0.f);
    *(float2*)&dst[(size_t)i * 128 + c] = o;
}

// ============ fused mean-pool (sorted batch, binary search) + head MLP ============
__global__ __launch_bounds__(128) void pool_mlp(
    const float* __restrict__ nx, const int* __restrict__ batch, int N,
    const float* __restrict__ Wl1, const float* __restrict__ bl1,
    const float* __restrict__ Wl2, const float* __restrict__ bl2,
    float* __restrict__ out)
{
    __shared__ float gx[128];
    __shared__ float hid[32];
    __shared__ int rng[2];
    const int g = blockIdx.x;
    const int t = threadIdx.x;
    if (t < 2) {
        const int target = g + t;
        int lo = 0, hi = N;
        while (lo < hi) {
            int mid = (lo + hi) >> 1;
            if (batch[mid] < target) lo = mid + 1; else hi = mid;
        }
        rng[t] = lo;
    }
    __syncthreads();
    const int s = rng[0], e = rng[1];
    float acc = 0.f;
    for (int i = s; i < e; ++i) acc += nx[(size_t)i * 128 + t];
    gx[t] = acc / fmaxf((float)(e - s), 1.f);
    __syncthreads();
    if (t < 32) {
        float a = bl1[t];
#pragma unroll 8
        for (int k = 0; k < 128; ++k) a = fmaf(gx[k], Wl1[k * 32 + t], a);
        hid[t] = a > 0.f ? a : expm1f(a);
    }
    __syncthreads();
    if (t < 2) {
        float a = bl2[t];
#pragma unroll
        for (int k = 0; k < 32; ++k) a = fmaf(hid[k], Wl2[k * 2 + t], a);
        out[(size_t)g * 2 + t] = a;
    }
}

extern "C" void kernel_launch(void* const* d_in, const int* in_sizes, int n_in,
                              void* d_out, int out_size, void* d_ws, size_t ws_size,
                              hipStream_t stream)
{
    const float* x     = (const float*)d_in[0];
    const int*   ei    = (const int*)d_in[1];
    const float* ea    = (const float*)d_in[2];
    const int*   batch = (const int*)d_in[3];
    const float* W1i   = (const float*)d_in[5];
    const float* W1r   = (const float*)d_in[6];
    const float* b1    = (const float*)d_in[7];
    const float* W2i   = (const float*)d_in[8];
    const float* W2r   = (const float*)d_in[9];
    const float* b2    = (const float*)d_in[10];
    const float* Wl1   = (const float*)d_in[11];
    const float* bl1   = (const float*)d_in[12];
    const float* Wl2   = (const float*)d_in[13];
    const float* bl2   = (const float*)d_in[14];

    const int N = in_sizes[0] / 768;
    const int E = in_sizes[2];
    const int G = out_size / 2;

    char* ws = (char*)d_ws;
    size_t off = 0;
    auto alloc = [&](size_t bytes) -> char* {
        char* p = ws + off;
        off = (off + bytes + 255) & ~(size_t)255;
        return p;
    };
    float* deg     = (float*)alloc((size_t)N * 4);
    int*   cnt     = (int*)alloc((size_t)N * 4);
    int*   rowptr  = (int*)alloc((size_t)(N + 1) * 4);
    int*   wp      = (int*)alloc((size_t)N * 4);
    int*   blkoff  = (int*)alloc((size_t)1056 * 4);
    int*   blkdum  = (int*)alloc((size_t)4 * 4);
    int*   csr_row = (int*)alloc((size_t)E * 4);
    float* csr_nrm = (float*)alloc((size_t)E * 4);
    float* bufA    = (float*)alloc((size_t)N * 128 * 4);
    float* bufB    = (float*)alloc((size_t)N * 128 * 4);
    unsigned short* W1t = (unsigned short*)alloc((size_t)256 * 768 * 2);
    unsigned short* W2t = (unsigned short*)alloc((size_t)256 * 128 * 2);

    const int eBlocks = (E + 255) / 256;
    const int gBlocks = (N + 63) / 64;
    const int nb      = (N + 1023) / 1024;
    const int nBlocks = (N + 255) / 256;

    // ---- CSR build + weight convert ----
    hipMemsetAsync(deg, 0, (size_t)N * 4, stream);
    hipMemsetAsync(cnt, 0, (size_t)N * 4, stream);
    deg_hist_kernel<<<eBlocks, 256, 0, stream>>>(ei, ea, deg, cnt, E);
    scan1_kernel<<<nb, 256, 0, stream>>>(cnt, rowptr, blkoff, N);
    scan1_kernel<<<1, 256, 0, stream>>>(blkoff, blkoff, blkdum, nb);
    scan3_kernel<<<nBlocks, 256, 0, stream>>>(rowptr, blkoff, wp, N, E);
    place_kernel<<<eBlocks, 256, 0, stream>>>(ei, ea, deg, wp, csr_row, csr_nrm, E);
    conv_weights<<<(256 * 768 + 256 * 128 + 255) / 256, 256, 0, stream>>>(
        W1i, W1r, W2i, W2r, W1t, W2t);

    // ---- layer 1 ----
    gemm_mfma_dual<<<gBlocks, 512, 0, stream>>>(x, W1t, b1, bufA, bufB, N, 768);
    agg_gather<<<(N * 64 + 255) / 256, 256, 0, stream>>>(
        bufA, bufB, rowptr, csr_row, csr_nrm, bufB, N);

    // ---- layer 2 (outR in-place on bufB) ----
    gemm_mfma_dual<<<gBlocks, 512, 0, stream>>>(bufB, W2t, b2, bufA, bufB, N, 128);
    agg_gather<<<(N * 64 + 255) / 256, 256, 0, stream>>>(
        bufA, bufB, rowptr, csr_row, csr_nrm, bufB, N);

    // ---- fused pool + head ----
    pool_mlp<<<G, 128, 0, stream>>>(bufB, batch, N, Wl1, bl1, Wl2, bl2, (float*)d_out);
}

// Round 5
// 604.196 us; speedup vs baseline: 10.5421x; 1.2526x over previous
//
#include <hip/hip_runtime.h>
#include <hip/hip_bf16.h>
#include <math.h>

typedef __attribute__((ext_vector_type(8))) short short8;
typedef __attribute__((ext_vector_type(4))) float f32x4;

__device__ __forceinline__ unsigned short f2bf(float f) {
    unsigned int u = __builtin_bit_cast(unsigned int, f);
    return (unsigned short)((u + 0x7fffu + ((u >> 16) & 1u)) >> 16);   // RNE
}
__device__ __forceinline__ float bflo(unsigned int u) {
    return __builtin_bit_cast(float, u << 16);
}
__device__ __forceinline__ float bfhi(unsigned int u) {
    return __builtin_bit_cast(float, u & 0xffff0000u);
}

// ============ degree + histogram ============
__global__ __launch_bounds__(256) void deg_hist_kernel(
    const int* __restrict__ ei, const float* __restrict__ ea,
    float* __restrict__ deg, int* __restrict__ cnt, int E)
{
    int e = blockIdx.x * 256 + threadIdx.x;
    if (e >= E) return;
    int c = ei[(size_t)E + e];
    atomicAdd(&deg[c], ea[e]);
    atomicAdd(&cnt[c], 1);
}

// ============ hierarchical exclusive scan ============
__global__ __launch_bounds__(256) void scan1_kernel(
    const int* __restrict__ in, int* __restrict__ out, int* __restrict__ blksum, int n)
{
    __shared__ int part[256];
    const int t = threadIdx.x;
    const int base = blockIdx.x * 1024 + t * 4;
    int v[4];
#pragma unroll
    for (int q = 0; q < 4; ++q) v[q] = (base + q < n) ? in[base + q] : 0;
    const int s = v[0] + v[1] + v[2] + v[3];
    part[t] = s;
    __syncthreads();
    for (int off = 1; off < 256; off <<= 1) {
        int x = (t >= off) ? part[t - off] : 0;
        __syncthreads();
        part[t] += x;
        __syncthreads();
    }
    if (t == 255) blksum[blockIdx.x] = part[255];
    int run = part[t] - s;
#pragma unroll
    for (int q = 0; q < 4; ++q) {
        if (base + q < n) out[base + q] = run;
        run += v[q];
    }
}

__global__ __launch_bounds__(256) void scan3_kernel(
    int* __restrict__ rowptr, const int* __restrict__ blkoff,
    int* __restrict__ wp, int n, int Etot)
{
    int i = blockIdx.x * 256 + threadIdx.x;
    if (i == 0) rowptr[n] = Etot;
    if (i >= n) return;
    int v = rowptr[i] + blkoff[i >> 10];
    rowptr[i] = v;
    wp[i] = v;
}

// ============ edge placement ============
__global__ __launch_bounds__(256) void place_kernel(
    const int* __restrict__ ei, const float* __restrict__ ea,
    const float* __restrict__ deg, int* __restrict__ wp,
    int* __restrict__ csr_row, float* __restrict__ csr_nrm, int E)
{
    int e = blockIdx.x * 256 + threadIdx.x;
    if (e >= E) return;
    int r = ei[e];
    int c = ei[(size_t)E + e];
    float dr = deg[r], dc = deg[c];
    float nm = (dr > 0.f ? rsqrtf(dr) : 0.f) * ea[e] * (dc > 0.f ? rsqrtf(dc) : 0.f);
    int p = atomicAdd(&wp[c], 1);
    csr_row[p] = r;
    csr_nrm[p] = nm;
}

// ============ weight pre-convert ============
// W1t: 256 x 768 (n<128 -> W1i, else W1r), W2t: 128 x 256 (k<128 -> W2i, else W2r)
__global__ __launch_bounds__(256) void conv_weights(
    const float* __restrict__ W1i, const float* __restrict__ W1r,
    const float* __restrict__ W2i, const float* __restrict__ W2r,
    unsigned short* __restrict__ W1t, unsigned short* __restrict__ W2t)
{
    int id = blockIdx.x * 256 + threadIdx.x;
    if (id < 256 * 768) {
        int n = id / 768, k = id % 768;
        float v = (n < 128) ? W1i[k * 128 + n] : W1r[k * 128 + (n - 128)];
        W1t[id] = f2bf(v);
    } else {
        int id2 = id - 256 * 768;
        if (id2 < 128 * 256) {
            int n = id2 >> 8, k = id2 & 255;
            float v = (k < 128) ? W2i[k * 128 + n] : W2r[(k - 128) * 128 + n];
            W2t[id2] = f2bf(v);
        }
    }
}

// ============ MFMA dual GEMM (layer 1) ============
// A: M x K fp32. Wt: 256 x K bf16. outP bf16 = A@Wi ; outR fp32 = A@Wr + bias.
// 512 thr, 8 waves (2M x 4N), tile 64 x 256, BK=64, XOR-swizzled LDS.
__global__ __launch_bounds__(512) void gemm_mfma_dual(
    const float* __restrict__ A, const unsigned short* __restrict__ Wt,
    const float* __restrict__ bias, unsigned short* __restrict__ outP,
    float* __restrict__ outR, int M, int K)
{
    __shared__ __align__(16) unsigned char As[64 * 128];
    __shared__ __align__(16) unsigned char Bs[256 * 128];

    const int t = threadIdx.x;
    const int m0 = blockIdx.x * 64;
    const int lane = t & 63;
    const int wid = t >> 6;
    const int wm = wid >> 2;
    const int wn = wid & 3;
    const int lr = lane & 15;
    const int lk = (lane >> 4) * 8;

    f32x4 acc[2][4] = {};

    const int sr = t >> 3;
    const int sk = (t & 7) * 8;
    const int aRow = m0 + sr;
    const bool aOk = (aRow < M);
    const float* aSrc = A + (size_t)(aOk ? aRow : 0) * K + sk;
    const int aDst = sr * 128 + ((sk * 2) ^ ((sr & 7) << 4));

    for (int k0 = 0; k0 < K; k0 += 64) {
        short8 av = {};
        if (aOk) {
            const float4 f0 = *(const float4*)(aSrc + k0);
            const float4 f1 = *(const float4*)(aSrc + k0 + 4);
            av[0] = (short)f2bf(f0.x); av[1] = (short)f2bf(f0.y);
            av[2] = (short)f2bf(f0.z); av[3] = (short)f2bf(f0.w);
            av[4] = (short)f2bf(f1.x); av[5] = (short)f2bf(f1.y);
            av[6] = (short)f2bf(f1.z); av[7] = (short)f2bf(f1.w);
        }
        *(short8*)(As + aDst) = av;
#pragma unroll
        for (int i = 0; i < 4; ++i) {
            const int idx = t + i * 512;
            const int n = idx >> 3, kk = (idx & 7) * 8;
            const short8 bv = *(const short8*)(Wt + (size_t)n * K + k0 + kk);
            *(short8*)(Bs + n * 128 + ((kk * 2) ^ ((n & 7) << 4))) = bv;
        }
        __syncthreads();
#pragma unroll
        for (int ks = 0; ks < 2; ++ks) {
            short8 a[2], b[4];
#pragma unroll
            for (int mf = 0; mf < 2; ++mf) {
                const int r = wm * 32 + mf * 16 + lr;
                a[mf] = *(const short8*)(As + r * 128 + (((ks * 32 + lk) * 2) ^ ((r & 7) << 4)));
            }
#pragma unroll
            for (int nf = 0; nf < 4; ++nf) {
                const int n = wn * 64 + nf * 16 + lr;
                b[nf] = *(const short8*)(Bs + n * 128 + (((ks * 32 + lk) * 2) ^ ((n & 7) << 4)));
            }
#pragma unroll
            for (int mf = 0; mf < 2; ++mf)
#pragma unroll
                for (int nf = 0; nf < 4; ++nf)
                    acc[mf][nf] = __builtin_amdgcn_mfma_f32_16x16x32_bf16(
                        a[mf], b[nf], acc[mf][nf], 0, 0, 0);
        }
        __syncthreads();
    }

#pragma unroll
    for (int mf = 0; mf < 2; ++mf) {
#pragma unroll
        for (int nf = 0; nf < 4; ++nf) {
            const int n = wn * 64 + nf * 16 + lr;
            const f32x4 v = acc[mf][nf];
            if (n < 128) {
#pragma unroll
                for (int j = 0; j < 4; ++j) {
                    const int m = m0 + wm * 32 + mf * 16 + (lane >> 4) * 4 + j;
                    if (m < M) outP[(size_t)m * 128 + n] = f2bf(v[j]);
                }
            } else {
                const int nl = n - 128;
                const float badd = bias[nl];
#pragma unroll
                for (int j = 0; j < 4; ++j) {
                    const int m = m0 + wm * 32 + mf * 16 + (lane >> 4) * 4 + j;
                    if (m < M) outR[(size_t)m * 128 + nl] = v[j] + badd;
                }
            }
        }
    }
}

// ============ MFMA single GEMM (layer 2, K=256 over [ah|h]) + bias + ReLU ============
// outX[m][n] = relu( (ah@W2i + h@W2r)[m][n] + bias[n] )
// 512 thr, 8 waves (4M x 2N), tile 128 x 128, BK=64.
__global__ __launch_bounds__(512) void gemm_mfma_single(
    const unsigned short* __restrict__ Aa,   // ah : k in [0,128)
    const unsigned short* __restrict__ Ah,   // h  : k in [128,256)
    const unsigned short* __restrict__ Wt,   // 128 x 256
    const float* __restrict__ bias,
    float* __restrict__ outX, int M)
{
    __shared__ __align__(16) unsigned char As[128 * 128];
    __shared__ __align__(16) unsigned char Bs[128 * 128];

    const int t = threadIdx.x;
    const int m0 = blockIdx.x * 128;
    const int lane = t & 63;
    const int wid = t >> 6;
    const int wm = wid >> 1;            // 0..3
    const int wn = wid & 1;             // 0..1
    const int lr = lane & 15;
    const int lk = (lane >> 4) * 8;

    f32x4 acc[2][4] = {};

    const int sr = t >> 2;              // 0..127
    const int sk = (t & 3) * 16;        // 0,16,32,48
    const int aRow = m0 + sr;
    const bool aOk = (aRow < M);
    const int rowSafe = aOk ? aRow : 0;
    const int sw = (sr & 7) << 4;

    for (int k0 = 0; k0 < 256; k0 += 64) {
        const unsigned short* src =
            (k0 < 128 ? Aa : Ah) + (size_t)rowSafe * 128 + (k0 & 127) + sk;
        const short8 v0 = *(const short8*)(src);
        const short8 v1 = *(const short8*)(src + 8);
        *(short8*)(As + sr * 128 + ((sk * 2) ^ sw)) = v0;
        *(short8*)(As + sr * 128 + ((sk * 2 + 16) ^ sw)) = v1;
        {
            const int n = t >> 2, kk = (t & 3) * 16;
            const unsigned short* bsrc = Wt + (size_t)n * 256 + k0 + kk;
            const short8 b0 = *(const short8*)(bsrc);
            const short8 b1 = *(const short8*)(bsrc + 8);
            const int bw = (n & 7) << 4;
            *(short8*)(Bs + n * 128 + ((kk * 2) ^ bw)) = b0;
            *(short8*)(Bs + n * 128 + ((kk * 2 + 16) ^ bw)) = b1;
        }
        __syncthreads();
#pragma unroll
        for (int ks = 0; ks < 2; ++ks) {
            short8 a[2], b[4];
#pragma unroll
            for (int mf = 0; mf < 2; ++mf) {
                const int r = wm * 32 + mf * 16 + lr;
                a[mf] = *(const short8*)(As + r * 128 + (((ks * 32 + lk) * 2) ^ ((r & 7) << 4)));
            }
#pragma unroll
            for (int nf = 0; nf < 4; ++nf) {
                const int n = wn * 64 + nf * 16 + lr;
                b[nf] = *(const short8*)(Bs + n * 128 + (((ks * 32 + lk) * 2) ^ ((n & 7) << 4)));
            }
#pragma unroll
            for (int mf = 0; mf < 2; ++mf)
#pragma unroll
                for (int nf = 0; nf < 4; ++nf)
                    acc[mf][nf] = __builtin_amdgcn_mfma_f32_16x16x32_bf16(
                        a[mf], b[nf], acc[mf][nf], 0, 0, 0);
        }
        __syncthreads();
    }

#pragma unroll
    for (int mf = 0; mf < 2; ++mf) {
#pragma unroll
        for (int nf = 0; nf < 4; ++nf) {
            const int n = wn * 64 + nf * 16 + lr;
            const float bb = bias[n];
            const f32x4 v = acc[mf][nf];
#pragma unroll
            for (int j = 0; j < 4; ++j) {
                const int m = m0 + wm * 32 + mf * 16 + (lane >> 4) * 4 + j;
                if (m < M) outX[(size_t)m * 128 + n] = fmaxf(v[j] + bb, 0.f);
            }
        }
    }
}

// ============ agg1: h = bf16(relu(R + gather(P))) ============
__global__ __launch_bounds__(256) void agg_bias_relu(
    const unsigned short* __restrict__ P, const float* __restrict__ R,
    const int* __restrict__ rowptr, const int* __restrict__ csr_row,
    const float* __restrict__ csr_nrm, unsigned short* __restrict__ hout, int N)
{
    const int i = (blockIdx.x * 256 + threadIdx.x) >> 6;
    const int lane = threadIdx.x & 63;
    if (i >= N) return;
    const int beg = rowptr[i];
    const int end = rowptr[i + 1];
    const int c = lane * 2;

    float a0 = 0.f, b0 = 0.f, a1 = 0.f, b1 = 0.f;
    float a2 = 0.f, b2 = 0.f, a3 = 0.f, b3 = 0.f;
    int j = beg;
    for (; j + 3 < end; j += 4) {
        const int r0 = csr_row[j],     r1 = csr_row[j + 1];
        const int r2 = csr_row[j + 2], r3 = csr_row[j + 3];
        const float n0 = csr_nrm[j],     n1 = csr_nrm[j + 1];
        const float n2 = csr_nrm[j + 2], n3 = csr_nrm[j + 3];
        const unsigned int u0 = *(const unsigned int*)&P[(size_t)r0 * 128 + c];
        const unsigned int u1 = *(const unsigned int*)&P[(size_t)r1 * 128 + c];
        const unsigned int u2 = *(const unsigned int*)&P[(size_t)r2 * 128 + c];
        const unsigned int u3 = *(const unsigned int*)&P[(size_t)r3 * 128 + c];
        a0 = fmaf(bflo(u0), n0, a0); b0 = fmaf(bfhi(u0), n0, b0);
        a1 = fmaf(bflo(u1), n1, a1); b1 = fmaf(bfhi(u1), n1, b1);
        a2 = fmaf(bflo(u2), n2, a2); b2 = fmaf(bfhi(u2), n2, b2);
        a3 = fmaf(bflo(u3), n3, a3); b3 = fmaf(bfhi(u3), n3, b3);
    }
    for (; j < end; ++j) {
        const int r0 = csr_row[j];
        const float n0 = csr_nrm[j];
        const unsigned int u0 = *(const unsigned int*)&P[(size_t)r0 * 128 + c];
        a0 = fmaf(bflo(u0), n0, a0); b0 = fmaf(bfhi(u0), n0, b0);
    }
    const float2 r = *(const float2*)&R[(size_t)i * 128 + c];
    const float sx = fmaxf((a0 + a1) + (a2 + a3) + r.x, 0.f);
    const float sy = fmaxf((b0 + b1) + (b2 + b3) + r.y, 0.f);
    const unsigned int o = (unsigned int)f2bf(sx) | ((unsigned int)f2bf(sy) << 16);
    *(unsigned int*)&hout[(size_t)i * 128 + c] = o;
}

// ============ agg2: ah = bf16(gather(h)) ============
__global__ __launch_bounds__(256) void agg_plain(
    const unsigned short* __restrict__ H,
    const int* __restrict__ rowptr, const int* __restrict__ csr_row,
    const float* __restrict__ csr_nrm, unsigned short* __restrict__ ahout, int N)
{
    const int i = (blockIdx.x * 256 + threadIdx.x) >> 6;
    const int lane = threadIdx.x & 63;
    if (i >= N) return;
    const int beg = rowptr[i];
    const int end = rowptr[i + 1];
    const int c = lane * 2;

    float a0 = 0.f, b0 = 0.f, a1 = 0.f, b1 = 0.f;
    float a2 = 0.f, b2 = 0.f, a3 = 0.f, b3 = 0.f;
    int j = beg;
    for (; j + 3 < end; j += 4) {
        const int r0 = csr_row[j],     r1 = csr_row[j + 1];
        const int r2 = csr_row[j + 2], r3 = csr_row[j + 3];
        const float n0 = csr_nrm[j],     n1 = csr_nrm[j + 1];
        const float n2 = csr_nrm[j + 2], n3 = csr_nrm[j + 3];
        const unsigned int u0 = *(const unsigned int*)&H[(size_t)r0 * 128 + c];
        const unsigned int u1 = *(const unsigned int*)&H[(size_t)r1 * 128 + c];
        const unsigned int u2 = *(const unsigned int*)&H[(size_t)r2 * 128 + c];
        const unsigned int u3 = *(const unsigned int*)&H[(size_t)r3 * 128 + c];
        a0 = fmaf(bflo(u0), n0, a0); b0 = fmaf(bfhi(u0), n0, b0);
        a1 = fmaf(bflo(u1), n1, a1); b1 = fmaf(bfhi(u1), n1, b1);
        a2 = fmaf(bflo(u2), n2, a2); b2 = fmaf(bfhi(u2), n2, b2);
        a3 = fmaf(bflo(u3), n3, a3); b3 = fmaf(bfhi(u3), n3, b3);
    }
    for (; j < end; ++j) {
        const int r0 = csr_row[j];
        const float n0 = csr_nrm[j];
        const unsigned int u0 = *(const unsigned int*)&H[(size_t)r0 * 128 + c];
        a0 = fmaf(bflo(u0), n0, a0); b0 = fmaf(bfhi(u0), n0, b0);
    }
    const float sx = (a0 + a1) + (a2 + a3);
    const float sy = (b0 + b1) + (b2 + b3);
    const unsigned int o = (unsigned int)f2bf(sx) | ((unsigned int)f2bf(sy) << 16);
    *(unsigned int*)&ahout[(size_t)i * 128 + c] = o;
}

// ============ fused mean-pool (sorted batch) + head MLP ============
__global__ __launch_bounds__(128) void pool_mlp(
    const float* __restrict__ nx, const int* __restrict__ batch, int N,
    const float* __restrict__ Wl1, const float* __restrict__ bl1,
    const float* __restrict__ Wl2, const float* __restrict__ bl2,
    float* __restrict__ out)
{
    __shared__ float gx[128];
    __shared__ float hid[32];
    __shared__ int rng[2];
    const int g = blockIdx.x;
    const int t = threadIdx.x;
    if (t < 2) {
        const int target = g + t;
        int lo = 0, hi = N;
        while (lo < hi) {
            int mid = (lo + hi) >> 1;
            if (batch[mid] < target) lo = mid + 1; else hi = mid;
        }
        rng[t] = lo;
    }
    __syncthreads();
    const int s = rng[0], e = rng[1];
    float acc = 0.f;
    for (int i = s; i < e; ++i) acc += nx[(size_t)i * 128 + t];
    gx[t] = acc / fmaxf((float)(e - s), 1.f);
    __syncthreads();
    if (t < 32) {
        float a = bl1[t];
#pragma unroll 8
        for (int k = 0; k < 128; ++k) a = fmaf(gx[k], Wl1[k * 32 + t], a);
        hid[t] = a > 0.f ? a : expm1f(a);
    }
    __syncthreads();
    if (t < 2) {
        float a = bl2[t];
#pragma unroll
        for (int k = 0; k < 32; ++k) a = fmaf(hid[k], Wl2[k * 2 + t], a);
        out[(size_t)g * 2 + t] = a;
    }
}

extern "C" void kernel_launch(void* const* d_in, const int* in_sizes, int n_in,
                              void* d_out, int out_size, void* d_ws, size_t ws_size,
                              hipStream_t stream)
{
    const float* x     = (const float*)d_in[0];
    const int*   ei    = (const int*)d_in[1];
    const float* ea    = (const float*)d_in[2];
    const int*   batch = (const int*)d_in[3];
    const float* W1i   = (const float*)d_in[5];
    const float* W1r   = (const float*)d_in[6];
    const float* b1    = (const float*)d_in[7];
    const float* W2i   = (const float*)d_in[8];
    const float* W2r   = (const float*)d_in[9];
    const float* b2    = (const float*)d_in[10];
    const float* Wl1   = (const float*)d_in[11];
    const float* bl1   = (const float*)d_in[12];
    const float* Wl2   = (const float*)d_in[13];
    const float* bl2   = (const float*)d_in[14];

    const int N = in_sizes[0] / 768;
    const int E = in_sizes[2];
    const int G = out_size / 2;

    char* ws = (char*)d_ws;
    size_t off = 0;
    auto alloc = [&](size_t bytes) -> char* {
        char* p = ws + off;
        off = (off + bytes + 255) & ~(size_t)255;
        return p;
    };
    float* deg     = (float*)alloc((size_t)N * 4);
    int*   cnt     = (int*)alloc((size_t)N * 4);
    int*   rowptr  = (int*)alloc((size_t)(N + 1) * 4);
    int*   wp      = (int*)alloc((size_t)N * 4);
    int*   blkoff  = (int*)alloc((size_t)1056 * 4);
    int*   blkdum  = (int*)alloc((size_t)4 * 4);
    int*   csr_row = (int*)alloc((size_t)E * 4);
    float* csr_nrm = (float*)alloc((size_t)E * 4);
    unsigned short* P1  = (unsigned short*)alloc((size_t)N * 128 * 2);
    unsigned short* hbf = (unsigned short*)alloc((size_t)N * 128 * 2);
    unsigned short* ahb = (unsigned short*)alloc((size_t)N * 128 * 2);
    float* R1   = (float*)alloc((size_t)N * 128 * 4);
    float* bufB = (float*)alloc((size_t)N * 128 * 4);
    unsigned short* W1t = (unsigned short*)alloc((size_t)256 * 768 * 2);
    unsigned short* W2t = (unsigned short*)alloc((size_t)128 * 256 * 2);

    const int eBlocks = (E + 255) / 256;
    const int nb      = (N + 1023) / 1024;
    const int nBlocks = (N + 255) / 256;

    // ---- CSR build + weight convert ----
    hipMemsetAsync(deg, 0, (size_t)N * 4, stream);
    hipMemsetAsync(cnt, 0, (size_t)N * 4, stream);
    deg_hist_kernel<<<eBlocks, 256, 0, stream>>>(ei, ea, deg, cnt, E);
    scan1_kernel<<<nb, 256, 0, stream>>>(cnt, rowptr, blkoff, N);
    scan1_kernel<<<1, 256, 0, stream>>>(blkoff, blkoff, blkdum, nb);
    scan3_kernel<<<nBlocks, 256, 0, stream>>>(rowptr, blkoff, wp, N, E);
    place_kernel<<<eBlocks, 256, 0, stream>>>(ei, ea, deg, wp, csr_row, csr_nrm, E);
    conv_weights<<<(256 * 768 + 128 * 256 + 255) / 256, 256, 0, stream>>>(
        W1i, W1r, W2i, W2r, W1t, W2t);

    // ---- layer 1: P1 = bf16(x@W1i), R1 = x@W1r + b1 ----
    gemm_mfma_dual<<<(N + 63) / 64, 512, 0, stream>>>(x, W1t, b1, P1, R1, N, 768);
    // h = bf16(relu(R1 + gather(P1)))   (elu(relu(.)) == relu(.))
    agg_bias_relu<<<(N * 64 + 255) / 256, 256, 0, stream>>>(
        P1, R1, rowptr, csr_row, csr_nrm, hbf, N);

    // ---- layer 2: ah = bf16(gather(h)); node_x = relu([ah|h]@[W2i;W2r] + b2) ----
    agg_plain<<<(N * 64 + 255) / 256, 256, 0, stream>>>(
        hbf, rowptr, csr_row, csr_nrm, ahb, N);
    gemm_mfma_single<<<(N + 127) / 128, 512, 0, stream>>>(ahb, hbf, W2t, b2, bufB, N);

    // ---- fused pool + head ----
    pool_mlp<<<G, 128, 0, stream>>>(bufB, batch, N, Wl1, bl1, Wl2, bl2, (float*)d_out);
}

// Round 6
// 546.282 us; speedup vs baseline: 11.6597x; 1.1060x over previous
//
#include <hip/hip_runtime.h>
#include <hip/hip_bf16.h>
#include <math.h>

typedef __attribute__((ext_vector_type(8))) short short8;
typedef __attribute__((ext_vector_type(4))) float f32x4;

__device__ __forceinline__ unsigned short f2bf(float f) {
    unsigned int u = __builtin_bit_cast(unsigned int, f);
    return (unsigned short)((u + 0x7fffu + ((u >> 16) & 1u)) >> 16);   // RNE
}
__device__ __forceinline__ float b2f(short s) {
    return __builtin_bit_cast(float, ((unsigned int)(unsigned short)s) << 16);
}

// ============ degree + histogram ============
__global__ __launch_bounds__(256) void deg_hist_kernel(
    const int* __restrict__ ei, const float* __restrict__ ea,
    float* __restrict__ deg, int* __restrict__ cnt, int E)
{
    int e = blockIdx.x * 256 + threadIdx.x;
    if (e >= E) return;
    int c = ei[(size_t)E + e];
    atomicAdd(&deg[c], ea[e]);
    atomicAdd(&cnt[c], 1);
}

// ============ hierarchical exclusive scan ============
__global__ __launch_bounds__(256) void scan1_kernel(
    const int* __restrict__ in, int* __restrict__ out, int* __restrict__ blksum, int n)
{
    __shared__ int part[256];
    const int t = threadIdx.x;
    const int base = blockIdx.x * 1024 + t * 4;
    int v[4];
#pragma unroll
    for (int q = 0; q < 4; ++q) v[q] = (base + q < n) ? in[base + q] : 0;
    const int s = v[0] + v[1] + v[2] + v[3];
    part[t] = s;
    __syncthreads();
    for (int off = 1; off < 256; off <<= 1) {
        int x = (t >= off) ? part[t - off] : 0;
        __syncthreads();
        part[t] += x;
        __syncthreads();
    }
    if (t == 255) blksum[blockIdx.x] = part[255];
    int run = part[t] - s;
#pragma unroll
    for (int q = 0; q < 4; ++q) {
        if (base + q < n) out[base + q] = run;
        run += v[q];
    }
}

__global__ __launch_bounds__(256) void scan3_kernel(
    int* __restrict__ rowptr, const int* __restrict__ blkoff,
    int* __restrict__ wp, int n, int Etot)
{
    int i = blockIdx.x * 256 + threadIdx.x;
    if (i == 0) rowptr[n] = Etot;
    if (i >= n) return;
    int v = rowptr[i] + blkoff[i >> 10];
    rowptr[i] = v;
    wp[i] = v;
}

// ============ edge placement: csr[p] = {row, nrm} ============
__global__ __launch_bounds__(256) void place_kernel(
    const int* __restrict__ ei, const float* __restrict__ ea,
    const float* __restrict__ deg, int* __restrict__ wp,
    int2* __restrict__ csr, int E)
{
    int e = blockIdx.x * 256 + threadIdx.x;
    if (e >= E) return;
    int r = ei[e];
    int c = ei[(size_t)E + e];
    float dr = deg[r], dc = deg[c];
    float nm = (dr > 0.f ? rsqrtf(dr) : 0.f) * ea[e] * (dc > 0.f ? rsqrtf(dc) : 0.f);
    int p = atomicAdd(&wp[c], 1);
    int2 rec;
    rec.x = r;
    rec.y = __builtin_bit_cast(int, nm);
    csr[p] = rec;
}

// ============ weight pre-convert ============
// W1t: 256 x 768 (n<128 -> W1i, else W1r), W2t: 128 x 256 (k<128 -> W2i, else W2r)
__global__ __launch_bounds__(256) void conv_weights(
    const float* __restrict__ W1i, const float* __restrict__ W1r,
    const float* __restrict__ W2i, const float* __restrict__ W2r,
    unsigned short* __restrict__ W1t, unsigned short* __restrict__ W2t)
{
    int id = blockIdx.x * 256 + threadIdx.x;
    if (id < 256 * 768) {
        int n = id / 768, k = id % 768;
        float v = (n < 128) ? W1i[k * 128 + n] : W1r[k * 128 + (n - 128)];
        W1t[id] = f2bf(v);
    } else {
        int id2 = id - 256 * 768;
        if (id2 < 128 * 256) {
            int n = id2 >> 8, k = id2 & 255;
            float v = (k < 128) ? W2i[k * 128 + n] : W2r[(k - 128) * 128 + n];
            W2t[id2] = f2bf(v);
        }
    }
}

// ============ MFMA dual GEMM (layer 1) ============
// A: M x K fp32. Wt: 256 x K bf16. outP bf16 = A@Wi ; outR bf16 = A@Wr + bias.
__global__ __launch_bounds__(512) void gemm_mfma_dual(
    const float* __restrict__ A, const unsigned short* __restrict__ Wt,
    const float* __restrict__ bias, unsigned short* __restrict__ outP,
    unsigned short* __restrict__ outR, int M, int K)
{
    __shared__ __align__(16) unsigned char As[64 * 128];
    __shared__ __align__(16) unsigned char Bs[256 * 128];

    const int t = threadIdx.x;
    const int m0 = blockIdx.x * 64;
    const int lane = t & 63;
    const int wid = t >> 6;
    const int wm = wid >> 2;
    const int wn = wid & 3;
    const int lr = lane & 15;
    const int lk = (lane >> 4) * 8;

    f32x4 acc[2][4] = {};

    const int sr = t >> 3;
    const int sk = (t & 7) * 8;
    const int aRow = m0 + sr;
    const bool aOk = (aRow < M);
    const float* aSrc = A + (size_t)(aOk ? aRow : 0) * K + sk;
    const int aDst = sr * 128 + ((sk * 2) ^ ((sr & 7) << 4));

    for (int k0 = 0; k0 < K; k0 += 64) {
        short8 av = {};
        if (aOk) {
            const float4 f0 = *(const float4*)(aSrc + k0);
            const float4 f1 = *(const float4*)(aSrc + k0 + 4);
            av[0] = (short)f2bf(f0.x); av[1] = (short)f2bf(f0.y);
            av[2] = (short)f2bf(f0.z); av[3] = (short)f2bf(f0.w);
            av[4] = (short)f2bf(f1.x); av[5] = (short)f2bf(f1.y);
            av[6] = (short)f2bf(f1.z); av[7] = (short)f2bf(f1.w);
        }
        *(short8*)(As + aDst) = av;
#pragma unroll
        for (int i = 0; i < 4; ++i) {
            const int idx = t + i * 512;
            const int n = idx >> 3, kk = (idx & 7) * 8;
            const short8 bv = *(const short8*)(Wt + (size_t)n * K + k0 + kk);
            *(short8*)(Bs + n * 128 + ((kk * 2) ^ ((n & 7) << 4))) = bv;
        }
        __syncthreads();
#pragma unroll
        for (int ks = 0; ks < 2; ++ks) {
            short8 a[2], b[4];
#pragma unroll
            for (int mf = 0; mf < 2; ++mf) {
                const int r = wm * 32 + mf * 16 + lr;
                a[mf] = *(const short8*)(As + r * 128 + (((ks * 32 + lk) * 2) ^ ((r & 7) << 4)));
            }
#pragma unroll
            for (int nf = 0; nf < 4; ++nf) {
                const int n = wn * 64 + nf * 16 + lr;
                b[nf] = *(const short8*)(Bs + n * 128 + (((ks * 32 + lk) * 2) ^ ((n & 7) << 4)));
            }
#pragma unroll
            for (int mf = 0; mf < 2; ++mf)
#pragma unroll
                for (int nf = 0; nf < 4; ++nf)
                    acc[mf][nf] = __builtin_amdgcn_mfma_f32_16x16x32_bf16(
                        a[mf], b[nf], acc[mf][nf], 0, 0, 0);
        }
        __syncthreads();
    }

#pragma unroll
    for (int mf = 0; mf < 2; ++mf) {
#pragma unroll
        for (int nf = 0; nf < 4; ++nf) {
            const int n = wn * 64 + nf * 16 + lr;
            const f32x4 v = acc[mf][nf];
            if (n < 128) {
#pragma unroll
                for (int j = 0; j < 4; ++j) {
                    const int m = m0 + wm * 32 + mf * 16 + (lane >> 4) * 4 + j;
                    if (m < M) outP[(size_t)m * 128 + n] = f2bf(v[j]);
                }
            } else {
                const int nl = n - 128;
                const float badd = bias[nl];
#pragma unroll
                for (int j = 0; j < 4; ++j) {
                    const int m = m0 + wm * 32 + mf * 16 + (lane >> 4) * 4 + j;
                    if (m < M) outR[(size_t)m * 128 + nl] = f2bf(v[j] + badd);
                }
            }
        }
    }
}

// ============ MFMA single GEMM (layer 2, K=256 over [ah|h]) + bias + ReLU ============
__global__ __launch_bounds__(512) void gemm_mfma_single(
    const unsigned short* __restrict__ Aa,   // ah : k in [0,128)
    const unsigned short* __restrict__ Ah,   // h  : k in [128,256)
    const unsigned short* __restrict__ Wt,   // 128 x 256
    const float* __restrict__ bias,
    float* __restrict__ outX, int M)
{
    __shared__ __align__(16) unsigned char As[128 * 128];
    __shared__ __align__(16) unsigned char Bs[128 * 128];

    const int t = threadIdx.x;
    const int m0 = blockIdx.x * 128;
    const int lane = t & 63;
    const int wid = t >> 6;
    const int wm = wid >> 1;
    const int wn = wid & 1;
    const int lr = lane & 15;
    const int lk = (lane >> 4) * 8;

    f32x4 acc[2][4] = {};

    const int sr = t >> 2;
    const int sk = (t & 3) * 16;
    const int aRow = m0 + sr;
    const bool aOk = (aRow < M);
    const int rowSafe = aOk ? aRow : 0;
    const int sw = (sr & 7) << 4;

    for (int k0 = 0; k0 < 256; k0 += 64) {
        const unsigned short* src =
            (k0 < 128 ? Aa : Ah) + (size_t)rowSafe * 128 + (k0 & 127) + sk;
        const short8 v0 = *(const short8*)(src);
        const short8 v1 = *(const short8*)(src + 8);
        *(short8*)(As + sr * 128 + ((sk * 2) ^ sw)) = v0;
        *(short8*)(As + sr * 128 + ((sk * 2 + 16) ^ sw)) = v1;
        {
            const int n = t >> 2, kk = (t & 3) * 16;
            const unsigned short* bsrc = Wt + (size_t)n * 256 + k0 + kk;
            const short8 b0 = *(const short8*)(bsrc);
            const short8 b1 = *(const short8*)(bsrc + 8);
            const int bw = (n & 7) << 4;
            *(short8*)(Bs + n * 128 + ((kk * 2) ^ bw)) = b0;
            *(short8*)(Bs + n * 128 + ((kk * 2 + 16) ^ bw)) = b1;
        }
        __syncthreads();
#pragma unroll
        for (int ks = 0; ks < 2; ++ks) {
            short8 a[2], b[4];
#pragma unroll
            for (int mf = 0; mf < 2; ++mf) {
                const int r = wm * 32 + mf * 16 + lr;
                a[mf] = *(const short8*)(As + r * 128 + (((ks * 32 + lk) * 2) ^ ((r & 7) << 4)));
            }
#pragma unroll
            for (int nf = 0; nf < 4; ++nf) {
                const int n = wn * 64 + nf * 16 + lr;
                b[nf] = *(const short8*)(Bs + n * 128 + (((ks * 32 + lk) * 2) ^ ((n & 7) << 4)));
            }
#pragma unroll
            for (int mf = 0; mf < 2; ++mf)
#pragma unroll
                for (int nf = 0; nf < 4; ++nf)
                    acc[mf][nf] = __builtin_amdgcn_mfma_f32_16x16x32_bf16(
                        a[mf], b[nf], acc[mf][nf], 0, 0, 0);
        }
        __syncthreads();
    }

#pragma unroll
    for (int mf = 0; mf < 2; ++mf) {
#pragma unroll
        for (int nf = 0; nf < 4; ++nf) {
            const int n = wn * 64 + nf * 16 + lr;
            const float bb = bias[n];
            const f32x4 v = acc[mf][nf];
#pragma unroll
            for (int j = 0; j < 4; ++j) {
                const int m = m0 + wm * 32 + mf * 16 + (lane >> 4) * 4 + j;
                if (m < M) outX[(size_t)m * 128 + n] = fmaxf(v[j] + bb, 0.f);
            }
        }
    }
}

// ============ agg1: h = bf16(relu(R + gather(P))) ============
// 16 lanes per node (bf16x8 per lane), 4 nodes per wave, 2-edge unroll.
__global__ __launch_bounds__(256) void agg_bias_relu(
    const unsigned short* __restrict__ P, const unsigned short* __restrict__ Rbf,
    const int* __restrict__ rowptr, const int2* __restrict__ csr,
    unsigned short* __restrict__ hout, int N)
{
    const int i = blockIdx.x * 16 + (threadIdx.x >> 4);
    const int l = threadIdx.x & 15;
    if (i >= N) return;
    const int beg = rowptr[i];
    const int end = rowptr[i + 1];
    const int c = l * 8;

    float acc0[8] = {0.f, 0.f, 0.f, 0.f, 0.f, 0.f, 0.f, 0.f};
    float acc1[8] = {0.f, 0.f, 0.f, 0.f, 0.f, 0.f, 0.f, 0.f};
    int j = beg;
    for (; j + 1 < end; j += 2) {
        const int2 e0 = csr[j];
        const int2 e1 = csr[j + 1];
        const short8 v0 = *(const short8*)(P + (size_t)e0.x * 128 + c);
        const short8 v1 = *(const short8*)(P + (size_t)e1.x * 128 + c);
        const float n0 = __builtin_bit_cast(float, e0.y);
        const float n1 = __builtin_bit_cast(float, e1.y);
#pragma unroll
        for (int q = 0; q < 8; ++q) {
            acc0[q] = fmaf(b2f(v0[q]), n0, acc0[q]);
            acc1[q] = fmaf(b2f(v1[q]), n1, acc1[q]);
        }
    }
    if (j < end) {
        const int2 e0 = csr[j];
        const short8 v0 = *(const short8*)(P + (size_t)e0.x * 128 + c);
        const float n0 = __builtin_bit_cast(float, e0.y);
#pragma unroll
        for (int q = 0; q < 8; ++q) acc0[q] = fmaf(b2f(v0[q]), n0, acc0[q]);
    }
    const short8 rv = *(const short8*)(Rbf + (size_t)i * 128 + c);
    short8 ov;
#pragma unroll
    for (int q = 0; q < 8; ++q)
        ov[q] = (short)f2bf(fmaxf(acc0[q] + acc1[q] + b2f(rv[q]), 0.f));
    *(short8*)(hout + (size_t)i * 128 + c) = ov;
}

// ============ agg2: ah = bf16(gather(h)) ============
__global__ __launch_bounds__(256) void agg_plain(
    const unsigned short* __restrict__ H,
    const int* __restrict__ rowptr, const int2* __restrict__ csr,
    unsigned short* __restrict__ ahout, int N)
{
    const int i = blockIdx.x * 16 + (threadIdx.x >> 4);
    const int l = threadIdx.x & 15;
    if (i >= N) return;
    const int beg = rowptr[i];
    const int end = rowptr[i + 1];
    const int c = l * 8;

    float acc0[8] = {0.f, 0.f, 0.f, 0.f, 0.f, 0.f, 0.f, 0.f};
    float acc1[8] = {0.f, 0.f, 0.f, 0.f, 0.f, 0.f, 0.f, 0.f};
    int j = beg;
    for (; j + 1 < end; j += 2) {
        const int2 e0 = csr[j];
        const int2 e1 = csr[j + 1];
        const short8 v0 = *(const short8*)(H + (size_t)e0.x * 128 + c);
        const short8 v1 = *(const short8*)(H + (size_t)e1.x * 128 + c);
        const float n0 = __builtin_bit_cast(float, e0.y);
        const float n1 = __builtin_bit_cast(float, e1.y);
#pragma unroll
        for (int q = 0; q < 8; ++q) {
            acc0[q] = fmaf(b2f(v0[q]), n0, acc0[q]);
            acc1[q] = fmaf(b2f(v1[q]), n1, acc1[q]);
        }
    }
    if (j < end) {
        const int2 e0 = csr[j];
        const short8 v0 = *(const short8*)(H + (size_t)e0.x * 128 + c);
        const float n0 = __builtin_bit_cast(float, e0.y);
#pragma unroll
        for (int q = 0; q < 8; ++q) acc0[q] = fmaf(b2f(v0[q]), n0, acc0[q]);
    }
    short8 ov;
#pragma unroll
    for (int q = 0; q < 8; ++q)
        ov[q] = (short)f2bf(acc0[q] + acc1[q]);
    *(short8*)(ahout + (size_t)i * 128 + c) = ov;
}

// ============ fused mean-pool (sorted batch) + head MLP ============
__global__ __launch_bounds__(128) void pool_mlp(
    const float* __restrict__ nx, const int* __restrict__ batch, int N,
    const float* __restrict__ Wl1, const float* __restrict__ bl1,
    const float* __restrict__ Wl2, const float* __restrict__ bl2,
    float* __restrict__ out)
{
    __shared__ float gx[128];
    __shared__ float hid[32];
    __shared__ int rng[2];
    const int g = blockIdx.x;
    const int t = threadIdx.x;
    if (t < 2) {
        const int target = g + t;
        int lo = 0, hi = N;
        while (lo < hi) {
            int mid = (lo + hi) >> 1;
            if (batch[mid] < target) lo = mid + 1; else hi = mid;
        }
        rng[t] = lo;
    }
    __syncthreads();
    const int s = rng[0], e = rng[1];
    float acc = 0.f;
    for (int i = s; i < e; ++i) acc += nx[(size_t)i * 128 + t];
    gx[t] = acc / fmaxf((float)(e - s), 1.f);
    __syncthreads();
    if (t < 32) {
        float a = bl1[t];
#pragma unroll 8
        for (int k = 0; k < 128; ++k) a = fmaf(gx[k], Wl1[k * 32 + t], a);
        hid[t] = a > 0.f ? a : expm1f(a);
    }
    __syncthreads();
    if (t < 2) {
        float a = bl2[t];
#pragma unroll
        for (int k = 0; k < 32; ++k) a = fmaf(hid[k], Wl2[k * 2 + t], a);
        out[(size_t)g * 2 + t] = a;
    }
}

extern "C" void kernel_launch(void* const* d_in, const int* in_sizes, int n_in,
                              void* d_out, int out_size, void* d_ws, size_t ws_size,
                              hipStream_t stream)
{
    const float* x     = (const float*)d_in[0];
    const int*   ei    = (const int*)d_in[1];
    const float* ea    = (const float*)d_in[2];
    const int*   batch = (const int*)d_in[3];
    const float* W1i   = (const float*)d_in[5];
    const float* W1r   = (const float*)d_in[6];
    const float* b1    = (const float*)d_in[7];
    const float* W2i   = (const float*)d_in[8];
    const float* W2r   = (const float*)d_in[9];
    const float* b2    = (const float*)d_in[10];
    const float* Wl1   = (const float*)d_in[11];
    const float* bl1   = (const float*)d_in[12];
    const float* Wl2   = (const float*)d_in[13];
    const float* bl2   = (const float*)d_in[14];

    const int N = in_sizes[0] / 768;
    const int E = in_sizes[2];
    const int G = out_size / 2;

    char* ws = (char*)d_ws;
    size_t off = 0;
    auto alloc = [&](size_t bytes) -> char* {
        char* p = ws + off;
        off = (off + bytes + 255) & ~(size_t)255;
        return p;
    };
    float* deg     = (float*)alloc((size_t)N * 4);
    int*   cnt     = (int*)alloc((size_t)N * 4);
    int*   rowptr  = (int*)alloc((size_t)(N + 1) * 4);
    int*   wp      = (int*)alloc((size_t)N * 4);
    int*   blkoff  = (int*)alloc((size_t)1056 * 4);
    int*   blkdum  = (int*)alloc((size_t)4 * 4);
    int2*  csr     = (int2*)alloc((size_t)E * 8);
    unsigned short* P1  = (unsigned short*)alloc((size_t)N * 128 * 2);
    unsigned short* R1  = (unsigned short*)alloc((size_t)N * 128 * 2);
    unsigned short* hbf = (unsigned short*)alloc((size_t)N * 128 * 2);
    unsigned short* ahb = (unsigned short*)alloc((size_t)N * 128 * 2);
    float* bufB = (float*)alloc((size_t)N * 128 * 4);
    unsigned short* W1t = (unsigned short*)alloc((size_t)256 * 768 * 2);
    unsigned short* W2t = (unsigned short*)alloc((size_t)128 * 256 * 2);

    const int eBlocks = (E + 255) / 256;
    const int nb      = (N + 1023) / 1024;
    const int nBlocks = (N + 255) / 256;
    const int aBlocks = (N + 15) / 16;

    // ---- CSR build + weight convert ----
    hipMemsetAsync(deg, 0, (size_t)N * 4, stream);
    hipMemsetAsync(cnt, 0, (size_t)N * 4, stream);
    deg_hist_kernel<<<eBlocks, 256, 0, stream>>>(ei, ea, deg, cnt, E);
    scan1_kernel<<<nb, 256, 0, stream>>>(cnt, rowptr, blkoff, N);
    scan1_kernel<<<1, 256, 0, stream>>>(blkoff, blkoff, blkdum, nb);
    scan3_kernel<<<nBlocks, 256, 0, stream>>>(rowptr, blkoff, wp, N, E);
    place_kernel<<<eBlocks, 256, 0, stream>>>(ei, ea, deg, wp, csr, E);
    conv_weights<<<(256 * 768 + 128 * 256 + 255) / 256, 256, 0, stream>>>(
        W1i, W1r, W2i, W2r, W1t, W2t);

    // ---- layer 1: P1 = bf16(x@W1i), R1 = bf16(x@W1r + b1) ----
    gemm_mfma_dual<<<(N + 63) / 64, 512, 0, stream>>>(x, W1t, b1, P1, R1, N, 768);
    agg_bias_relu<<<aBlocks, 256, 0, stream>>>(P1, R1, rowptr, csr, hbf, N);

    // ---- layer 2: ah = bf16(gather(h)); node_x = relu([ah|h]@[W2i;W2r] + b2) ----
    agg_plain<<<aBlocks, 256, 0, stream>>>(hbf, rowptr, csr, ahb, N);
    gemm_mfma_single<<<(N + 127) / 128, 512, 0, stream>>>(ahb, hbf, W2t, b2, bufB, N);

    // ---- fused pool + head ----
    pool_mlp<<<G, 128, 0, stream>>>(bufB, batch, N, Wl1, bl1, Wl2, bl2, (float*)d_out);
}

// Round 7
// 538.146 us; speedup vs baseline: 11.8359x; 1.0151x over previous
//
#include <hip/hip_runtime.h>
#include <hip/hip_bf16.h>
#include <math.h>

typedef __attribute__((ext_vector_type(8))) short short8;
typedef __attribute__((ext_vector_type(4))) float f32x4;
typedef __attribute__((address_space(1))) const void gvoid;
typedef __attribute__((address_space(3))) void lvoid;

__device__ __forceinline__ unsigned short f2bf(float f) {
    unsigned int u = __builtin_bit_cast(unsigned int, f);
    return (unsigned short)((u + 0x7fffu + ((u >> 16) & 1u)) >> 16);   // RNE
}
__device__ __forceinline__ float b2f(short s) {
    return __builtin_bit_cast(float, ((unsigned int)(unsigned short)s) << 16);
}
__device__ __forceinline__ unsigned int cvtpk(float lo, float hi) {
    unsigned int r;
    asm("v_cvt_pk_bf16_f32 %0, %1, %2" : "=v"(r) : "v"(lo), "v"(hi));
    return r;
}

// ============ degree + histogram ============
__global__ __launch_bounds__(256) void deg_hist_kernel(
    const int* __restrict__ ei, const float* __restrict__ ea,
    float* __restrict__ deg, int* __restrict__ cnt, int E)
{
    int e = blockIdx.x * 256 + threadIdx.x;
    if (e >= E) return;
    int c = ei[(size_t)E + e];
    atomicAdd(&deg[c], ea[e]);
    atomicAdd(&cnt[c], 1);
}

// ============ hierarchical exclusive scan ============
__global__ __launch_bounds__(256) void scan1_kernel(
    const int* __restrict__ in, int* __restrict__ out, int* __restrict__ blksum, int n)
{
    __shared__ int part[256];
    const int t = threadIdx.x;
    const int base = blockIdx.x * 1024 + t * 4;
    int v[4];
#pragma unroll
    for (int q = 0; q < 4; ++q) v[q] = (base + q < n) ? in[base + q] : 0;
    const int s = v[0] + v[1] + v[2] + v[3];
    part[t] = s;
    __syncthreads();
    for (int off = 1; off < 256; off <<= 1) {
        int x = (t >= off) ? part[t - off] : 0;
        __syncthreads();
        part[t] += x;
        __syncthreads();
    }
    if (t == 255) blksum[blockIdx.x] = part[255];
    int run = part[t] - s;
#pragma unroll
    for (int q = 0; q < 4; ++q) {
        if (base + q < n) out[base + q] = run;
        run += v[q];
    }
}

__global__ __launch_bounds__(256) void scan3_kernel(
    int* __restrict__ rowptr, const int* __restrict__ blkoff,
    int* __restrict__ wp, int n, int Etot)
{
    int i = blockIdx.x * 256 + threadIdx.x;
    if (i == 0) rowptr[n] = Etot;
    if (i >= n) return;
    int v = rowptr[i] + blkoff[i >> 10];
    rowptr[i] = v;
    wp[i] = v;
}

// ============ edge placement: csr[p] = {row, nrm} ============
__global__ __launch_bounds__(256) void place_kernel(
    const int* __restrict__ ei, const float* __restrict__ ea,
    const float* __restrict__ deg, int* __restrict__ wp,
    int2* __restrict__ csr, int E)
{
    int e = blockIdx.x * 256 + threadIdx.x;
    if (e >= E) return;
    int r = ei[e];
    int c = ei[(size_t)E + e];
    float dr = deg[r], dc = deg[c];
    float nm = (dr > 0.f ? rsqrtf(dr) : 0.f) * ea[e] * (dc > 0.f ? rsqrtf(dc) : 0.f);
    int p = atomicAdd(&wp[c], 1);
    int2 rec;
    rec.x = r;
    rec.y = __builtin_bit_cast(int, nm);
    csr[p] = rec;
}

// ============ weight pre-convert, PRE-SWIZZLED for global_load_lds ============
// Stored so a LINEAR global->LDS DMA produces the XOR-swizzled LDS layout the
// GEMM fragment reads expect (G21: inverse-swizzle the source).
// W1t[n][j]: j = win*64 + sl*8 + el holds orig k = win*64 + (sl^(n&7))*8 + el.
__global__ __launch_bounds__(256) void conv_weights(
    const float* __restrict__ W1i, const float* __restrict__ W1r,
    const float* __restrict__ W2i, const float* __restrict__ W2r,
    unsigned short* __restrict__ W1t, unsigned short* __restrict__ W2t)
{
    int id = blockIdx.x * 256 + threadIdx.x;
    if (id < 256 * 768) {
        int n = id / 768, j = id % 768;
        int k = (j & ~63) | ((((j >> 3) & 7) ^ (n & 7)) << 3) | (j & 7);
        float v = (n < 128) ? W1i[k * 128 + n] : W1r[k * 128 + (n - 128)];
        W1t[id] = f2bf(v);
    } else {
        int id2 = id - 256 * 768;
        if (id2 < 128 * 256) {
            int n = id2 >> 8, j = id2 & 255;
            int k = (j & ~63) | ((((j >> 3) & 7) ^ (n & 7)) << 3) | (j & 7);
            float v = (k < 128) ? W2i[k * 128 + n] : W2r[(k - 128) * 128 + n];
            W2t[id2] = f2bf(v);
        }
    }
}

// ============ MFMA dual GEMM (layer 1) ============
// A: M x K fp32. Wt: 256 x K bf16 PRE-SWIZZLED. outP/outR bf16.
// 512 thr, 8 waves (2M x 4N), tile 64 x 256, BK=64.
// B staged via global_load_lds (pure DMA); A reg-staged with v_cvt_pk_bf16_f32.
__global__ __launch_bounds__(512) void gemm_mfma_dual(
    const float* __restrict__ A, const unsigned short* __restrict__ Wt,
    const float* __restrict__ bias, unsigned short* __restrict__ outP,
    unsigned short* __restrict__ outR, int M, int K)
{
    __shared__ __align__(16) unsigned char As[64 * 128];    // 64 x 64 bf16
    __shared__ __align__(16) unsigned char Bs[256 * 128];   // 256 x 64 bf16

    const int t = threadIdx.x;
    const int m0 = blockIdx.x * 64;
    const int lane = t & 63;
    const int wid = t >> 6;
    const int wm = wid >> 2;
    const int wn = wid & 3;
    const int lr = lane & 15;
    const int lk = (lane >> 4) * 8;

    f32x4 acc[2][4] = {};

    const int sr = t >> 3;
    const int sk = (t & 7) * 8;
    const int aRow = m0 + sr;
    const bool aOk = (aRow < M);
    const float* aSrc = A + (size_t)(aOk ? aRow : 0) * K + sk;
    const int aDst = sr * 128 + ((sk * 2) ^ ((sr & 7) << 4));
    // B DMA source: lane covers row n = chunk*8 + (lane>>3), 16B at (lane&7)*8
    const unsigned short* bSrc = Wt + (size_t)(lane >> 3) * K + (lane & 7) * 8;

    for (int k0 = 0; k0 < K; k0 += 64) {
        // ---- B: 4 x global_load_lds (1KB per wave each) ----
#pragma unroll
        for (int i = 0; i < 4; ++i) {
            const int chunk = i * 8 + wid;
            __builtin_amdgcn_global_load_lds(
                (gvoid*)(bSrc + (size_t)chunk * 8 * K + k0),
                (lvoid*)(Bs + chunk * 1024), 16, 0, 0);
        }
        // ---- A: fp32 -> bf16 via cvt_pk ----
        unsigned int p0 = 0, p1 = 0, p2 = 0, p3 = 0;
        if (aOk) {
            const float4 f0 = *(const float4*)(aSrc + k0);
            const float4 f1 = *(const float4*)(aSrc + k0 + 4);
            p0 = cvtpk(f0.x, f0.y);
            p1 = cvtpk(f0.z, f0.w);
            p2 = cvtpk(f1.x, f1.y);
            p3 = cvtpk(f1.z, f1.w);
        }
        uint4 uv = {p0, p1, p2, p3};
        *(uint4*)(As + aDst) = uv;
        __syncthreads();
#pragma unroll
        for (int ks = 0; ks < 2; ++ks) {
            short8 a[2], b[4];
#pragma unroll
            for (int mf = 0; mf < 2; ++mf) {
                const int r = wm * 32 + mf * 16 + lr;
                a[mf] = *(const short8*)(As + r * 128 + (((ks * 32 + lk) * 2) ^ ((r & 7) << 4)));
            }
#pragma unroll
            for (int nf = 0; nf < 4; ++nf) {
                const int n = wn * 64 + nf * 16 + lr;
                b[nf] = *(const short8*)(Bs + n * 128 + (((ks * 32 + lk) * 2) ^ ((n & 7) << 4)));
            }
#pragma unroll
            for (int mf = 0; mf < 2; ++mf)
#pragma unroll
                for (int nf = 0; nf < 4; ++nf)
                    acc[mf][nf] = __builtin_amdgcn_mfma_f32_16x16x32_bf16(
                        a[mf], b[nf], acc[mf][nf], 0, 0, 0);
        }
        __syncthreads();
    }

#pragma unroll
    for (int mf = 0; mf < 2; ++mf) {
#pragma unroll
        for (int nf = 0; nf < 4; ++nf) {
            const int n = wn * 64 + nf * 16 + lr;
            const f32x4 v = acc[mf][nf];
            if (n < 128) {
#pragma unroll
                for (int j = 0; j < 4; ++j) {
                    const int m = m0 + wm * 32 + mf * 16 + (lane >> 4) * 4 + j;
                    if (m < M) outP[(size_t)m * 128 + n] = f2bf(v[j]);
                }
            } else {
                const int nl = n - 128;
                const float badd = bias[nl];
#pragma unroll
                for (int j = 0; j < 4; ++j) {
                    const int m = m0 + wm * 32 + mf * 16 + (lane >> 4) * 4 + j;
                    if (m < M) outR[(size_t)m * 128 + nl] = f2bf(v[j] + badd);
                }
            }
        }
    }
}

// ============ MFMA single GEMM (layer 2, K=256 over [ah|h]) + bias + ReLU ============
// Output bf16. W2t pre-swizzled, B staged via global_load_lds.
__global__ __launch_bounds__(512) void gemm_mfma_single(
    const unsigned short* __restrict__ Aa,   // ah : k in [0,128)
    const unsigned short* __restrict__ Ah,   // h  : k in [128,256)
    const unsigned short* __restrict__ Wt,   // 128 x 256 pre-swizzled
    const float* __restrict__ bias,
    unsigned short* __restrict__ outX, int M)
{
    __shared__ __align__(16) unsigned char As[128 * 128];
    __shared__ __align__(16) unsigned char Bs[128 * 128];

    const int t = threadIdx.x;
    const int m0 = blockIdx.x * 128;
    const int lane = t & 63;
    const int wid = t >> 6;
    const int wm = wid >> 1;
    const int wn = wid & 1;
    const int lr = lane & 15;
    const int lk = (lane >> 4) * 8;

    f32x4 acc[2][4] = {};

    const int sr = t >> 2;
    const int sk = (t & 3) * 16;
    const int aRow = m0 + sr;
    const bool aOk = (aRow < M);
    const int rowSafe = aOk ? aRow : 0;
    const int sw = (sr & 7) << 4;
    const unsigned short* bSrc = Wt + (size_t)(lane >> 3) * 256 + (lane & 7) * 8;

    for (int k0 = 0; k0 < 256; k0 += 64) {
        // ---- B: 2 x global_load_lds ----
#pragma unroll
        for (int i = 0; i < 2; ++i) {
            const int chunk = i * 8 + wid;
            __builtin_amdgcn_global_load_lds(
                (gvoid*)(bSrc + (size_t)chunk * 8 * 256 + k0),
                (lvoid*)(Bs + chunk * 1024), 16, 0, 0);
        }
        // ---- A: bf16 copy (reg-staged, swizzled ds_write) ----
        const unsigned short* src =
            (k0 < 128 ? Aa : Ah) + (size_t)rowSafe * 128 + (k0 & 127) + sk;
        const short8 v0 = *(const short8*)(src);
        const short8 v1 = *(const short8*)(src + 8);
        *(short8*)(As + sr * 128 + ((sk * 2) ^ sw)) = v0;
        *(short8*)(As + sr * 128 + ((sk * 2 + 16) ^ sw)) = v1;
        __syncthreads();
#pragma unroll
        for (int ks = 0; ks < 2; ++ks) {
            short8 a[2], b[4];
#pragma unroll
            for (int mf = 0; mf < 2; ++mf) {
                const int r = wm * 32 + mf * 16 + lr;
                a[mf] = *(const short8*)(As + r * 128 + (((ks * 32 + lk) * 2) ^ ((r & 7) << 4)));
            }
#pragma unroll
            for (int nf = 0; nf < 4; ++nf) {
                const int n = wn * 64 + nf * 16 + lr;
                b[nf] = *(const short8*)(Bs + n * 128 + (((ks * 32 + lk) * 2) ^ ((n & 7) << 4)));
            }
#pragma unroll
            for (int mf = 0; mf < 2; ++mf)
#pragma unroll
                for (int nf = 0; nf < 4; ++nf)
                    acc[mf][nf] = __builtin_amdgcn_mfma_f32_16x16x32_bf16(
                        a[mf], b[nf], acc[mf][nf], 0, 0, 0);
        }
        __syncthreads();
    }

#pragma unroll
    for (int mf = 0; mf < 2; ++mf) {
#pragma unroll
        for (int nf = 0; nf < 4; ++nf) {
            const int n = wn * 64 + nf * 16 + lr;
            const float bb = bias[n];
            const f32x4 v = acc[mf][nf];
#pragma unroll
            for (int j = 0; j < 4; ++j) {
                const int m = m0 + wm * 32 + mf * 16 + (lane >> 4) * 4 + j;
                if (m < M) outX[(size_t)m * 128 + n] = f2bf(fmaxf(v[j] + bb, 0.f));
            }
        }
    }
}

// ============ agg1: h = bf16(relu(R + gather(P))), 4-edge unroll ============
// 16 lanes per node (bf16x8 per lane), 4 nodes per wave.
__global__ __launch_bounds__(256) void agg_bias_relu(
    const unsigned short* __restrict__ P, const unsigned short* __restrict__ Rbf,
    const int* __restrict__ rowptr, const int2* __restrict__ csr,
    unsigned short* __restrict__ hout, int N)
{
    const int i = blockIdx.x * 16 + (threadIdx.x >> 4);
    const int l = threadIdx.x & 15;
    if (i >= N) return;
    const int beg = rowptr[i];
    const int end = rowptr[i + 1];
    const int c = l * 8;

    float acc0[8] = {}, acc1[8] = {}, acc2[8] = {}, acc3[8] = {};
    int j = beg;
    for (; j + 3 < end; j += 4) {
        const int2 e0 = csr[j],     e1 = csr[j + 1];
        const int2 e2 = csr[j + 2], e3 = csr[j + 3];
        const short8 v0 = *(const short8*)(P + (size_t)e0.x * 128 + c);
        const short8 v1 = *(const short8*)(P + (size_t)e1.x * 128 + c);
        const short8 v2 = *(const short8*)(P + (size_t)e2.x * 128 + c);
        const short8 v3 = *(const short8*)(P + (size_t)e3.x * 128 + c);
        const float n0 = __builtin_bit_cast(float, e0.y);
        const float n1 = __builtin_bit_cast(float, e1.y);
        const float n2 = __builtin_bit_cast(float, e2.y);
        const float n3 = __builtin_bit_cast(float, e3.y);
#pragma unroll
        for (int q = 0; q < 8; ++q) {
            acc0[q] = fmaf(b2f(v0[q]), n0, acc0[q]);
            acc1[q] = fmaf(b2f(v1[q]), n1, acc1[q]);
            acc2[q] = fmaf(b2f(v2[q]), n2, acc2[q]);
            acc3[q] = fmaf(b2f(v3[q]), n3, acc3[q]);
        }
    }
    for (; j < end; ++j) {
        const int2 e0 = csr[j];
        const short8 v0 = *(const short8*)(P + (size_t)e0.x * 128 + c);
        const float n0 = __builtin_bit_cast(float, e0.y);
#pragma unroll
        for (int q = 0; q < 8; ++q) acc0[q] = fmaf(b2f(v0[q]), n0, acc0[q]);
    }
    const short8 rv = *(const short8*)(Rbf + (size_t)i * 128 + c);
    short8 ov;
#pragma unroll
    for (int q = 0; q < 8; ++q)
        ov[q] = (short)f2bf(fmaxf((acc0[q] + acc1[q]) + (acc2[q] + acc3[q]) + b2f(rv[q]), 0.f));
    *(short8*)(hout + (size_t)i * 128 + c) = ov;
}

// ============ agg2: ah = bf16(gather(h)), 4-edge unroll ============
__global__ __launch_bounds__(256) void agg_plain(
    const unsigned short* __restrict__ H,
    const int* __restrict__ rowptr, const int2* __restrict__ csr,
    unsigned short* __restrict__ ahout, int N)
{
    const int i = blockIdx.x * 16 + (threadIdx.x >> 4);
    const int l = threadIdx.x & 15;
    if (i >= N) return;
    const int beg = rowptr[i];
    const int end = rowptr[i + 1];
    const int c = l * 8;

    float acc0[8] = {}, acc1[8] = {}, acc2[8] = {}, acc3[8] = {};
    int j = beg;
    for (; j + 3 < end; j += 4) {
        const int2 e0 = csr[j],     e1 = csr[j + 1];
        const int2 e2 = csr[j + 2], e3 = csr[j + 3];
        const short8 v0 = *(const short8*)(H + (size_t)e0.x * 128 + c);
        const short8 v1 = *(const short8*)(H + (size_t)e1.x * 128 + c);
        const short8 v2 = *(const short8*)(H + (size_t)e2.x * 128 + c);
        const short8 v3 = *(const short8*)(H + (size_t)e3.x * 128 + c);
        const float n0 = __builtin_bit_cast(float, e0.y);
        const float n1 = __builtin_bit_cast(float, e1.y);
        const float n2 = __builtin_bit_cast(float, e2.y);
        const float n3 = __builtin_bit_cast(float, e3.y);
#pragma unroll
        for (int q = 0; q < 8; ++q) {
            acc0[q] = fmaf(b2f(v0[q]), n0, acc0[q]);
            acc1[q] = fmaf(b2f(v1[q]), n1, acc1[q]);
            acc2[q] = fmaf(b2f(v2[q]), n2, acc2[q]);
            acc3[q] = fmaf(b2f(v3[q]), n3, acc3[q]);
        }
    }
    for (; j < end; ++j) {
        const int2 e0 = csr[j];
        const short8 v0 = *(const short8*)(H + (size_t)e0.x * 128 + c);
        const float n0 = __builtin_bit_cast(float, e0.y);
#pragma unroll
        for (int q = 0; q < 8; ++q) acc0[q] = fmaf(b2f(v0[q]), n0, acc0[q]);
    }
    short8 ov;
#pragma unroll
    for (int q = 0; q < 8; ++q)
        ov[q] = (short)f2bf((acc0[q] + acc1[q]) + (acc2[q] + acc3[q]));
    *(short8*)(ahout + (size_t)i * 128 + c) = ov;
}

// ============ fused mean-pool (sorted batch, bf16 input) + head MLP ============
__global__ __launch_bounds__(128) void pool_mlp(
    const unsigned short* __restrict__ nx, const int* __restrict__ batch, int N,
    const float* __restrict__ Wl1, const float* __restrict__ bl1,
    const float* __restrict__ Wl2, const float* __restrict__ bl2,
    float* __restrict__ out)
{
    __shared__ float gx[128];
    __shared__ float hid[32];
    __shared__ int rng[2];
    const int g = blockIdx.x;
    const int t = threadIdx.x;
    if (t < 2) {
        const int target = g + t;
        int lo = 0, hi = N;
        while (lo < hi) {
            int mid = (lo + hi) >> 1;
            if (batch[mid] < target) lo = mid + 1; else hi = mid;
        }
        rng[t] = lo;
    }
    __syncthreads();
    const int s = rng[0], e = rng[1];
    float acc = 0.f;
    for (int i = s; i < e; ++i) acc += b2f((short)nx[(size_t)i * 128 + t]);
    gx[t] = acc / fmaxf((float)(e - s), 1.f);
    __syncthreads();
    if (t < 32) {
        float a = bl1[t];
#pragma unroll 8
        for (int k = 0; k < 128; ++k) a = fmaf(gx[k], Wl1[k * 32 + t], a);
        hid[t] = a > 0.f ? a : expm1f(a);
    }
    __syncthreads();
    if (t < 2) {
        float a = bl2[t];
#pragma unroll
        for (int k = 0; k < 32; ++k) a = fmaf(hid[k], Wl2[k * 2 + t], a);
        out[(size_t)g * 2 + t] = a;
    }
}

extern "C" void kernel_launch(void* const* d_in, const int* in_sizes, int n_in,
                              void* d_out, int out_size, void* d_ws, size_t ws_size,
                              hipStream_t stream)
{
    const float* x     = (const float*)d_in[0];
    const int*   ei    = (const int*)d_in[1];
    const float* ea    = (const float*)d_in[2];
    const int*   batch = (const int*)d_in[3];
    const float* W1i   = (const float*)d_in[5];
    const float* W1r   = (const float*)d_in[6];
    const float* b1    = (const float*)d_in[7];
    const float* W2i   = (const float*)d_in[8];
    const float* W2r   = (const float*)d_in[9];
    const float* b2    = (const float*)d_in[10];
    const float* Wl1   = (const float*)d_in[11];
    const float* bl1   = (const float*)d_in[12];
    const float* Wl2   = (const float*)d_in[13];
    const float* bl2   = (const float*)d_in[14];

    const int N = in_sizes[0] / 768;
    const int E = in_sizes[2];
    const int G = out_size / 2;

    char* ws = (char*)d_ws;
    size_t off = 0;
    auto alloc = [&](size_t bytes) -> char* {
        char* p = ws + off;
        off = (off + bytes + 255) & ~(size_t)255;
        return p;
    };
    float* deg     = (float*)alloc((size_t)N * 4);
    int*   cnt     = (int*)alloc((size_t)N * 4);
    int*   rowptr  = (int*)alloc((size_t)(N + 1) * 4);
    int*   wp      = (int*)alloc((size_t)N * 4);
    int*   blkoff  = (int*)alloc((size_t)1056 * 4);
    int*   blkdum  = (int*)alloc((size_t)4 * 4);
    int2*  csr     = (int2*)alloc((size_t)E * 8);
    unsigned short* P1   = (unsigned short*)alloc((size_t)N * 128 * 2);
    unsigned short* R1   = (unsigned short*)alloc((size_t)N * 128 * 2);
    unsigned short* hbf  = (unsigned short*)alloc((size_t)N * 128 * 2);
    unsigned short* ahb  = (unsigned short*)alloc((size_t)N * 128 * 2);
    unsigned short* nxb  = (unsigned short*)alloc((size_t)N * 128 * 2);
    unsigned short* W1t  = (unsigned short*)alloc((size_t)256 * 768 * 2);
    unsigned short* W2t  = (unsigned short*)alloc((size_t)128 * 256 * 2);

    const int eBlocks = (E + 255) / 256;
    const int nb      = (N + 1023) / 1024;
    const int nBlocks = (N + 255) / 256;
    const int aBlocks = (N + 15) / 16;

    // ---- CSR build + weight convert ----
    hipMemsetAsync(deg, 0, (size_t)N * 4, stream);
    hipMemsetAsync(cnt, 0, (size_t)N * 4, stream);
    deg_hist_kernel<<<eBlocks, 256, 0, stream>>>(ei, ea, deg, cnt, E);
    scan1_kernel<<<nb, 256, 0, stream>>>(cnt, rowptr, blkoff, N);
    scan1_kernel<<<1, 256, 0, stream>>>(blkoff, blkoff, blkdum, nb);
    scan3_kernel<<<nBlocks, 256, 0, stream>>>(rowptr, blkoff, wp, N, E);
    place_kernel<<<eBlocks, 256, 0, stream>>>(ei, ea, deg, wp, csr, E);
    conv_weights<<<(256 * 768 + 128 * 256 + 255) / 256, 256, 0, stream>>>(
        W1i, W1r, W2i, W2r, W1t, W2t);

    // ---- layer 1: P1 = bf16(x@W1i), R1 = bf16(x@W1r + b1) ----
    gemm_mfma_dual<<<(N + 63) / 64, 512, 0, stream>>>(x, W1t, b1, P1, R1, N, 768);
    agg_bias_relu<<<aBlocks, 256, 0, stream>>>(P1, R1, rowptr, csr, hbf, N);

    // ---- layer 2: ah = bf16(gather(h)); node_x = bf16(relu([ah|h]@W2 + b2)) ----
    agg_plain<<<aBlocks, 256, 0, stream>>>(hbf, rowptr, csr, ahb, N);
    gemm_mfma_single<<<(N + 127) / 128, 512, 0, stream>>>(ahb, hbf, W2t, b2, nxb, N);

    // ---- fused pool + head ----
    pool_mlp<<<G, 128, 0, stream>>>(nxb, batch, N, Wl1, bl1, Wl2, bl2, (float*)d_out);
}

// Round 8
// 455.611 us; speedup vs baseline: 13.9801x; 1.1812x over previous
//
#include <hip/hip_runtime.h>
#include <hip/hip_bf16.h>
#include <math.h>

typedef __attribute__((ext_vector_type(8))) short short8;
typedef __attribute__((ext_vector_type(4))) float f32x4;
typedef __attribute__((address_space(1))) const void gvoid;
typedef __attribute__((address_space(3))) void lvoid;

__device__ __forceinline__ unsigned short f2bf(float f) {
    unsigned int u = __builtin_bit_cast(unsigned int, f);
    return (unsigned short)((u + 0x7fffu + ((u >> 16) & 1u)) >> 16);   // RNE
}
__device__ __forceinline__ float b2f(short s) {
    return __builtin_bit_cast(float, ((unsigned int)(unsigned short)s) << 16);
}
__device__ __forceinline__ unsigned int cvtpk(float lo, float hi) {
    unsigned int r;
    asm("v_cvt_pk_bf16_f32 %0, %1, %2" : "=v"(r) : "v"(lo), "v"(hi));
    return r;
}

// ============ degree + count histogram, ONE u64 atomic per edge ============
// packed[c] = (count << 42) | sum(round(ew * 2^20))
// max sum = 1.6M * 2^20 < 2^42 ; max count 1.6M < 2^22.  [halves the per-line
// serialized atomic chain vs separate deg/cnt atomics]
__global__ __launch_bounds__(256) void deg_hist_kernel(
    const int* __restrict__ ei, const float* __restrict__ ea,
    unsigned long long* __restrict__ packed, int E)
{
    int e = blockIdx.x * 256 + threadIdx.x;
    if (e >= E) return;
    int c = ei[(size_t)E + e];
    unsigned long long fx = (unsigned long long)(ea[e] * 1048576.0f + 0.5f);
    atomicAdd(&packed[c], (1ULL << 42) | fx);
}

// ============ scan pass 1 over packed counts ============
__global__ __launch_bounds__(256) void scan1p_kernel(
    const unsigned long long* __restrict__ packed, int* __restrict__ out,
    int* __restrict__ blksum, int n)
{
    __shared__ int part[256];
    const int t = threadIdx.x;
    const int base = blockIdx.x * 1024 + t * 4;
    int v[4];
#pragma unroll
    for (int q = 0; q < 4; ++q)
        v[q] = (base + q < n) ? (int)(packed[base + q] >> 42) : 0;
    const int s = v[0] + v[1] + v[2] + v[3];
    part[t] = s;
    __syncthreads();
    for (int off = 1; off < 256; off <<= 1) {
        int x = (t >= off) ? part[t - off] : 0;
        __syncthreads();
        part[t] += x;
        __syncthreads();
    }
    if (t == 255) blksum[blockIdx.x] = part[255];
    int run = part[t] - s;
#pragma unroll
    for (int q = 0; q < 4; ++q) {
        if (base + q < n) out[base + q] = run;
        run += v[q];
    }
}

// ============ scan pass 1 over ints (block sums) ============
__global__ __launch_bounds__(256) void scan1_kernel(
    const int* __restrict__ in, int* __restrict__ out, int* __restrict__ blksum, int n)
{
    __shared__ int part[256];
    const int t = threadIdx.x;
    const int base = blockIdx.x * 1024 + t * 4;
    int v[4];
#pragma unroll
    for (int q = 0; q < 4; ++q) v[q] = (base + q < n) ? in[base + q] : 0;
    const int s = v[0] + v[1] + v[2] + v[3];
    part[t] = s;
    __syncthreads();
    for (int off = 1; off < 256; off <<= 1) {
        int x = (t >= off) ? part[t - off] : 0;
        __syncthreads();
        part[t] += x;
        __syncthreads();
    }
    if (t == 255) blksum[blockIdx.x] = part[255];
    int run = part[t] - s;
#pragma unroll
    for (int q = 0; q < 4; ++q) {
        if (base + q < n) out[base + q] = run;
        run += v[q];
    }
}

// ============ scan finalize + wp init + dinv = rsqrt(deg) ============
__global__ __launch_bounds__(256) void scan3_kernel(
    int* __restrict__ rowptr, const int* __restrict__ blkoff,
    int* __restrict__ wp, const unsigned long long* __restrict__ packed,
    float* __restrict__ dinv, int n, int Etot)
{
    int i = blockIdx.x * 256 + threadIdx.x;
    if (i == 0) rowptr[n] = Etot;
    if (i >= n) return;
    int v = rowptr[i] + blkoff[i >> 10];
    rowptr[i] = v;
    wp[i] = v;
    unsigned long long fx = packed[i] & ((1ULL << 42) - 1);
    dinv[i] = (fx > 0) ? rsqrtf((float)fx * 9.5367431640625e-7f) : 0.f;
}

// ============ edge placement: csr[p] = {row, nrm} ============
__global__ __launch_bounds__(256) void place_kernel(
    const int* __restrict__ ei, const float* __restrict__ ea,
    const float* __restrict__ dinv, int* __restrict__ wp,
    int2* __restrict__ csr, int E)
{
    int e = blockIdx.x * 256 + threadIdx.x;
    if (e >= E) return;
    int r = ei[e];
    int c = ei[(size_t)E + e];
    float nm = dinv[r] * ea[e] * dinv[c];
    int p = atomicAdd(&wp[c], 1);
    int2 rec;
    rec.x = r;
    rec.y = __builtin_bit_cast(int, nm);
    csr[p] = rec;
}

// ============ weight pre-convert, PRE-SWIZZLED for global_load_lds ============
__global__ __launch_bounds__(256) void conv_weights(
    const float* __restrict__ W1i, const float* __restrict__ W1r,
    const float* __restrict__ W2i, const float* __restrict__ W2r,
    unsigned short* __restrict__ W1t, unsigned short* __restrict__ W2t)
{
    int id = blockIdx.x * 256 + threadIdx.x;
    if (id < 256 * 768) {
        int n = id / 768, j = id % 768;
        int k = (j & ~63) | ((((j >> 3) & 7) ^ (n & 7)) << 3) | (j & 7);
        float v = (n < 128) ? W1i[k * 128 + n] : W1r[k * 128 + (n - 128)];
        W1t[id] = f2bf(v);
    } else {
        int id2 = id - 256 * 768;
        if (id2 < 128 * 256) {
            int n = id2 >> 8, j = id2 & 255;
            int k = (j & ~63) | ((((j >> 3) & 7) ^ (n & 7)) << 3) | (j & 7);
            float v = (k < 128) ? W2i[k * 128 + n] : W2r[(k - 128) * 128 + n];
            W2t[id2] = f2bf(v);
        }
    }
}

// ============ MFMA dual GEMM (layer 1) ============
__global__ __launch_bounds__(512) void gemm_mfma_dual(
    const float* __restrict__ A, const unsigned short* __restrict__ Wt,
    const float* __restrict__ bias, unsigned short* __restrict__ outP,
    unsigned short* __restrict__ outR, int M, int K)
{
    __shared__ __align__(16) unsigned char As[64 * 128];
    __shared__ __align__(16) unsigned char Bs[256 * 128];

    const int t = threadIdx.x;
    const int m0 = blockIdx.x * 64;
    const int lane = t & 63;
    const int wid = t >> 6;
    const int wm = wid >> 2;
    const int wn = wid & 3;
    const int lr = lane & 15;
    const int lk = (lane >> 4) * 8;

    f32x4 acc[2][4] = {};

    const int sr = t >> 3;
    const int sk = (t & 7) * 8;
    const int aRow = m0 + sr;
    const bool aOk = (aRow < M);
    const float* aSrc = A + (size_t)(aOk ? aRow : 0) * K + sk;
    const int aDst = sr * 128 + ((sk * 2) ^ ((sr & 7) << 4));
    const unsigned short* bSrc = Wt + (size_t)(lane >> 3) * K + (lane & 7) * 8;

    for (int k0 = 0; k0 < K; k0 += 64) {
#pragma unroll
        for (int i = 0; i < 4; ++i) {
            const int chunk = i * 8 + wid;
            __builtin_amdgcn_global_load_lds(
                (gvoid*)(bSrc + (size_t)chunk * 8 * K + k0),
                (lvoid*)(Bs + chunk * 1024), 16, 0, 0);
        }
        unsigned int p0 = 0, p1 = 0, p2 = 0, p3 = 0;
        if (aOk) {
            const float4 f0 = *(const float4*)(aSrc + k0);
            const float4 f1 = *(const float4*)(aSrc + k0 + 4);
            p0 = cvtpk(f0.x, f0.y);
            p1 = cvtpk(f0.z, f0.w);
            p2 = cvtpk(f1.x, f1.y);
            p3 = cvtpk(f1.z, f1.w);
        }
        uint4 uv = {p0, p1, p2, p3};
        *(uint4*)(As + aDst) = uv;
        __syncthreads();
#pragma unroll
        for (int ks = 0; ks < 2; ++ks) {
            short8 a[2], b[4];
#pragma unroll
            for (int mf = 0; mf < 2; ++mf) {
                const int r = wm * 32 + mf * 16 + lr;
                a[mf] = *(const short8*)(As + r * 128 + (((ks * 32 + lk) * 2) ^ ((r & 7) << 4)));
            }
#pragma unroll
            for (int nf = 0; nf < 4; ++nf) {
                const int n = wn * 64 + nf * 16 + lr;
                b[nf] = *(const short8*)(Bs + n * 128 + (((ks * 32 + lk) * 2) ^ ((n & 7) << 4)));
            }
#pragma unroll
            for (int mf = 0; mf < 2; ++mf)
#pragma unroll
                for (int nf = 0; nf < 4; ++nf)
                    acc[mf][nf] = __builtin_amdgcn_mfma_f32_16x16x32_bf16(
                        a[mf], b[nf], acc[mf][nf], 0, 0, 0);
        }
        __syncthreads();
    }

#pragma unroll
    for (int mf = 0; mf < 2; ++mf) {
#pragma unroll
        for (int nf = 0; nf < 4; ++nf) {
            const int n = wn * 64 + nf * 16 + lr;
            const f32x4 v = acc[mf][nf];
            if (n < 128) {
#pragma unroll
                for (int j = 0; j < 4; ++j) {
                    const int m = m0 + wm * 32 + mf * 16 + (lane >> 4) * 4 + j;
                    if (m < M) outP[(size_t)m * 128 + n] = f2bf(v[j]);
                }
            } else {
                const int nl = n - 128;
                const float badd = bias[nl];
#pragma unroll
                for (int j = 0; j < 4; ++j) {
                    const int m = m0 + wm * 32 + mf * 16 + (lane >> 4) * 4 + j;
                    if (m < M) outR[(size_t)m * 128 + nl] = f2bf(v[j] + badd);
                }
            }
        }
    }
}

// ============ MFMA single GEMM (layer 2, K=256 over [ah|h]) + bias + ReLU ============
__global__ __launch_bounds__(512) void gemm_mfma_single(
    const unsigned short* __restrict__ Aa,
    const unsigned short* __restrict__ Ah,
    const unsigned short* __restrict__ Wt,
    const float* __restrict__ bias,
    unsigned short* __restrict__ outX, int M)
{
    __shared__ __align__(16) unsigned char As[128 * 128];
    __shared__ __align__(16) unsigned char Bs[128 * 128];

    const int t = threadIdx.x;
    const int m0 = blockIdx.x * 128;
    const int lane = t & 63;
    const int wid = t >> 6;
    const int wm = wid >> 1;
    const int wn = wid & 1;
    const int lr = lane & 15;
    const int lk = (lane >> 4) * 8;

    f32x4 acc[2][4] = {};

    const int sr = t >> 2;
    const int sk = (t & 3) * 16;
    const int aRow = m0 + sr;
    const bool aOk = (aRow < M);
    const int rowSafe = aOk ? aRow : 0;
    const int sw = (sr & 7) << 4;
    const unsigned short* bSrc = Wt + (size_t)(lane >> 3) * 256 + (lane & 7) * 8;

    for (int k0 = 0; k0 < 256; k0 += 64) {
#pragma unroll
        for (int i = 0; i < 2; ++i) {
            const int chunk = i * 8 + wid;
            __builtin_amdgcn_global_load_lds(
                (gvoid*)(bSrc + (size_t)chunk * 8 * 256 + k0),
                (lvoid*)(Bs + chunk * 1024), 16, 0, 0);
        }
        const unsigned short* src =
            (k0 < 128 ? Aa : Ah) + (size_t)rowSafe * 128 + (k0 & 127) + sk;
        const short8 v0 = *(const short8*)(src);
        const short8 v1 = *(const short8*)(src + 8);
        *(short8*)(As + sr * 128 + ((sk * 2) ^ sw)) = v0;
        *(short8*)(As + sr * 128 + ((sk * 2 + 16) ^ sw)) = v1;
        __syncthreads();
#pragma unroll
        for (int ks = 0; ks < 2; ++ks) {
            short8 a[2], b[4];
#pragma unroll
            for (int mf = 0; mf < 2; ++mf) {
                const int r = wm * 32 + mf * 16 + lr;
                a[mf] = *(const short8*)(As + r * 128 + (((ks * 32 + lk) * 2) ^ ((r & 7) << 4)));
            }
#pragma unroll
            for (int nf = 0; nf < 4; ++nf) {
                const int n = wn * 64 + nf * 16 + lr;
                b[nf] = *(const short8*)(Bs + n * 128 + (((ks * 32 + lk) * 2) ^ ((n & 7) << 4)));
            }
#pragma unroll
            for (int mf = 0; mf < 2; ++mf)
#pragma unroll
                for (int nf = 0; nf < 4; ++nf)
                    acc[mf][nf] = __builtin_amdgcn_mfma_f32_16x16x32_bf16(
                        a[mf], b[nf], acc[mf][nf], 0, 0, 0);
        }
        __syncthreads();
    }

#pragma unroll
    for (int mf = 0; mf < 2; ++mf) {
#pragma unroll
        for (int nf = 0; nf < 4; ++nf) {
            const int n = wn * 64 + nf * 16 + lr;
            const float bb = bias[n];
            const f32x4 v = acc[mf][nf];
#pragma unroll
            for (int j = 0; j < 4; ++j) {
                const int m = m0 + wm * 32 + mf * 16 + (lane >> 4) * 4 + j;
                if (m < M) outX[(size_t)m * 128 + n] = f2bf(fmaxf(v[j] + bb, 0.f));
            }
        }
    }
}

// ============ agg1: h = bf16(relu(R + gather(P))), 4-edge unroll ============
__global__ __launch_bounds__(256) void agg_bias_relu(
    const unsigned short* __restrict__ P, const unsigned short* __restrict__ Rbf,
    const int* __restrict__ rowptr, const int2* __restrict__ csr,
    unsigned short* __restrict__ hout, int N)
{
    const int i = blockIdx.x * 16 + (threadIdx.x >> 4);
    const int l = threadIdx.x & 15;
    if (i >= N) return;
    const int beg = rowptr[i];
    const int end = rowptr[i + 1];
    const int c = l * 8;

    float acc0[8] = {}, acc1[8] = {}, acc2[8] = {}, acc3[8] = {};
    int j = beg;
    for (; j + 3 < end; j += 4) {
        const int2 e0 = csr[j],     e1 = csr[j + 1];
        const int2 e2 = csr[j + 2], e3 = csr[j + 3];
        const short8 v0 = *(const short8*)(P + (size_t)e0.x * 128 + c);
        const short8 v1 = *(const short8*)(P + (size_t)e1.x * 128 + c);
        const short8 v2 = *(const short8*)(P + (size_t)e2.x * 128 + c);
        const short8 v3 = *(const short8*)(P + (size_t)e3.x * 128 + c);
        const float n0 = __builtin_bit_cast(float, e0.y);
        const float n1 = __builtin_bit_cast(float, e1.y);
        const float n2 = __builtin_bit_cast(float, e2.y);
        const float n3 = __builtin_bit_cast(float, e3.y);
#pragma unroll
        for (int q = 0; q < 8; ++q) {
            acc0[q] = fmaf(b2f(v0[q]), n0, acc0[q]);
            acc1[q] = fmaf(b2f(v1[q]), n1, acc1[q]);
            acc2[q] = fmaf(b2f(v2[q]), n2, acc2[q]);
            acc3[q] = fmaf(b2f(v3[q]), n3, acc3[q]);
        }
    }
    for (; j < end; ++j) {
        const int2 e0 = csr[j];
        const short8 v0 = *(const short8*)(P + (size_t)e0.x * 128 + c);
        const float n0 = __builtin_bit_cast(float, e0.y);
#pragma unroll
        for (int q = 0; q < 8; ++q) acc0[q] = fmaf(b2f(v0[q]), n0, acc0[q]);
    }
    const short8 rv = *(const short8*)(Rbf + (size_t)i * 128 + c);
    short8 ov;
#pragma unroll
    for (int q = 0; q < 8; ++q)
        ov[q] = (short)f2bf(fmaxf((acc0[q] + acc1[q]) + (acc2[q] + acc3[q]) + b2f(rv[q]), 0.f));
    *(short8*)(hout + (size_t)i * 128 + c) = ov;
}

// ============ agg2: ah = bf16(gather(h)), 4-edge unroll ============
__global__ __launch_bounds__(256) void agg_plain(
    const unsigned short* __restrict__ H,
    const int* __restrict__ rowptr, const int2* __restrict__ csr,
    unsigned short* __restrict__ ahout, int N)
{
    const int i = blockIdx.x * 16 + (threadIdx.x >> 4);
    const int l = threadIdx.x & 15;
    if (i >= N) return;
    const int beg = rowptr[i];
    const int end = rowptr[i + 1];
    const int c = l * 8;

    float acc0[8] = {}, acc1[8] = {}, acc2[8] = {}, acc3[8] = {};
    int j = beg;
    for (; j + 3 < end; j += 4) {
        const int2 e0 = csr[j],     e1 = csr[j + 1];
        const int2 e2 = csr[j + 2], e3 = csr[j + 3];
        const short8 v0 = *(const short8*)(H + (size_t)e0.x * 128 + c);
        const short8 v1 = *(const short8*)(H + (size_t)e1.x * 128 + c);
        const short8 v2 = *(const short8*)(H + (size_t)e2.x * 128 + c);
        const short8 v3 = *(const short8*)(H + (size_t)e3.x * 128 + c);
        const float n0 = __builtin_bit_cast(float, e0.y);
        const float n1 = __builtin_bit_cast(float, e1.y);
        const float n2 = __builtin_bit_cast(float, e2.y);
        const float n3 = __builtin_bit_cast(float, e3.y);
#pragma unroll
        for (int q = 0; q < 8; ++q) {
            acc0[q] = fmaf(b2f(v0[q]), n0, acc0[q]);
            acc1[q] = fmaf(b2f(v1[q]), n1, acc1[q]);
            acc2[q] = fmaf(b2f(v2[q]), n2, acc2[q]);
            acc3[q] = fmaf(b2f(v3[q]), n3, acc3[q]);
        }
    }
    for (; j < end; ++j) {
        const int2 e0 = csr[j];
        const short8 v0 = *(const short8*)(H + (size_t)e0.x * 128 + c);
        const float n0 = __builtin_bit_cast(float, e0.y);
#pragma unroll
        for (int q = 0; q < 8; ++q) acc0[q] = fmaf(b2f(v0[q]), n0, acc0[q]);
    }
    short8 ov;
#pragma unroll
    for (int q = 0; q < 8; ++q)
        ov[q] = (short)f2bf((acc0[q] + acc1[q]) + (acc2[q] + acc3[q]));
    *(short8*)(ahout + (size_t)i * 128 + c) = ov;
}

// ============ fused mean-pool (sorted batch, bf16 input) + head MLP ============
__global__ __launch_bounds__(128) void pool_mlp(
    const unsigned short* __restrict__ nx, const int* __restrict__ batch, int N,
    const float* __restrict__ Wl1, const float* __restrict__ bl1,
    const float* __restrict__ Wl2, const float* __restrict__ bl2,
    float* __restrict__ out)
{
    __shared__ float gx[128];
    __shared__ float hid[32];
    __shared__ int rng[2];
    const int g = blockIdx.x;
    const int t = threadIdx.x;
    if (t < 2) {
        const int target = g + t;
        int lo = 0, hi = N;
        while (lo < hi) {
            int mid = (lo + hi) >> 1;
            if (batch[mid] < target) lo = mid + 1; else hi = mid;
        }
        rng[t] = lo;
    }
    __syncthreads();
    const int s = rng[0], e = rng[1];
    float a0 = 0.f, a1 = 0.f, a2 = 0.f, a3 = 0.f;
    int i = s;
    for (; i + 3 < e; i += 4) {
        a0 += b2f((short)nx[(size_t)(i + 0) * 128 + t]);
        a1 += b2f((short)nx[(size_t)(i + 1) * 128 + t]);
        a2 += b2f((short)nx[(size_t)(i + 2) * 128 + t]);
        a3 += b2f((short)nx[(size_t)(i + 3) * 128 + t]);
    }
    for (; i < e; ++i) a0 += b2f((short)nx[(size_t)i * 128 + t]);
    gx[t] = ((a0 + a1) + (a2 + a3)) / fmaxf((float)(e - s), 1.f);
    __syncthreads();
    if (t < 32) {
        float a = bl1[t];
#pragma unroll 8
        for (int k = 0; k < 128; ++k) a = fmaf(gx[k], Wl1[k * 32 + t], a);
        hid[t] = a > 0.f ? a : expm1f(a);
    }
    __syncthreads();
    if (t < 2) {
        float a = bl2[t];
#pragma unroll
        for (int k = 0; k < 32; ++k) a = fmaf(hid[k], Wl2[k * 2 + t], a);
        out[(size_t)g * 2 + t] = a;
    }
}

extern "C" void kernel_launch(void* const* d_in, const int* in_sizes, int n_in,
                              void* d_out, int out_size, void* d_ws, size_t ws_size,
                              hipStream_t stream)
{
    const float* x     = (const float*)d_in[0];
    const int*   ei    = (const int*)d_in[1];
    const float* ea    = (const float*)d_in[2];
    const int*   batch = (const int*)d_in[3];
    const float* W1i   = (const float*)d_in[5];
    const float* W1r   = (const float*)d_in[6];
    const float* b1    = (const float*)d_in[7];
    const float* W2i   = (const float*)d_in[8];
    const float* W2r   = (const float*)d_in[9];
    const float* b2    = (const float*)d_in[10];
    const float* Wl1   = (const float*)d_in[11];
    const float* bl1   = (const float*)d_in[12];
    const float* Wl2   = (const float*)d_in[13];
    const float* bl2   = (const float*)d_in[14];

    const int N = in_sizes[0] / 768;
    const int E = in_sizes[2];
    const int G = out_size / 2;

    char* ws = (char*)d_ws;
    size_t off = 0;
    auto alloc = [&](size_t bytes) -> char* {
        char* p = ws + off;
        off = (off + bytes + 255) & ~(size_t)255;
        return p;
    };
    unsigned long long* packed = (unsigned long long*)alloc((size_t)N * 8);
    float* dinv    = (float*)alloc((size_t)N * 4);
    int*   rowptr  = (int*)alloc((size_t)(N + 1) * 4);
    int*   wp      = (int*)alloc((size_t)N * 4);
    int*   blkoff  = (int*)alloc((size_t)1056 * 4);
    int*   blkdum  = (int*)alloc((size_t)4 * 4);
    int2*  csr     = (int2*)alloc((size_t)E * 8);
    unsigned short* P1   = (unsigned short*)alloc((size_t)N * 128 * 2);
    unsigned short* R1   = (unsigned short*)alloc((size_t)N * 128 * 2);
    unsigned short* hbf  = (unsigned short*)alloc((size_t)N * 128 * 2);
    unsigned short* ahb  = (unsigned short*)alloc((size_t)N * 128 * 2);
    unsigned short* nxb  = (unsigned short*)alloc((size_t)N * 128 * 2);
    unsigned short* W1t  = (unsigned short*)alloc((size_t)256 * 768 * 2);
    unsigned short* W2t  = (unsigned short*)alloc((size_t)128 * 256 * 2);

    const int eBlocks = (E + 255) / 256;
    const int nb      = (N + 1023) / 1024;
    const int nBlocks = (N + 255) / 256;
    const int aBlocks = (N + 15) / 16;

    // ---- CSR build + weight convert ----
    hipMemsetAsync(packed, 0, (size_t)N * 8, stream);
    deg_hist_kernel<<<eBlocks, 256, 0, stream>>>(ei, ea, packed, E);
    scan1p_kernel<<<nb, 256, 0, stream>>>(packed, rowptr, blkoff, N);
    scan1_kernel<<<1, 256, 0, stream>>>(blkoff, blkoff, blkdum, nb);
    scan3_kernel<<<nBlocks, 256, 0, stream>>>(rowptr, blkoff, wp, packed, dinv, N, E);
    place_kernel<<<eBlocks, 256, 0, stream>>>(ei, ea, dinv, wp, csr, E);
    conv_weights<<<(256 * 768 + 128 * 256 + 255) / 256, 256, 0, stream>>>(
        W1i, W1r, W2i, W2r, W1t, W2t);

    // ---- layer 1: P1 = bf16(x@W1i), R1 = bf16(x@W1r + b1) ----
    gemm_mfma_dual<<<(N + 63) / 64, 512, 0, stream>>>(x, W1t, b1, P1, R1, N, 768);
    agg_bias_relu<<<aBlocks, 256, 0, stream>>>(P1, R1, rowptr, csr, hbf, N);

    // ---- layer 2: ah = bf16(gather(h)); node_x = bf16(relu([ah|h]@W2 + b2)) ----
    agg_plain<<<aBlocks, 256, 0, stream>>>(hbf, rowptr, csr, ahb, N);
    gemm_mfma_single<<<(N + 127) / 128, 512, 0, stream>>>(ahb, hbf, W2t, b2, nxb, N);

    // ---- fused pool + head ----
    pool_mlp<<<G, 128, 0, stream>>>(nxb, batch, N, Wl1, bl1, Wl2, bl2, (float*)d_out);
}

// Round 9
// 430.441 us; speedup vs baseline: 14.7975x; 1.0585x over previous
//
#include <hip/hip_runtime.h>
#include <hip/hip_bf16.h>
#include <math.h>

typedef __attribute__((ext_vector_type(8))) short short8;
typedef __attribute__((ext_vector_type(4))) float f32x4;
typedef __attribute__((address_space(1))) const void gvoid;
typedef __attribute__((address_space(3))) void lvoid;

#define NC 8   // histogram privatization copies

__device__ __forceinline__ unsigned short f2bf(float f) {
    unsigned int u = __builtin_bit_cast(unsigned int, f);
    return (unsigned short)((u + 0x7fffu + ((u >> 16) & 1u)) >> 16);   // RNE
}
__device__ __forceinline__ float b2f(short s) {
    return __builtin_bit_cast(float, ((unsigned int)(unsigned short)s) << 16);
}
__device__ __forceinline__ unsigned int cvtpk(float lo, float hi) {
    unsigned int r;
    asm("v_cvt_pk_bf16_f32 %0, %1, %2" : "=v"(r) : "v"(lo), "v"(hi));
    return r;
}

// ============ hist: privatized u64 packed (cnt<<42 | fixpt-deg); rank from return ============
__global__ __launch_bounds__(256) void deg_hist_kernel(
    const int* __restrict__ ei, const float* __restrict__ ea,
    unsigned long long* __restrict__ packed, int* __restrict__ rank, int N, int E)
{
    int e = blockIdx.x * 256 + threadIdx.x;
    if (e >= E) return;
    const int copy = blockIdx.x & (NC - 1);
    int c = ei[(size_t)E + e];
    unsigned long long fx = (unsigned long long)(ea[e] * 1048576.0f + 0.5f);
    unsigned long long old = atomicAdd(&packed[(size_t)copy * N + c], (1ULL << 42) | fx);
    rank[e] = (int)(old >> 42);
}

// ============ scan pass 1: per-node total count over NC copies ============
__global__ __launch_bounds__(256) void scan1p_kernel(
    const unsigned long long* __restrict__ packed, int* __restrict__ out,
    int* __restrict__ blksum, int n)
{
    __shared__ int part[256];
    const int t = threadIdx.x;
    const int base = blockIdx.x * 1024 + t * 4;
    int v[4];
#pragma unroll
    for (int q = 0; q < 4; ++q) {
        int s = 0;
        if (base + q < n) {
#pragma unroll
            for (int p = 0; p < NC; ++p)
                s += (int)(packed[(size_t)p * n + base + q] >> 42);
        }
        v[q] = s;
    }
    const int s = v[0] + v[1] + v[2] + v[3];
    part[t] = s;
    __syncthreads();
    for (int off = 1; off < 256; off <<= 1) {
        int x = (t >= off) ? part[t - off] : 0;
        __syncthreads();
        part[t] += x;
        __syncthreads();
    }
    if (t == 255) blksum[blockIdx.x] = part[255];
    int run = part[t] - s;
#pragma unroll
    for (int q = 0; q < 4; ++q) {
        if (base + q < n) out[base + q] = run;
        run += v[q];
    }
}

// ============ scan pass over block sums ============
__global__ __launch_bounds__(256) void scan1_kernel(
    const int* __restrict__ in, int* __restrict__ out, int* __restrict__ blksum, int n)
{
    __shared__ int part[256];
    const int t = threadIdx.x;
    const int base = blockIdx.x * 1024 + t * 4;
    int v[4];
#pragma unroll
    for (int q = 0; q < 4; ++q) v[q] = (base + q < n) ? in[base + q] : 0;
    const int s = v[0] + v[1] + v[2] + v[3];
    part[t] = s;
    __syncthreads();
    for (int off = 1; off < 256; off <<= 1) {
        int x = (t >= off) ? part[t - off] : 0;
        __syncthreads();
        part[t] += x;
        __syncthreads();
    }
    if (t == 255) blksum[blockIdx.x] = part[255];
    int run = part[t] - s;
#pragma unroll
    for (int q = 0; q < 4; ++q) {
        if (base + q < n) out[base + q] = run;
        run += v[q];
    }
}

// ============ finalize: rowptr += blkoff; per-copy bases; dinv ============
__global__ __launch_bounds__(256) void scan3_kernel(
    int* __restrict__ rowptr, const int* __restrict__ blkoff,
    int* __restrict__ wpb, const unsigned long long* __restrict__ packed,
    float* __restrict__ dinv, int n, int Etot)
{
    int i = blockIdx.x * 256 + threadIdx.x;
    if (i == 0) rowptr[n] = Etot;
    if (i >= n) return;
    int base = rowptr[i] + blkoff[i >> 10];
    rowptr[i] = base;
    unsigned long long degfx = 0;
    int acc = base;
#pragma unroll
    for (int p = 0; p < NC; ++p) {
        unsigned long long v = packed[(size_t)p * n + i];
        wpb[(size_t)p * n + i] = acc;
        acc += (int)(v >> 42);
        degfx += v & ((1ULL << 42) - 1);
    }
    dinv[i] = (degfx > 0) ? rsqrtf((float)degfx * 9.5367431640625e-7f) : 0.f;
}

// ============ edge placement: NO atomics (base + rank) ============
__global__ __launch_bounds__(256) void place_kernel(
    const int* __restrict__ ei, const float* __restrict__ ea,
    const float* __restrict__ dinv, const int* __restrict__ wpb,
    const int* __restrict__ rank, int2* __restrict__ csr, int N, int E)
{
    int e = blockIdx.x * 256 + threadIdx.x;
    if (e >= E) return;
    const int copy = blockIdx.x & (NC - 1);
    int r = ei[e];
    int c = ei[(size_t)E + e];
    float nm = dinv[r] * ea[e] * dinv[c];
    int pos = wpb[(size_t)copy * N + c] + rank[e];
    int2 rec;
    rec.x = r;
    rec.y = __builtin_bit_cast(int, nm);
    csr[pos] = rec;
}

// ============ weight pre-convert, PRE-SWIZZLED for global_load_lds ============
__global__ __launch_bounds__(256) void conv_weights(
    const float* __restrict__ W1i, const float* __restrict__ W1r,
    const float* __restrict__ W2i, const float* __restrict__ W2r,
    unsigned short* __restrict__ W1t, unsigned short* __restrict__ W2t)
{
    int id = blockIdx.x * 256 + threadIdx.x;
    if (id < 256 * 768) {
        int n = id / 768, j = id % 768;
        int k = (j & ~63) | ((((j >> 3) & 7) ^ (n & 7)) << 3) | (j & 7);
        float v = (n < 128) ? W1i[k * 128 + n] : W1r[k * 128 + (n - 128)];
        W1t[id] = f2bf(v);
    } else {
        int id2 = id - 256 * 768;
        if (id2 < 128 * 256) {
            int n = id2 >> 8, j = id2 & 255;
            int k = (j & ~63) | ((((j >> 3) & 7) ^ (n & 7)) << 3) | (j & 7);
            float v = (k < 128) ? W2i[k * 128 + n] : W2r[(k - 128) * 128 + n];
            W2t[id2] = f2bf(v);
        }
    }
}

// ============ MFMA dual GEMM (layer 1), DOUBLE-BUFFERED ============
// Issue-early/write-late (T14): barrier -> issue next B-DMA + next A-loads ->
// MFMA(cur) -> cvt+ds_write(next).
__global__ __launch_bounds__(512) void gemm_mfma_dual(
    const float* __restrict__ A, const unsigned short* __restrict__ Wt,
    const float* __restrict__ bias, unsigned short* __restrict__ outP,
    unsigned short* __restrict__ outR, int M, int K)
{
    __shared__ __align__(16) unsigned char As[2][64 * 128];
    __shared__ __align__(16) unsigned char Bs[2][256 * 128];

    const int t = threadIdx.x;
    const int m0 = blockIdx.x * 64;
    const int lane = t & 63;
    const int wid = t >> 6;
    const int wm = wid >> 2;
    const int wn = wid & 3;
    const int lr = lane & 15;
    const int lk = (lane >> 4) * 8;

    f32x4 acc[2][4] = {};

    const int sr = t >> 3;
    const int sk = (t & 7) * 8;
    const int aRow = m0 + sr;
    const bool aOk = (aRow < M);
    const float* aSrc = A + (size_t)(aOk ? aRow : 0) * K + sk;
    const int aDst = sr * 128 + ((sk * 2) ^ ((sr & 7) << 4));
    const unsigned short* bSrc = Wt + (size_t)(lane >> 3) * K + (lane & 7) * 8;

    // ---- prologue: stage tile 0 ----
#pragma unroll
    for (int i = 0; i < 4; ++i) {
        const int chunk = i * 8 + wid;
        __builtin_amdgcn_global_load_lds(
            (gvoid*)(bSrc + (size_t)chunk * 8 * K),
            (lvoid*)(&Bs[0][chunk * 1024]), 16, 0, 0);
    }
    {
        float4 f0 = {}, f1 = {};
        if (aOk) { f0 = *(const float4*)(aSrc); f1 = *(const float4*)(aSrc + 4); }
        uint4 uv = {cvtpk(f0.x, f0.y), cvtpk(f0.z, f0.w),
                    cvtpk(f1.x, f1.y), cvtpk(f1.z, f1.w)};
        *(uint4*)(&As[0][aDst]) = uv;
    }

    for (int k0 = 0; k0 < K; k0 += 64) {
        const int cur = (k0 >> 6) & 1;
        const int nxt = cur ^ 1;
        const bool hasNext = (k0 + 64 < K);
        __syncthreads();   // stage(cur) complete (drains vmcnt incl. DMA + lgkm)

        float4 g0 = {}, g1 = {};
        if (hasNext) {
            // issue next B-DMA + next A global loads (latency hides under MFMA)
#pragma unroll
            for (int i = 0; i < 4; ++i) {
                const int chunk = i * 8 + wid;
                __builtin_amdgcn_global_load_lds(
                    (gvoid*)(bSrc + (size_t)chunk * 8 * K + k0 + 64),
                    (lvoid*)(&Bs[nxt][chunk * 1024]), 16, 0, 0);
            }
            if (aOk) {
                g0 = *(const float4*)(aSrc + k0 + 64);
                g1 = *(const float4*)(aSrc + k0 + 64 + 4);
            }
        }

        // ---- compute(cur) ----
#pragma unroll
        for (int ks = 0; ks < 2; ++ks) {
            short8 a[2], b[4];
#pragma unroll
            for (int mf = 0; mf < 2; ++mf) {
                const int r = wm * 32 + mf * 16 + lr;
                a[mf] = *(const short8*)(&As[cur][r * 128 + (((ks * 32 + lk) * 2) ^ ((r & 7) << 4))]);
            }
#pragma unroll
            for (int nf = 0; nf < 4; ++nf) {
                const int n = wn * 64 + nf * 16 + lr;
                b[nf] = *(const short8*)(&Bs[cur][n * 128 + (((ks * 32 + lk) * 2) ^ ((n & 7) << 4))]);
            }
#pragma unroll
            for (int mf = 0; mf < 2; ++mf)
#pragma unroll
                for (int nf = 0; nf < 4; ++nf)
                    acc[mf][nf] = __builtin_amdgcn_mfma_f32_16x16x32_bf16(
                        a[mf], b[nf], acc[mf][nf], 0, 0, 0);
        }

        // ---- write-late: A(next) into LDS ----
        if (hasNext) {
            uint4 uv = {cvtpk(g0.x, g0.y), cvtpk(g0.z, g0.w),
                        cvtpk(g1.x, g1.y), cvtpk(g1.z, g1.w)};
            *(uint4*)(&As[nxt][aDst]) = uv;
        }
    }

#pragma unroll
    for (int mf = 0; mf < 2; ++mf) {
#pragma unroll
        for (int nf = 0; nf < 4; ++nf) {
            const int n = wn * 64 + nf * 16 + lr;
            const f32x4 v = acc[mf][nf];
            if (n < 128) {
#pragma unroll
                for (int j = 0; j < 4; ++j) {
                    const int m = m0 + wm * 32 + mf * 16 + (lane >> 4) * 4 + j;
                    if (m < M) outP[(size_t)m * 128 + n] = f2bf(v[j]);
                }
            } else {
                const int nl = n - 128;
                const float badd = bias[nl];
#pragma unroll
                for (int j = 0; j < 4; ++j) {
                    const int m = m0 + wm * 32 + mf * 16 + (lane >> 4) * 4 + j;
                    if (m < M) outR[(size_t)m * 128 + nl] = f2bf(v[j] + badd);
                }
            }
        }
    }
}

// ============ MFMA single GEMM (layer 2, K=256 over [ah|h]) + bias + ReLU ============
__global__ __launch_bounds__(512) void gemm_mfma_single(
    const unsigned short* __restrict__ Aa,
    const unsigned short* __restrict__ Ah,
    const unsigned short* __restrict__ Wt,
    const float* __restrict__ bias,
    unsigned short* __restrict__ outX, int M)
{
    __shared__ __align__(16) unsigned char As[128 * 128];
    __shared__ __align__(16) unsigned char Bs[128 * 128];

    const int t = threadIdx.x;
    const int m0 = blockIdx.x * 128;
    const int lane = t & 63;
    const int wid = t >> 6;
    const int wm = wid >> 1;
    const int wn = wid & 1;
    const int lr = lane & 15;
    const int lk = (lane >> 4) * 8;

    f32x4 acc[2][4] = {};

    const int sr = t >> 2;
    const int sk = (t & 3) * 16;
    const int aRow = m0 + sr;
    const bool aOk = (aRow < M);
    const int rowSafe = aOk ? aRow : 0;
    const int sw = (sr & 7) << 4;
    const unsigned short* bSrc = Wt + (size_t)(lane >> 3) * 256 + (lane & 7) * 8;

    for (int k0 = 0; k0 < 256; k0 += 64) {
#pragma unroll
        for (int i = 0; i < 2; ++i) {
            const int chunk = i * 8 + wid;
            __builtin_amdgcn_global_load_lds(
                (gvoid*)(bSrc + (size_t)chunk * 8 * 256 + k0),
                (lvoid*)(Bs + chunk * 1024), 16, 0, 0);
        }
        const unsigned short* src =
            (k0 < 128 ? Aa : Ah) + (size_t)rowSafe * 128 + (k0 & 127) + sk;
        const short8 v0 = *(const short8*)(src);
        const short8 v1 = *(const short8*)(src + 8);
        *(short8*)(As + sr * 128 + ((sk * 2) ^ sw)) = v0;
        *(short8*)(As + sr * 128 + ((sk * 2 + 16) ^ sw)) = v1;
        __syncthreads();
#pragma unroll
        for (int ks = 0; ks < 2; ++ks) {
            short8 a[2], b[4];
#pragma unroll
            for (int mf = 0; mf < 2; ++mf) {
                const int r = wm * 32 + mf * 16 + lr;
                a[mf] = *(const short8*)(As + r * 128 + (((ks * 32 + lk) * 2) ^ ((r & 7) << 4)));
            }
#pragma unroll
            for (int nf = 0; nf < 4; ++nf) {
                const int n = wn * 64 + nf * 16 + lr;
                b[nf] = *(const short8*)(Bs + n * 128 + (((ks * 32 + lk) * 2) ^ ((n & 7) << 4)));
            }
#pragma unroll
            for (int mf = 0; mf < 2; ++mf)
#pragma unroll
                for (int nf = 0; nf < 4; ++nf)
                    acc[mf][nf] = __builtin_amdgcn_mfma_f32_16x16x32_bf16(
                        a[mf], b[nf], acc[mf][nf], 0, 0, 0);
        }
        __syncthreads();
    }

#pragma unroll
    for (int mf = 0; mf < 2; ++mf) {
#pragma unroll
        for (int nf = 0; nf < 4; ++nf) {
            const int n = wn * 64 + nf * 16 + lr;
            const float bb = bias[n];
            const f32x4 v = acc[mf][nf];
#pragma unroll
            for (int j = 0; j < 4; ++j) {
                const int m = m0 + wm * 32 + mf * 16 + (lane >> 4) * 4 + j;
                if (m < M) outX[(size_t)m * 128 + n] = f2bf(fmaxf(v[j] + bb, 0.f));
            }
        }
    }
}

// ============ agg1: h = bf16(relu(R + gather(P))), 4-edge unroll ============
__global__ __launch_bounds__(256) void agg_bias_relu(
    const unsigned short* __restrict__ P, const unsigned short* __restrict__ Rbf,
    const int* __restrict__ rowptr, const int2* __restrict__ csr,
    unsigned short* __restrict__ hout, int N)
{
    const int i = blockIdx.x * 16 + (threadIdx.x >> 4);
    const int l = threadIdx.x & 15;
    if (i >= N) return;
    const int beg = rowptr[i];
    const int end = rowptr[i + 1];
    const int c = l * 8;

    float acc0[8] = {}, acc1[8] = {}, acc2[8] = {}, acc3[8] = {};
    int j = beg;
    for (; j + 3 < end; j += 4) {
        const int2 e0 = csr[j],     e1 = csr[j + 1];
        const int2 e2 = csr[j + 2], e3 = csr[j + 3];
        const short8 v0 = *(const short8*)(P + (size_t)e0.x * 128 + c);
        const short8 v1 = *(const short8*)(P + (size_t)e1.x * 128 + c);
        const short8 v2 = *(const short8*)(P + (size_t)e2.x * 128 + c);
        const short8 v3 = *(const short8*)(P + (size_t)e3.x * 128 + c);
        const float n0 = __builtin_bit_cast(float, e0.y);
        const float n1 = __builtin_bit_cast(float, e1.y);
        const float n2 = __builtin_bit_cast(float, e2.y);
        const float n3 = __builtin_bit_cast(float, e3.y);
#pragma unroll
        for (int q = 0; q < 8; ++q) {
            acc0[q] = fmaf(b2f(v0[q]), n0, acc0[q]);
            acc1[q] = fmaf(b2f(v1[q]), n1, acc1[q]);
            acc2[q] = fmaf(b2f(v2[q]), n2, acc2[q]);
            acc3[q] = fmaf(b2f(v3[q]), n3, acc3[q]);
        }
    }
    for (; j < end; ++j) {
        const int2 e0 = csr[j];
        const short8 v0 = *(const short8*)(P + (size_t)e0.x * 128 + c);
        const float n0 = __builtin_bit_cast(float, e0.y);
#pragma unroll
        for (int q = 0; q < 8; ++q) acc0[q] = fmaf(b2f(v0[q]), n0, acc0[q]);
    }
    const short8 rv = *(const short8*)(Rbf + (size_t)i * 128 + c);
    short8 ov;
#pragma unroll
    for (int q = 0; q < 8; ++q)
        ov[q] = (short)f2bf(fmaxf((acc0[q] + acc1[q]) + (acc2[q] + acc3[q]) + b2f(rv[q]), 0.f));
    *(short8*)(hout + (size_t)i * 128 + c) = ov;
}

// ============ agg2: ah = bf16(gather(h)), 4-edge unroll ============
__global__ __launch_bounds__(256) void agg_plain(
    const unsigned short* __restrict__ H,
    const int* __restrict__ rowptr, const int2* __restrict__ csr,
    unsigned short* __restrict__ ahout, int N)
{
    const int i = blockIdx.x * 16 + (threadIdx.x >> 4);
    const int l = threadIdx.x & 15;
    if (i >= N) return;
    const int beg = rowptr[i];
    const int end = rowptr[i + 1];
    const int c = l * 8;

    float acc0[8] = {}, acc1[8] = {}, acc2[8] = {}, acc3[8] = {};
    int j = beg;
    for (; j + 3 < end; j += 4) {
        const int2 e0 = csr[j],     e1 = csr[j + 1];
        const int2 e2 = csr[j + 2], e3 = csr[j + 3];
        const short8 v0 = *(const short8*)(H + (size_t)e0.x * 128 + c);
        const short8 v1 = *(const short8*)(H + (size_t)e1.x * 128 + c);
        const short8 v2 = *(const short8*)(H + (size_t)e2.x * 128 + c);
        const short8 v3 = *(const short8*)(H + (size_t)e3.x * 128 + c);
        const float n0 = __builtin_bit_cast(float, e0.y);
        const float n1 = __builtin_bit_cast(float, e1.y);
        const float n2 = __builtin_bit_cast(float, e2.y);
        const float n3 = __builtin_bit_cast(float, e3.y);
#pragma unroll
        for (int q = 0; q < 8; ++q) {
            acc0[q] = fmaf(b2f(v0[q]), n0, acc0[q]);
            acc1[q] = fmaf(b2f(v1[q]), n1, acc1[q]);
            acc2[q] = fmaf(b2f(v2[q]), n2, acc2[q]);
            acc3[q] = fmaf(b2f(v3[q]), n3, acc3[q]);
        }
    }
    for (; j < end; ++j) {
        const int2 e0 = csr[j];
        const short8 v0 = *(const short8*)(H + (size_t)e0.x * 128 + c);
        const float n0 = __builtin_bit_cast(float, e0.y);
#pragma unroll
        for (int q = 0; q < 8; ++q) acc0[q] = fmaf(b2f(v0[q]), n0, acc0[q]);
    }
    short8 ov;
#pragma unroll
    for (int q = 0; q < 8; ++q)
        ov[q] = (short)f2bf((acc0[q] + acc1[q]) + (acc2[q] + acc3[q]));
    *(short8*)(ahout + (size_t)i * 128 + c) = ov;
}

// ============ fused mean-pool (sorted batch, bf16 input, 2-way node split) + MLP ============
__global__ __launch_bounds__(256) void pool_mlp(
    const unsigned short* __restrict__ nx, const int* __restrict__ batch, int N,
    const float* __restrict__ Wl1, const float* __restrict__ bl1,
    const float* __restrict__ Wl2, const float* __restrict__ bl2,
    float* __restrict__ out)
{
    __shared__ float gxp[2][128];
    __shared__ float hid[32];
    __shared__ int rng[2];
    const int g = blockIdx.x;
    const int t = threadIdx.x;
    if (t < 2) {
        const int target = g + t;
        int lo = 0, hi = N;
        while (lo < hi) {
            int mid = (lo + hi) >> 1;
            if (batch[mid] < target) lo = mid + 1; else hi = mid;
        }
        rng[t] = lo;
    }
    __syncthreads();
    const int s = rng[0], e = rng[1];
    const int col = t & 127;
    const int half = t >> 7;
    float a0 = 0.f, a1 = 0.f, a2 = 0.f, a3 = 0.f;
    int i = s + half;
    for (; i + 6 < e; i += 8) {
        a0 += b2f((short)nx[(size_t)(i + 0) * 128 + col]);
        a1 += b2f((short)nx[(size_t)(i + 2) * 128 + col]);
        a2 += b2f((short)nx[(size_t)(i + 4) * 128 + col]);
        a3 += b2f((short)nx[(size_t)(i + 6) * 128 + col]);
    }
    for (; i < e; i += 2) a0 += b2f((short)nx[(size_t)i * 128 + col]);
    gxp[half][col] = (a0 + a1) + (a2 + a3);
    __syncthreads();
    if (t < 128) gxp[0][t] = (gxp[0][t] + gxp[1][t]) / fmaxf((float)(e - s), 1.f);
    __syncthreads();
    if (t < 32) {
        float a = bl1[t];
#pragma unroll 8
        for (int k = 0; k < 128; ++k) a = fmaf(gxp[0][k], Wl1[k * 32 + t], a);
        hid[t] = a > 0.f ? a : expm1f(a);
    }
    __syncthreads();
    if (t < 2) {
        float a = bl2[t];
#pragma unroll
        for (int k = 0; k < 32; ++k) a = fmaf(hid[k], Wl2[k * 2 + t], a);
        out[(size_t)g * 2 + t] = a;
    }
}

extern "C" void kernel_launch(void* const* d_in, const int* in_sizes, int n_in,
                              void* d_out, int out_size, void* d_ws, size_t ws_size,
                              hipStream_t stream)
{
    const float* x     = (const float*)d_in[0];
    const int*   ei    = (const int*)d_in[1];
    const float* ea    = (const float*)d_in[2];
    const int*   batch = (const int*)d_in[3];
    const float* W1i   = (const float*)d_in[5];
    const float* W1r   = (const float*)d_in[6];
    const float* b1    = (const float*)d_in[7];
    const float* W2i   = (const float*)d_in[8];
    const float* W2r   = (const float*)d_in[9];
    const float* b2    = (const float*)d_in[10];
    const float* Wl1   = (const float*)d_in[11];
    const float* bl1   = (const float*)d_in[12];
    const float* Wl2   = (const float*)d_in[13];
    const float* bl2   = (const float*)d_in[14];

    const int N = in_sizes[0] / 768;
    const int E = in_sizes[2];
    const int G = out_size / 2;

    char* ws = (char*)d_ws;
    size_t off = 0;
    auto alloc = [&](size_t bytes) -> char* {
        char* p = ws + off;
        off = (off + bytes + 255) & ~(size_t)255;
        return p;
    };
    unsigned long long* packed = (unsigned long long*)alloc((size_t)NC * N * 8);
    int*   rank    = (int*)alloc((size_t)E * 4);
    int*   wpb     = (int*)alloc((size_t)NC * N * 4);
    float* dinv    = (float*)alloc((size_t)N * 4);
    int*   rowptr  = (int*)alloc((size_t)(N + 1) * 4);
    int*   blkoff  = (int*)alloc((size_t)1056 * 4);
    int*   blkdum  = (int*)alloc((size_t)4 * 4);
    int2*  csr     = (int2*)alloc((size_t)E * 8);
    unsigned short* P1   = (unsigned short*)alloc((size_t)N * 128 * 2);
    unsigned short* R1   = (unsigned short*)alloc((size_t)N * 128 * 2);
    unsigned short* hbf  = (unsigned short*)alloc((size_t)N * 128 * 2);
    unsigned short* ahb  = (unsigned short*)alloc((size_t)N * 128 * 2);
    unsigned short* nxb  = (unsigned short*)alloc((size_t)N * 128 * 2);
    unsigned short* W1t  = (unsigned short*)alloc((size_t)256 * 768 * 2);
    unsigned short* W2t  = (unsigned short*)alloc((size_t)128 * 256 * 2);

    const int eBlocks = (E + 255) / 256;
    const int nb      = (N + 1023) / 1024;
    const int nBlocks = (N + 255) / 256;
    const int aBlocks = (N + 15) / 16;

    // ---- CSR build + weight convert ----
    hipMemsetAsync(packed, 0, (size_t)NC * N * 8, stream);
    deg_hist_kernel<<<eBlocks, 256, 0, stream>>>(ei, ea, packed, rank, N, E);
    scan1p_kernel<<<nb, 256, 0, stream>>>(packed, rowptr, blkoff, N);
    scan1_kernel<<<1, 256, 0, stream>>>(blkoff, blkoff, blkdum, nb);
    scan3_kernel<<<nBlocks, 256, 0, stream>>>(rowptr, blkoff, wpb, packed, dinv, N, E);
    place_kernel<<<eBlocks, 256, 0, stream>>>(ei, ea, dinv, wpb, rank, csr, N, E);
    conv_weights<<<(256 * 768 + 128 * 256 + 255) / 256, 256, 0, stream>>>(
        W1i, W1r, W2i, W2r, W1t, W2t);

    // ---- layer 1: P1 = bf16(x@W1i), R1 = bf16(x@W1r + b1) ----
    gemm_mfma_dual<<<(N + 63) / 64, 512, 0, stream>>>(x, W1t, b1, P1, R1, N, 768);
    agg_bias_relu<<<aBlocks, 256, 0, stream>>>(P1, R1, rowptr, csr, hbf, N);

    // ---- layer 2: ah = bf16(gather(h)); node_x = bf16(relu([ah|h]@W2 + b2)) ----
    agg_plain<<<aBlocks, 256, 0, stream>>>(hbf, rowptr, csr, ahb, N);
    gemm_mfma_single<<<(N + 127) / 128, 512, 0, stream>>>(ahb, hbf, W2t, b2, nxb, N);

    // ---- fused pool + head ----
    pool_mlp<<<G, 256, 0, stream>>>(nxb, batch, N, Wl1, bl1, Wl2, bl2, (float*)d_out);
}

// Round 11
// 380.674 us; speedup vs baseline: 16.7321x; 1.1307x over previous
//
#include <hip/hip_runtime.h>
#include <hip/hip_bf16.h>
#include <math.h>

typedef __attribute__((ext_vector_type(8))) short short8;
typedef __attribute__((ext_vector_type(4))) float f32x4;
typedef __attribute__((ext_vector_type(2))) float f32x2;
typedef __attribute__((address_space(1))) const void gvoid;
typedef __attribute__((address_space(3))) void lvoid;

#define NC 8   // histogram privatization copies

__device__ __forceinline__ unsigned short f2bf(float f) {
    unsigned int u = __builtin_bit_cast(unsigned int, f);
    return (unsigned short)((u + 0x7fffu + ((u >> 16) & 1u)) >> 16);   // RNE
}
__device__ __forceinline__ float b2f(short s) {
    return __builtin_bit_cast(float, ((unsigned int)(unsigned short)s) << 16);
}
__device__ __forceinline__ unsigned int cvtpk(float lo, float hi) {
    unsigned int r;
    asm("v_cvt_pk_bf16_f32 %0, %1, %2" : "=v"(r) : "v"(lo), "v"(hi));
    return r;
}
// fp8 e4m3 (OCP) HW converts — word-select must be a LITERAL constant
__device__ __forceinline__ unsigned int pk8_lo(float a, float b, unsigned int old) {
    return (unsigned int)__builtin_amdgcn_cvt_pk_fp8_f32(a, b, (int)old, false);
}
__device__ __forceinline__ unsigned int pk8_hi(float a, float b, unsigned int old) {
    return (unsigned int)__builtin_amdgcn_cvt_pk_fp8_f32(a, b, (int)old, true);
}
__device__ __forceinline__ f32x2 up8_lo(unsigned int v) {
    return __builtin_amdgcn_cvt_pk_f32_fp8((int)v, false);
}
__device__ __forceinline__ f32x2 up8_hi(unsigned int v) {
    return __builtin_amdgcn_cvt_pk_f32_fp8((int)v, true);
}

// ============ hist: privatized u64 packed (cnt<<42 | fixpt-deg); rank from return ============
__global__ __launch_bounds__(256) void deg_hist_kernel(
    const int* __restrict__ ei, const float* __restrict__ ea,
    unsigned long long* __restrict__ packed, int* __restrict__ rank, int N, int E)
{
    int e = blockIdx.x * 256 + threadIdx.x;
    if (e >= E) return;
    const int copy = blockIdx.x & (NC - 1);
    int c = ei[(size_t)E + e];
    unsigned long long fx = (unsigned long long)(ea[e] * 1048576.0f + 0.5f);
    unsigned long long old = atomicAdd(&packed[(size_t)copy * N + c], (1ULL << 42) | fx);
    rank[e] = (int)(old >> 42);
}

// ============ scan pass 1: per-node total count over NC copies ============
__global__ __launch_bounds__(256) void scan1p_kernel(
    const unsigned long long* __restrict__ packed, int* __restrict__ out,
    int* __restrict__ blksum, int n)
{
    __shared__ int part[256];
    const int t = threadIdx.x;
    const int base = blockIdx.x * 1024 + t * 4;
    int v[4];
#pragma unroll
    for (int q = 0; q < 4; ++q) {
        int s = 0;
        if (base + q < n) {
#pragma unroll
            for (int p = 0; p < NC; ++p)
                s += (int)(packed[(size_t)p * n + base + q] >> 42);
        }
        v[q] = s;
    }
    const int s = v[0] + v[1] + v[2] + v[3];
    part[t] = s;
    __syncthreads();
    for (int off = 1; off < 256; off <<= 1) {
        int x = (t >= off) ? part[t - off] : 0;
        __syncthreads();
        part[t] += x;
        __syncthreads();
    }
    if (t == 255) blksum[blockIdx.x] = part[255];
    int run = part[t] - s;
#pragma unroll
    for (int q = 0; q < 4; ++q) {
        if (base + q < n) out[base + q] = run;
        run += v[q];
    }
}

// ============ scan pass over block sums ============
__global__ __launch_bounds__(256) void scan1_kernel(
    const int* __restrict__ in, int* __restrict__ out, int* __restrict__ blksum, int n)
{
    __shared__ int part[256];
    const int t = threadIdx.x;
    const int base = blockIdx.x * 1024 + t * 4;
    int v[4];
#pragma unroll
    for (int q = 0; q < 4; ++q) v[q] = (base + q < n) ? in[base + q] : 0;
    const int s = v[0] + v[1] + v[2] + v[3];
    part[t] = s;
    __syncthreads();
    for (int off = 1; off < 256; off <<= 1) {
        int x = (t >= off) ? part[t - off] : 0;
        __syncthreads();
        part[t] += x;
        __syncthreads();
    }
    if (t == 255) blksum[blockIdx.x] = part[255];
    int run = part[t] - s;
#pragma unroll
    for (int q = 0; q < 4; ++q) {
        if (base + q < n) out[base + q] = run;
        run += v[q];
    }
}

// ============ finalize: rowptr += blkoff; per-copy bases; dinv ============
__global__ __launch_bounds__(256) void scan3_kernel(
    int* __restrict__ rowptr, const int* __restrict__ blkoff,
    int* __restrict__ wpb, const unsigned long long* __restrict__ packed,
    float* __restrict__ dinv, int n, int Etot)
{
    int i = blockIdx.x * 256 + threadIdx.x;
    if (i == 0) rowptr[n] = Etot;
    if (i >= n) return;
    int base = rowptr[i] + blkoff[i >> 10];
    rowptr[i] = base;
    unsigned long long degfx = 0;
    int acc = base;
#pragma unroll
    for (int p = 0; p < NC; ++p) {
        unsigned long long v = packed[(size_t)p * n + i];
        wpb[(size_t)p * n + i] = acc;
        acc += (int)(v >> 42);
        degfx += v & ((1ULL << 42) - 1);
    }
    dinv[i] = (degfx > 0) ? rsqrtf((float)degfx * 9.5367431640625e-7f) : 0.f;
}

// ============ edge placement: NO atomics (base + rank) ============
__global__ __launch_bounds__(256) void place_kernel(
    const int* __restrict__ ei, const float* __restrict__ ea,
    const float* __restrict__ dinv, const int* __restrict__ wpb,
    const int* __restrict__ rank, int2* __restrict__ csr, int N, int E)
{
    int e = blockIdx.x * 256 + threadIdx.x;
    if (e >= E) return;
    const int copy = blockIdx.x & (NC - 1);
    int r = ei[e];
    int c = ei[(size_t)E + e];
    float nm = dinv[r] * ea[e] * dinv[c];
    int pos = wpb[(size_t)copy * N + c] + rank[e];
    int2 rec;
    rec.x = r;
    rec.y = __builtin_bit_cast(int, nm);
    csr[pos] = rec;
}

// ============ weight pre-convert, PRE-SWIZZLED for global_load_lds ============
__global__ __launch_bounds__(256) void conv_weights(
    const float* __restrict__ W1i, const float* __restrict__ W1r,
    const float* __restrict__ W2i, const float* __restrict__ W2r,
    unsigned short* __restrict__ W1t, unsigned short* __restrict__ W2t)
{
    int id = blockIdx.x * 256 + threadIdx.x;
    if (id < 256 * 768) {
        int n = id / 768, j = id % 768;
        int k = (j & ~63) | ((((j >> 3) & 7) ^ (n & 7)) << 3) | (j & 7);
        float v = (n < 128) ? W1i[k * 128 + n] : W1r[k * 128 + (n - 128)];
        W1t[id] = f2bf(v);
    } else {
        int id2 = id - 256 * 768;
        if (id2 < 128 * 256) {
            int n = id2 >> 8, j = id2 & 255;
            int k = (j & ~63) | ((((j >> 3) & 7) ^ (n & 7)) << 3) | (j & 7);
            float v = (k < 128) ? W2i[k * 128 + n] : W2r[(k - 128) * 128 + n];
            W2t[id2] = f2bf(v);
        }
    }
}

// ============ MFMA dual GEMM (layer 1), double-buffered ============
// outP: fp8 e4m3 (for agg1 gather); outR: bf16.
__global__ __launch_bounds__(512) void gemm_mfma_dual(
    const float* __restrict__ A, const unsigned short* __restrict__ Wt,
    const float* __restrict__ bias, unsigned char* __restrict__ outP8,
    unsigned short* __restrict__ outR, int M, int K)
{
    __shared__ __align__(16) unsigned char As[2][64 * 128];
    __shared__ __align__(16) unsigned char Bs[2][256 * 128];

    const int t = threadIdx.x;
    const int m0 = blockIdx.x * 64;
    const int lane = t & 63;
    const int wid = t >> 6;
    const int wm = wid >> 2;
    const int wn = wid & 3;
    const int lr = lane & 15;
    const int lk = (lane >> 4) * 8;

    f32x4 acc[2][4] = {};

    const int sr = t >> 3;
    const int sk = (t & 7) * 8;
    const int aRow = m0 + sr;
    const bool aOk = (aRow < M);
    const float* aSrc = A + (size_t)(aOk ? aRow : 0) * K + sk;
    const int aDst = sr * 128 + ((sk * 2) ^ ((sr & 7) << 4));
    const unsigned short* bSrc = Wt + (size_t)(lane >> 3) * K + (lane & 7) * 8;

    // ---- prologue: stage tile 0 ----
#pragma unroll
    for (int i = 0; i < 4; ++i) {
        const int chunk = i * 8 + wid;
        __builtin_amdgcn_global_load_lds(
            (gvoid*)(bSrc + (size_t)chunk * 8 * K),
            (lvoid*)(&Bs[0][chunk * 1024]), 16, 0, 0);
    }
    {
        float4 f0 = {}, f1 = {};
        if (aOk) { f0 = *(const float4*)(aSrc); f1 = *(const float4*)(aSrc + 4); }
        uint4 uv = {cvtpk(f0.x, f0.y), cvtpk(f0.z, f0.w),
                    cvtpk(f1.x, f1.y), cvtpk(f1.z, f1.w)};
        *(uint4*)(&As[0][aDst]) = uv;
    }

    for (int k0 = 0; k0 < K; k0 += 64) {
        const int cur = (k0 >> 6) & 1;
        const int nxt = cur ^ 1;
        const bool hasNext = (k0 + 64 < K);
        __syncthreads();

        float4 g0 = {}, g1 = {};
        if (hasNext) {
#pragma unroll
            for (int i = 0; i < 4; ++i) {
                const int chunk = i * 8 + wid;
                __builtin_amdgcn_global_load_lds(
                    (gvoid*)(bSrc + (size_t)chunk * 8 * K + k0 + 64),
                    (lvoid*)(&Bs[nxt][chunk * 1024]), 16, 0, 0);
            }
            if (aOk) {
                g0 = *(const float4*)(aSrc + k0 + 64);
                g1 = *(const float4*)(aSrc + k0 + 64 + 4);
            }
        }

#pragma unroll
        for (int ks = 0; ks < 2; ++ks) {
            short8 a[2], b[4];
#pragma unroll
            for (int mf = 0; mf < 2; ++mf) {
                const int r = wm * 32 + mf * 16 + lr;
                a[mf] = *(const short8*)(&As[cur][r * 128 + (((ks * 32 + lk) * 2) ^ ((r & 7) << 4))]);
            }
#pragma unroll
            for (int nf = 0; nf < 4; ++nf) {
                const int n = wn * 64 + nf * 16 + lr;
                b[nf] = *(const short8*)(&Bs[cur][n * 128 + (((ks * 32 + lk) * 2) ^ ((n & 7) << 4))]);
            }
#pragma unroll
            for (int mf = 0; mf < 2; ++mf)
#pragma unroll
                for (int nf = 0; nf < 4; ++nf)
                    acc[mf][nf] = __builtin_amdgcn_mfma_f32_16x16x32_bf16(
                        a[mf], b[nf], acc[mf][nf], 0, 0, 0);
        }

        if (hasNext) {
            uint4 uv = {cvtpk(g0.x, g0.y), cvtpk(g0.z, g0.w),
                        cvtpk(g1.x, g1.y), cvtpk(g1.z, g1.w)};
            *(uint4*)(&As[nxt][aDst]) = uv;
        }
    }

#pragma unroll
    for (int mf = 0; mf < 2; ++mf) {
#pragma unroll
        for (int nf = 0; nf < 4; ++nf) {
            const int n = wn * 64 + nf * 16 + lr;
            const f32x4 v = acc[mf][nf];
            const int mb = m0 + wm * 32 + mf * 16 + (lane >> 4) * 4;
            if (n < 128) {
                const unsigned int u01 = pk8_lo(v[0], v[1], 0u);
                const unsigned int u23 = pk8_lo(v[2], v[3], 0u);
                if (mb + 0 < M) outP8[(size_t)(mb + 0) * 128 + n] = (unsigned char)(u01);
                if (mb + 1 < M) outP8[(size_t)(mb + 1) * 128 + n] = (unsigned char)(u01 >> 8);
                if (mb + 2 < M) outP8[(size_t)(mb + 2) * 128 + n] = (unsigned char)(u23);
                if (mb + 3 < M) outP8[(size_t)(mb + 3) * 128 + n] = (unsigned char)(u23 >> 8);
            } else {
                const int nl = n - 128;
                const float badd = bias[nl];
#pragma unroll
                for (int j = 0; j < 4; ++j) {
                    if (mb + j < M) outR[(size_t)(mb + j) * 128 + nl] = f2bf(v[j] + badd);
                }
            }
        }
    }
}

// ============ MFMA single GEMM (layer 2, K=256 over [ah|h]) + bias + ReLU ============
__global__ __launch_bounds__(512) void gemm_mfma_single(
    const unsigned short* __restrict__ Aa,
    const unsigned short* __restrict__ Ah,
    const unsigned short* __restrict__ Wt,
    const float* __restrict__ bias,
    unsigned short* __restrict__ outX, int M)
{
    __shared__ __align__(16) unsigned char As[128 * 128];
    __shared__ __align__(16) unsigned char Bs[128 * 128];

    const int t = threadIdx.x;
    const int m0 = blockIdx.x * 128;
    const int lane = t & 63;
    const int wid = t >> 6;
    const int wm = wid >> 1;
    const int wn = wid & 1;
    const int lr = lane & 15;
    const int lk = (lane >> 4) * 8;

    f32x4 acc[2][4] = {};

    const int sr = t >> 2;
    const int sk = (t & 3) * 16;
    const int aRow = m0 + sr;
    const bool aOk = (aRow < M);
    const int rowSafe = aOk ? aRow : 0;
    const int sw = (sr & 7) << 4;
    const unsigned short* bSrc = Wt + (size_t)(lane >> 3) * 256 + (lane & 7) * 8;

    for (int k0 = 0; k0 < 256; k0 += 64) {
#pragma unroll
        for (int i = 0; i < 2; ++i) {
            const int chunk = i * 8 + wid;
            __builtin_amdgcn_global_load_lds(
                (gvoid*)(bSrc + (size_t)chunk * 8 * 256 + k0),
                (lvoid*)(Bs + chunk * 1024), 16, 0, 0);
        }
        const unsigned short* src =
            (k0 < 128 ? Aa : Ah) + (size_t)rowSafe * 128 + (k0 & 127) + sk;
        const short8 v0 = *(const short8*)(src);
        const short8 v1 = *(const short8*)(src + 8);
        *(short8*)(As + sr * 128 + ((sk * 2) ^ sw)) = v0;
        *(short8*)(As + sr * 128 + ((sk * 2 + 16) ^ sw)) = v1;
        __syncthreads();
#pragma unroll
        for (int ks = 0; ks < 2; ++ks) {
            short8 a[2], b[4];
#pragma unroll
            for (int mf = 0; mf < 2; ++mf) {
                const int r = wm * 32 + mf * 16 + lr;
                a[mf] = *(const short8*)(As + r * 128 + (((ks * 32 + lk) * 2) ^ ((r & 7) << 4)));
            }
#pragma unroll
            for (int nf = 0; nf < 4; ++nf) {
                const int n = wn * 64 + nf * 16 + lr;
                b[nf] = *(const short8*)(Bs + n * 128 + (((ks * 32 + lk) * 2) ^ ((n & 7) << 4)));
            }
#pragma unroll
            for (int mf = 0; mf < 2; ++mf)
#pragma unroll
                for (int nf = 0; nf < 4; ++nf)
                    acc[mf][nf] = __builtin_amdgcn_mfma_f32_16x16x32_bf16(
                        a[mf], b[nf], acc[mf][nf], 0, 0, 0);
        }
        __syncthreads();
    }

#pragma unroll
    for (int mf = 0; mf < 2; ++mf) {
#pragma unroll
        for (int nf = 0; nf < 4; ++nf) {
            const int n = wn * 64 + nf * 16 + lr;
            const float bb = bias[n];
            const f32x4 v = acc[mf][nf];
#pragma unroll
            for (int j = 0; j < 4; ++j) {
                const int m = m0 + wm * 32 + mf * 16 + (lane >> 4) * 4 + j;
                if (m < M) outX[(size_t)m * 128 + n] = f2bf(fmaxf(v[j] + bb, 0.f));
            }
        }
    }
}

// ============ agg1: gather fp8 P -> h (bf16 for GEMM + fp8 for agg2) ============
__global__ __launch_bounds__(256) void agg_bias_relu(
    const unsigned char* __restrict__ P8, const unsigned short* __restrict__ Rbf,
    const int* __restrict__ rowptr, const int2* __restrict__ csr,
    unsigned short* __restrict__ hout, unsigned char* __restrict__ h8out, int N)
{
    const int i = blockIdx.x * 16 + (threadIdx.x >> 4);
    const int l = threadIdx.x & 15;
    if (i >= N) return;
    const int beg = rowptr[i];
    const int end = rowptr[i + 1];
    const int c = l * 8;

    float acc0[8] = {}, acc1[8] = {}, acc2[8] = {}, acc3[8] = {};
    int j = beg;
    for (; j + 3 < end; j += 4) {
        const int2 e0 = csr[j],     e1 = csr[j + 1];
        const int2 e2 = csr[j + 2], e3 = csr[j + 3];
        const uint2 u0 = *(const uint2*)(P8 + (size_t)e0.x * 128 + c);
        const uint2 u1 = *(const uint2*)(P8 + (size_t)e1.x * 128 + c);
        const uint2 u2 = *(const uint2*)(P8 + (size_t)e2.x * 128 + c);
        const uint2 u3 = *(const uint2*)(P8 + (size_t)e3.x * 128 + c);
        const float n0 = __builtin_bit_cast(float, e0.y);
        const float n1 = __builtin_bit_cast(float, e1.y);
        const float n2 = __builtin_bit_cast(float, e2.y);
        const float n3 = __builtin_bit_cast(float, e3.y);
        {
            const f32x2 p0 = up8_lo(u0.x), p1 = up8_hi(u0.x);
            const f32x2 p2 = up8_lo(u0.y), p3 = up8_hi(u0.y);
            acc0[0] = fmaf(p0.x, n0, acc0[0]); acc0[1] = fmaf(p0.y, n0, acc0[1]);
            acc0[2] = fmaf(p1.x, n0, acc0[2]); acc0[3] = fmaf(p1.y, n0, acc0[3]);
            acc0[4] = fmaf(p2.x, n0, acc0[4]); acc0[5] = fmaf(p2.y, n0, acc0[5]);
            acc0[6] = fmaf(p3.x, n0, acc0[6]); acc0[7] = fmaf(p3.y, n0, acc0[7]);
        }
        {
            const f32x2 p0 = up8_lo(u1.x), p1 = up8_hi(u1.x);
            const f32x2 p2 = up8_lo(u1.y), p3 = up8_hi(u1.y);
            acc1[0] = fmaf(p0.x, n1, acc1[0]); acc1[1] = fmaf(p0.y, n1, acc1[1]);
            acc1[2] = fmaf(p1.x, n1, acc1[2]); acc1[3] = fmaf(p1.y, n1, acc1[3]);
            acc1[4] = fmaf(p2.x, n1, acc1[4]); acc1[5] = fmaf(p2.y, n1, acc1[5]);
            acc1[6] = fmaf(p3.x, n1, acc1[6]); acc1[7] = fmaf(p3.y, n1, acc1[7]);
        }
        {
            const f32x2 p0 = up8_lo(u2.x), p1 = up8_hi(u2.x);
            const f32x2 p2 = up8_lo(u2.y), p3 = up8_hi(u2.y);
            acc2[0] = fmaf(p0.x, n2, acc2[0]); acc2[1] = fmaf(p0.y, n2, acc2[1]);
            acc2[2] = fmaf(p1.x, n2, acc2[2]); acc2[3] = fmaf(p1.y, n2, acc2[3]);
            acc2[4] = fmaf(p2.x, n2, acc2[4]); acc2[5] = fmaf(p2.y, n2, acc2[5]);
            acc2[6] = fmaf(p3.x, n2, acc2[6]); acc2[7] = fmaf(p3.y, n2, acc2[7]);
        }
        {
            const f32x2 p0 = up8_lo(u3.x), p1 = up8_hi(u3.x);
            const f32x2 p2 = up8_lo(u3.y), p3 = up8_hi(u3.y);
            acc3[0] = fmaf(p0.x, n3, acc3[0]); acc3[1] = fmaf(p0.y, n3, acc3[1]);
            acc3[2] = fmaf(p1.x, n3, acc3[2]); acc3[3] = fmaf(p1.y, n3, acc3[3]);
            acc3[4] = fmaf(p2.x, n3, acc3[4]); acc3[5] = fmaf(p2.y, n3, acc3[5]);
            acc3[6] = fmaf(p3.x, n3, acc3[6]); acc3[7] = fmaf(p3.y, n3, acc3[7]);
        }
    }
    for (; j < end; ++j) {
        const int2 e0 = csr[j];
        const uint2 u0 = *(const uint2*)(P8 + (size_t)e0.x * 128 + c);
        const float n0 = __builtin_bit_cast(float, e0.y);
        const f32x2 p0 = up8_lo(u0.x), p1 = up8_hi(u0.x);
        const f32x2 p2 = up8_lo(u0.y), p3 = up8_hi(u0.y);
        acc0[0] = fmaf(p0.x, n0, acc0[0]); acc0[1] = fmaf(p0.y, n0, acc0[1]);
        acc0[2] = fmaf(p1.x, n0, acc0[2]); acc0[3] = fmaf(p1.y, n0, acc0[3]);
        acc0[4] = fmaf(p2.x, n0, acc0[4]); acc0[5] = fmaf(p2.y, n0, acc0[5]);
        acc0[6] = fmaf(p3.x, n0, acc0[6]); acc0[7] = fmaf(p3.y, n0, acc0[7]);
    }
    const short8 rv = *(const short8*)(Rbf + (size_t)i * 128 + c);
    float s[8];
    short8 ov;
#pragma unroll
    for (int q = 0; q < 8; ++q) {
        s[q] = fmaxf((acc0[q] + acc1[q]) + (acc2[q] + acc3[q]) + b2f(rv[q]), 0.f);
        ov[q] = (short)f2bf(s[q]);
    }
    *(short8*)(hout + (size_t)i * 128 + c) = ov;
    unsigned int w0 = 0, w1 = 0;
    w0 = pk8_lo(s[0], s[1], w0); w0 = pk8_hi(s[2], s[3], w0);
    w1 = pk8_lo(s[4], s[5], w1); w1 = pk8_hi(s[6], s[7], w1);
    uint2 wv = {w0, w1};
    *(uint2*)(h8out + (size_t)i * 128 + c) = wv;
}

// ============ agg2: ah = bf16(gather(fp8 h)) ============
__global__ __launch_bounds__(256) void agg_plain(
    const unsigned char* __restrict__ H8,
    const int* __restrict__ rowptr, const int2* __restrict__ csr,
    unsigned short* __restrict__ ahout, int N)
{
    const int i = blockIdx.x * 16 + (threadIdx.x >> 4);
    const int l = threadIdx.x & 15;
    if (i >= N) return;
    const int beg = rowptr[i];
    const int end = rowptr[i + 1];
    const int c = l * 8;

    float acc0[8] = {}, acc1[8] = {}, acc2[8] = {}, acc3[8] = {};
    int j = beg;
    for (; j + 3 < end; j += 4) {
        const int2 e0 = csr[j],     e1 = csr[j + 1];
        const int2 e2 = csr[j + 2], e3 = csr[j + 3];
        const uint2 u0 = *(const uint2*)(H8 + (size_t)e0.x * 128 + c);
        const uint2 u1 = *(const uint2*)(H8 + (size_t)e1.x * 128 + c);
        const uint2 u2 = *(const uint2*)(H8 + (size_t)e2.x * 128 + c);
        const uint2 u3 = *(const uint2*)(H8 + (size_t)e3.x * 128 + c);
        const float n0 = __builtin_bit_cast(float, e0.y);
        const float n1 = __builtin_bit_cast(float, e1.y);
        const float n2 = __builtin_bit_cast(float, e2.y);
        const float n3 = __builtin_bit_cast(float, e3.y);
        {
            const f32x2 p0 = up8_lo(u0.x), p1 = up8_hi(u0.x);
            const f32x2 p2 = up8_lo(u0.y), p3 = up8_hi(u0.y);
            acc0[0] = fmaf(p0.x, n0, acc0[0]); acc0[1] = fmaf(p0.y, n0, acc0[1]);
            acc0[2] = fmaf(p1.x, n0, acc0[2]); acc0[3] = fmaf(p1.y, n0, acc0[3]);
            acc0[4] = fmaf(p2.x, n0, acc0[4]); acc0[5] = fmaf(p2.y, n0, acc0[5]);
            acc0[6] = fmaf(p3.x, n0, acc0[6]); acc0[7] = fmaf(p3.y, n0, acc0[7]);
        }
        {
            const f32x2 p0 = up8_lo(u1.x), p1 = up8_hi(u1.x);
            const f32x2 p2 = up8_lo(u1.y), p3 = up8_hi(u1.y);
            acc1[0] = fmaf(p0.x, n1, acc1[0]); acc1[1] = fmaf(p0.y, n1, acc1[1]);
            acc1[2] = fmaf(p1.x, n1, acc1[2]); acc1[3] = fmaf(p1.y, n1, acc1[3]);
            acc1[4] = fmaf(p2.x, n1, acc1[4]); acc1[5] = fmaf(p2.y, n1, acc1[5]);
            acc1[6] = fmaf(p3.x, n1, acc1[6]); acc1[7] = fmaf(p3.y, n1, acc1[7]);
        }
        {
            const f32x2 p0 = up8_lo(u2.x), p1 = up8_hi(u2.x);
            const f32x2 p2 = up8_lo(u2.y), p3 = up8_hi(u2.y);
            acc2[0] = fmaf(p0.x, n2, acc2[0]); acc2[1] = fmaf(p0.y, n2, acc2[1]);
            acc2[2] = fmaf(p1.x, n2, acc2[2]); acc2[3] = fmaf(p1.y, n2, acc2[3]);
            acc2[4] = fmaf(p2.x, n2, acc2[4]); acc2[5] = fmaf(p2.y, n2, acc2[5]);
            acc2[6] = fmaf(p3.x, n2, acc2[6]); acc2[7] = fmaf(p3.y, n2, acc2[7]);
        }
        {
            const f32x2 p0 = up8_lo(u3.x), p1 = up8_hi(u3.x);
            const f32x2 p2 = up8_lo(u3.y), p3 = up8_hi(u3.y);
            acc3[0] = fmaf(p0.x, n3, acc3[0]); acc3[1] = fmaf(p0.y, n3, acc3[1]);
            acc3[2] = fmaf(p1.x, n3, acc3[2]); acc3[3] = fmaf(p1.y, n3, acc3[3]);
            acc3[4] = fmaf(p2.x, n3, acc3[4]); acc3[5] = fmaf(p2.y, n3, acc3[5]);
            acc3[6] = fmaf(p3.x, n3, acc3[6]); acc3[7] = fmaf(p3.y, n3, acc3[7]);
        }
    }
    for (; j < end; ++j) {
        const int2 e0 = csr[j];
        const uint2 u0 = *(const uint2*)(H8 + (size_t)e0.x * 128 + c);
        const float n0 = __builtin_bit_cast(float, e0.y);
        const f32x2 p0 = up8_lo(u0.x), p1 = up8_hi(u0.x);
        const f32x2 p2 = up8_lo(u0.y), p3 = up8_hi(u0.y);
        acc0[0] = fmaf(p0.x, n0, acc0[0]); acc0[1] = fmaf(p0.y, n0, acc0[1]);
        acc0[2] = fmaf(p1.x, n0, acc0[2]); acc0[3] = fmaf(p1.y, n0, acc0[3]);
        acc0[4] = fmaf(p2.x, n0, acc0[4]); acc0[5] = fmaf(p2.y, n0, acc0[5]);
        acc0[6] = fmaf(p3.x, n0, acc0[6]); acc0[7] = fmaf(p3.y, n0, acc0[7]);
    }
    short8 ov;
#pragma unroll
    for (int q = 0; q < 8; ++q)
        ov[q] = (short)f2bf((acc0[q] + acc1[q]) + (acc2[q] + acc3[q]));
    *(short8*)(ahout + (size_t)i * 128 + c) = ov;
}

// ============ fused mean-pool (sorted batch, bf16, 4 node-streams, 4B loads) + MLP ============
__global__ __launch_bounds__(256) void pool_mlp(
    const unsigned short* __restrict__ nx, const int* __restrict__ batch, int N,
    const float* __restrict__ Wl1, const float* __restrict__ bl1,
    const float* __restrict__ Wl2, const float* __restrict__ bl2,
    float* __restrict__ out)
{
    __shared__ float gxp[4][128];
    __shared__ float hid[32];
    __shared__ int rng[2];
    const int g = blockIdx.x;
    const int t = threadIdx.x;
    if (t < 2) {
        const int target = g + t;
        int lo = 0, hi = N;
        while (lo < hi) {
            int mid = (lo + hi) >> 1;
            if (batch[mid] < target) lo = mid + 1; else hi = mid;
        }
        rng[t] = lo;
    }
    __syncthreads();
    const int s = rng[0], e = rng[1];
    const int pr = t & 63;
    const int strm = t >> 6;
    float a0 = 0.f, b0 = 0.f, a1 = 0.f, b1 = 0.f;
    int i = s + strm;
    for (; i + 4 < e; i += 8) {
        const unsigned int u = *(const unsigned int*)&nx[(size_t)i * 128 + pr * 2];
        const unsigned int v = *(const unsigned int*)&nx[(size_t)(i + 4) * 128 + pr * 2];
        a0 += b2f((short)(u & 0xffff)); b0 += b2f((short)(u >> 16));
        a1 += b2f((short)(v & 0xffff)); b1 += b2f((short)(v >> 16));
    }
    if (i < e) {
        const unsigned int u = *(const unsigned int*)&nx[(size_t)i * 128 + pr * 2];
        a0 += b2f((short)(u & 0xffff)); b0 += b2f((short)(u >> 16));
    }
    gxp[strm][pr * 2] = a0 + a1;
    gxp[strm][pr * 2 + 1] = b0 + b1;
    __syncthreads();
    if (t < 128) {
        gxp[0][t] = ((gxp[0][t] + gxp[1][t]) + (gxp[2][t] + gxp[3][t]))
                    / fmaxf((float)(e - s), 1.f);
    }
    __syncthreads();
    if (t < 32) {
        float a = bl1[t];
#pragma unroll 8
        for (int k = 0; k < 128; ++k) a = fmaf(gxp[0][k], Wl1[k * 32 + t], a);
        hid[t] = a > 0.f ? a : expm1f(a);
    }
    __syncthreads();
    if (t < 2) {
        float a = bl2[t];
#pragma unroll
        for (int k = 0; k < 32; ++k) a = fmaf(hid[k], Wl2[k * 2 + t], a);
        out[(size_t)g * 2 + t] = a;
    }
}

extern "C" void kernel_launch(void* const* d_in, const int* in_sizes, int n_in,
                              void* d_out, int out_size, void* d_ws, size_t ws_size,
                              hipStream_t stream)
{
    const float* x     = (const float*)d_in[0];
    const int*   ei    = (const int*)d_in[1];
    const float* ea    = (const float*)d_in[2];
    const int*   batch = (const int*)d_in[3];
    const float* W1i   = (const float*)d_in[5];
    const float* W1r   = (const float*)d_in[6];
    const float* b1    = (const float*)d_in[7];
    const float* W2i   = (const float*)d_in[8];
    const float* W2r   = (const float*)d_in[9];
    const float* b2    = (const float*)d_in[10];
    const float* Wl1   = (const float*)d_in[11];
    const float* bl1   = (const float*)d_in[12];
    const float* Wl2   = (const float*)d_in[13];
    const float* bl2   = (const float*)d_in[14];

    const int N = in_sizes[0] / 768;
    const int E = in_sizes[2];
    const int G = out_size / 2;

    char* ws = (char*)d_ws;
    size_t off = 0;
    auto alloc = [&](size_t bytes) -> char* {
        char* p = ws + off;
        off = (off + bytes + 255) & ~(size_t)255;
        return p;
    };
    unsigned long long* packed = (unsigned long long*)alloc((size_t)NC * N * 8);
    int*   rank    = (int*)alloc((size_t)E * 4);
    int*   wpb     = (int*)alloc((size_t)NC * N * 4);
    float* dinv    = (float*)alloc((size_t)N * 4);
    int*   rowptr  = (int*)alloc((size_t)(N + 1) * 4);
    int*   blkoff  = (int*)alloc((size_t)1056 * 4);
    int*   blkdum  = (int*)alloc((size_t)4 * 4);
    int2*  csr     = (int2*)alloc((size_t)E * 8);
    unsigned char*  P8   = (unsigned char*)alloc((size_t)N * 128);
    unsigned char*  H8   = (unsigned char*)alloc((size_t)N * 128);
    unsigned short* R1   = (unsigned short*)alloc((size_t)N * 128 * 2);
    unsigned short* hbf  = (unsigned short*)alloc((size_t)N * 128 * 2);
    unsigned short* ahb  = (unsigned short*)alloc((size_t)N * 128 * 2);
    unsigned short* nxb  = (unsigned short*)alloc((size_t)N * 128 * 2);
    unsigned short* W1t  = (unsigned short*)alloc((size_t)256 * 768 * 2);
    unsigned short* W2t  = (unsigned short*)alloc((size_t)128 * 256 * 2);

    const int eBlocks = (E + 255) / 256;
    const int nb      = (N + 1023) / 1024;
    const int nBlocks = (N + 255) / 256;
    const int aBlocks = (N + 15) / 16;

    // ---- CSR build + weight convert ----
    (void)hipMemsetAsync(packed, 0, (size_t)NC * N * 8, stream);
    deg_hist_kernel<<<eBlocks, 256, 0, stream>>>(ei, ea, packed, rank, N, E);
    scan1p_kernel<<<nb, 256, 0, stream>>>(packed, rowptr, blkoff, N);
    scan1_kernel<<<1, 256, 0, stream>>>(blkoff, blkoff, blkdum, nb);
    scan3_kernel<<<nBlocks, 256, 0, stream>>>(rowptr, blkoff, wpb, packed, dinv, N, E);
    place_kernel<<<eBlocks, 256, 0, stream>>>(ei, ea, dinv, wpb, rank, csr, N, E);
    conv_weights<<<(256 * 768 + 128 * 256 + 255) / 256, 256, 0, stream>>>(
        W1i, W1r, W2i, W2r, W1t, W2t);

    // ---- layer 1: P8 = fp8(x@W1i), R1 = bf16(x@W1r + b1) ----
    gemm_mfma_dual<<<(N + 63) / 64, 512, 0, stream>>>(x, W1t, b1, P8, R1, N, 768);
    // h = relu(R1 + gather(P8)) -> hbf (bf16) + H8 (fp8)
    agg_bias_relu<<<aBlocks, 256, 0, stream>>>(P8, R1, rowptr, csr, hbf, H8, N);

    // ---- layer 2: ah = bf16(gather(H8)); node_x = bf16(relu([ah|h]@W2 + b2)) ----
    agg_plain<<<aBlocks, 256, 0, stream>>>(H8, rowptr, csr, ahb, N);
    gemm_mfma_single<<<(N + 127) / 128, 512, 0, stream>>>(ahb, hbf, W2t, b2, nxb, N);

    // ---- fused pool + head ----
    pool_mlp<<<G, 256, 0, stream>>>(nxb, batch, N, Wl1, bl1, Wl2, bl2, (float*)d_out);
}

// Round 13
// 369.865 us; speedup vs baseline: 17.2211x; 1.0292x over previous
//
#include <hip/hip_runtime.h>
#include <hip/hip_bf16.h>
#include <math.h>

typedef __attribute__((ext_vector_type(8))) short short8;
typedef __attribute__((ext_vector_type(4))) float f32x4;
typedef __attribute__((ext_vector_type(2))) float f32x2;
typedef __attribute__((address_space(1))) const void gvoid;
typedef __attribute__((address_space(3))) void lvoid;

#define NC 8   // histogram privatization copies

__device__ __forceinline__ unsigned short f2bf(float f) {
    unsigned int u = __builtin_bit_cast(unsigned int, f);
    return (unsigned short)((u + 0x7fffu + ((u >> 16) & 1u)) >> 16);   // RNE
}
__device__ __forceinline__ float b2f(short s) {
    return __builtin_bit_cast(float, ((unsigned int)(unsigned short)s) << 16);
}
__device__ __forceinline__ unsigned int cvtpk(float lo, float hi) {
    unsigned int r;
    asm("v_cvt_pk_bf16_f32 %0, %1, %2" : "=v"(r) : "v"(lo), "v"(hi));
    return r;
}
// fp8 e4m3 (OCP) HW converts — word-select must be a LITERAL constant
__device__ __forceinline__ unsigned int pk8_lo(float a, float b, unsigned int old) {
    return (unsigned int)__builtin_amdgcn_cvt_pk_fp8_f32(a, b, (int)old, false);
}
__device__ __forceinline__ unsigned int pk8_hi(float a, float b, unsigned int old) {
    return (unsigned int)__builtin_amdgcn_cvt_pk_fp8_f32(a, b, (int)old, true);
}
__device__ __forceinline__ f32x2 up8_lo(unsigned int v) {
    return __builtin_amdgcn_cvt_pk_f32_fp8((int)v, false);
}
__device__ __forceinline__ f32x2 up8_hi(unsigned int v) {
    return __builtin_amdgcn_cvt_pk_f32_fp8((int)v, true);
}

// ============ FUSED: hist (privatized u64, rank) + weight pre-convert ============
__global__ __launch_bounds__(256) void hist_conv_kernel(
    const int* __restrict__ ei, const float* __restrict__ ea,
    unsigned long long* __restrict__ packed, int* __restrict__ rank, int N, int E,
    int eBlocks,
    const float* __restrict__ W1i, const float* __restrict__ W1r,
    const float* __restrict__ W2i, const float* __restrict__ W2r,
    unsigned short* __restrict__ W1t, unsigned short* __restrict__ W2t)
{
    if ((int)blockIdx.x < eBlocks) {
        int e = blockIdx.x * 256 + threadIdx.x;
        if (e >= E) return;
        const int copy = blockIdx.x & (NC - 1);
        int c = ei[(size_t)E + e];
        unsigned long long fx = (unsigned long long)(ea[e] * 1048576.0f + 0.5f);
        unsigned long long old = atomicAdd(&packed[(size_t)copy * N + c], (1ULL << 42) | fx);
        rank[e] = (int)(old >> 42);
    } else {
        int id = (blockIdx.x - eBlocks) * 256 + threadIdx.x;
        if (id < 256 * 768) {
            int n = id / 768, j = id % 768;
            int k = (j & ~63) | ((((j >> 3) & 7) ^ (n & 7)) << 3) | (j & 7);
            float v = (n < 128) ? W1i[k * 128 + n] : W1r[k * 128 + (n - 128)];
            W1t[id] = f2bf(v);
        } else {
            int id2 = id - 256 * 768;
            if (id2 < 128 * 256) {
                int n = id2 >> 8, j = id2 & 255;
                int k = (j & ~63) | ((((j >> 3) & 7) ^ (n & 7)) << 3) | (j & 7);
                float v = (k < 128) ? W2i[k * 128 + n] : W2r[(k - 128) * 128 + n];
                W2t[id2] = f2bf(v);
            }
        }
    }
}

// ============ scan pass 1: per-node total count over NC copies ============
__global__ __launch_bounds__(256) void scan1p_kernel(
    const unsigned long long* __restrict__ packed, int* __restrict__ out,
    int* __restrict__ blksum, int n)
{
    __shared__ int part[256];
    const int t = threadIdx.x;
    const int base = blockIdx.x * 1024 + t * 4;
    int v[4];
#pragma unroll
    for (int q = 0; q < 4; ++q) {
        int s = 0;
        if (base + q < n) {
#pragma unroll
            for (int p = 0; p < NC; ++p)
                s += (int)(packed[(size_t)p * n + base + q] >> 42);
        }
        v[q] = s;
    }
    const int s = v[0] + v[1] + v[2] + v[3];
    part[t] = s;
    __syncthreads();
    for (int off = 1; off < 256; off <<= 1) {
        int x = (t >= off) ? part[t - off] : 0;
        __syncthreads();
        part[t] += x;
        __syncthreads();
    }
    if (t == 255) blksum[blockIdx.x] = part[255];
    int run = part[t] - s;
#pragma unroll
    for (int q = 0; q < 4; ++q) {
        if (base + q < n) out[base + q] = run;
        run += v[q];
    }
}

// ============ finalize (re-scans <=256 block sums in shared): rowptr, wpb, dinv ============
__global__ __launch_bounds__(256) void scan3_kernel(
    int* __restrict__ rowptr, const int* __restrict__ blksum,
    int* __restrict__ wpb, const unsigned long long* __restrict__ packed,
    float* __restrict__ dinv, int n, int Etot, int nb)
{
    __shared__ int tmp[256];
    __shared__ int sexcl[256];
    const int t = threadIdx.x;
    const int v = (t < nb) ? blksum[t] : 0;
    tmp[t] = v;
    __syncthreads();
    for (int off = 1; off < 256; off <<= 1) {
        int x = (t >= off) ? tmp[t - off] : 0;
        __syncthreads();
        tmp[t] += x;
        __syncthreads();
    }
    sexcl[t] = tmp[t] - v;
    __syncthreads();
    const int i = blockIdx.x * 256 + t;
    if (i == 0) rowptr[n] = Etot;
    if (i >= n) return;
    int base = rowptr[i] + sexcl[i >> 10];
    rowptr[i] = base;
    unsigned long long degfx = 0;
    int acc = base;
#pragma unroll
    for (int p = 0; p < NC; ++p) {
        unsigned long long vv = packed[(size_t)p * n + i];
        wpb[(size_t)p * n + i] = acc;
        acc += (int)(vv >> 42);
        degfx += vv & ((1ULL << 42) - 1);
    }
    dinv[i] = (degfx > 0) ? rsqrtf((float)degfx * 9.5367431640625e-7f) : 0.f;
}

// ============ edge placement: NO atomics (base + rank) ============
__global__ __launch_bounds__(256) void place_kernel(
    const int* __restrict__ ei, const float* __restrict__ ea,
    const float* __restrict__ dinv, const int* __restrict__ wpb,
    const int* __restrict__ rank, int2* __restrict__ csr, int N, int E)
{
    int e = blockIdx.x * 256 + threadIdx.x;
    if (e >= E) return;
    const int copy = blockIdx.x & (NC - 1);
    int r = ei[e];
    int c = ei[(size_t)E + e];
    float nm = dinv[r] * ea[e] * dinv[c];
    int pos = wpb[(size_t)copy * N + c] + rank[e];
    int2 rec;
    rec.x = r;
    rec.y = __builtin_bit_cast(int, nm);
    csr[pos] = rec;
}

// ============ MFMA dual GEMM (layer 1), single-buffered ============
// outP: fp8 e4m3 (gather operand only); outR: bf16.
__global__ __launch_bounds__(512) void gemm_mfma_dual(
    const float* __restrict__ A, const unsigned short* __restrict__ Wt,
    const float* __restrict__ bias, unsigned char* __restrict__ outP8,
    unsigned short* __restrict__ outR, int M, int K)
{
    __shared__ __align__(16) unsigned char As[64 * 128];
    __shared__ __align__(16) unsigned char Bs[256 * 128];

    const int t = threadIdx.x;
    const int m0 = blockIdx.x * 64;
    const int lane = t & 63;
    const int wid = t >> 6;
    const int wm = wid >> 2;
    const int wn = wid & 3;
    const int lr = lane & 15;
    const int lk = (lane >> 4) * 8;

    f32x4 acc[2][4] = {};

    const int sr = t >> 3;
    const int sk = (t & 7) * 8;
    const int aRow = m0 + sr;
    const bool aOk = (aRow < M);
    const float* aSrc = A + (size_t)(aOk ? aRow : 0) * K + sk;
    const int aDst = sr * 128 + ((sk * 2) ^ ((sr & 7) << 4));
    const unsigned short* bSrc = Wt + (size_t)(lane >> 3) * K + (lane & 7) * 8;

    for (int k0 = 0; k0 < K; k0 += 64) {
#pragma unroll
        for (int i = 0; i < 4; ++i) {
            const int chunk = i * 8 + wid;
            __builtin_amdgcn_global_load_lds(
                (gvoid*)(bSrc + (size_t)chunk * 8 * K + k0),
                (lvoid*)(Bs + chunk * 1024), 16, 0, 0);
        }
        unsigned int p0 = 0, p1 = 0, p2 = 0, p3 = 0;
        if (aOk) {
            const float4 f0 = *(const float4*)(aSrc + k0);
            const float4 f1 = *(const float4*)(aSrc + k0 + 4);
            p0 = cvtpk(f0.x, f0.y);
            p1 = cvtpk(f0.z, f0.w);
            p2 = cvtpk(f1.x, f1.y);
            p3 = cvtpk(f1.z, f1.w);
        }
        uint4 uv = {p0, p1, p2, p3};
        *(uint4*)(As + aDst) = uv;
        __syncthreads();
#pragma unroll
        for (int ks = 0; ks < 2; ++ks) {
            short8 a[2], b[4];
#pragma unroll
            for (int mf = 0; mf < 2; ++mf) {
                const int r = wm * 32 + mf * 16 + lr;
                a[mf] = *(const short8*)(As + r * 128 + (((ks * 32 + lk) * 2) ^ ((r & 7) << 4)));
            }
#pragma unroll
            for (int nf = 0; nf < 4; ++nf) {
                const int n = wn * 64 + nf * 16 + lr;
                b[nf] = *(const short8*)(Bs + n * 128 + (((ks * 32 + lk) * 2) ^ ((n & 7) << 4)));
            }
#pragma unroll
            for (int mf = 0; mf < 2; ++mf)
#pragma unroll
                for (int nf = 0; nf < 4; ++nf)
                    acc[mf][nf] = __builtin_amdgcn_mfma_f32_16x16x32_bf16(
                        a[mf], b[nf], acc[mf][nf], 0, 0, 0);
        }
        __syncthreads();
    }

#pragma unroll
    for (int mf = 0; mf < 2; ++mf) {
#pragma unroll
        for (int nf = 0; nf < 4; ++nf) {
            const int n = wn * 64 + nf * 16 + lr;
            const f32x4 v = acc[mf][nf];
            const int mb = m0 + wm * 32 + mf * 16 + (lane >> 4) * 4;
            if (n < 128) {
                const unsigned int u01 = pk8_lo(v[0], v[1], 0u);
                const unsigned int u23 = pk8_lo(v[2], v[3], 0u);
                if (mb + 0 < M) outP8[(size_t)(mb + 0) * 128 + n] = (unsigned char)(u01);
                if (mb + 1 < M) outP8[(size_t)(mb + 1) * 128 + n] = (unsigned char)(u01 >> 8);
                if (mb + 2 < M) outP8[(size_t)(mb + 2) * 128 + n] = (unsigned char)(u23);
                if (mb + 3 < M) outP8[(size_t)(mb + 3) * 128 + n] = (unsigned char)(u23 >> 8);
            } else {
                const int nl = n - 128;
                const float badd = bias[nl];
#pragma unroll
                for (int j = 0; j < 4; ++j) {
                    if (mb + j < M) outR[(size_t)(mb + j) * 128 + nl] = f2bf(v[j] + badd);
                }
            }
        }
    }
}

// ============ MFMA single GEMM (layer 2, K=256 over bf16 [ah|h]) + bias + ReLU ============
__global__ __launch_bounds__(512) void gemm_mfma_single(
    const unsigned short* __restrict__ Aa,   // ah bf16 : k in [0,128)
    const unsigned short* __restrict__ Ah,   // h  bf16 : k in [128,256)
    const unsigned short* __restrict__ Wt,   // 128 x 256 bf16 pre-swizzled
    const float* __restrict__ bias,
    unsigned short* __restrict__ outX, int M)
{
    __shared__ __align__(16) unsigned char As[128 * 128];
    __shared__ __align__(16) unsigned char Bs[128 * 128];

    const int t = threadIdx.x;
    const int m0 = blockIdx.x * 128;
    const int lane = t & 63;
    const int wid = t >> 6;
    const int wm = wid >> 1;
    const int wn = wid & 1;
    const int lr = lane & 15;
    const int lk = (lane >> 4) * 8;

    f32x4 acc[2][4] = {};

    const int sr = t >> 2;
    const int sk = (t & 3) * 16;
    const int aRow = m0 + sr;
    const bool aOk = (aRow < M);
    const int rowSafe = aOk ? aRow : 0;
    const int sw = (sr & 7) << 4;
    const unsigned short* bSrc = Wt + (size_t)(lane >> 3) * 256 + (lane & 7) * 8;

    for (int k0 = 0; k0 < 256; k0 += 64) {
#pragma unroll
        for (int i = 0; i < 2; ++i) {
            const int chunk = i * 8 + wid;
            __builtin_amdgcn_global_load_lds(
                (gvoid*)(bSrc + (size_t)chunk * 8 * 256 + k0),
                (lvoid*)(Bs + chunk * 1024), 16, 0, 0);
        }
        const unsigned short* src =
            (k0 < 128 ? Aa : Ah) + (size_t)rowSafe * 128 + (k0 & 127) + sk;
        const short8 v0 = *(const short8*)(src);
        const short8 v1 = *(const short8*)(src + 8);
        *(short8*)(As + sr * 128 + ((sk * 2) ^ sw)) = v0;
        *(short8*)(As + sr * 128 + ((sk * 2 + 16) ^ sw)) = v1;
        __syncthreads();
#pragma unroll
        for (int ks = 0; ks < 2; ++ks) {
            short8 a[2], b[4];
#pragma unroll
            for (int mf = 0; mf < 2; ++mf) {
                const int r = wm * 32 + mf * 16 + lr;
                a[mf] = *(const short8*)(As + r * 128 + (((ks * 32 + lk) * 2) ^ ((r & 7) << 4)));
            }
#pragma unroll
            for (int nf = 0; nf < 4; ++nf) {
                const int n = wn * 64 + nf * 16 + lr;
                b[nf] = *(const short8*)(Bs + n * 128 + (((ks * 32 + lk) * 2) ^ ((n & 7) << 4)));
            }
#pragma unroll
            for (int mf = 0; mf < 2; ++mf)
#pragma unroll
                for (int nf = 0; nf < 4; ++nf)
                    acc[mf][nf] = __builtin_amdgcn_mfma_f32_16x16x32_bf16(
                        a[mf], b[nf], acc[mf][nf], 0, 0, 0);
        }
        __syncthreads();
    }

#pragma unroll
    for (int mf = 0; mf < 2; ++mf) {
#pragma unroll
        for (int nf = 0; nf < 4; ++nf) {
            const int n = wn * 64 + nf * 16 + lr;
            const float bb = bias[n];
            const f32x4 v = acc[mf][nf];
#pragma unroll
            for (int j = 0; j < 4; ++j) {
                const int m = m0 + wm * 32 + mf * 16 + (lane >> 4) * 4 + j;
                if (m < M) outX[(size_t)m * 128 + n] = f2bf(fmaxf(v[j] + bb, 0.f));
            }
        }
    }
}

// ============ agg1: gather fp8 P -> h (bf16 for GEMM2 + fp8 for agg2) ============
__global__ __launch_bounds__(256) void agg_bias_relu(
    const unsigned char* __restrict__ P8, const unsigned short* __restrict__ Rbf,
    const int* __restrict__ rowptr, const int2* __restrict__ csr,
    unsigned short* __restrict__ hout, unsigned char* __restrict__ h8out, int N)
{
    const int i = blockIdx.x * 16 + (threadIdx.x >> 4);
    const int l = threadIdx.x & 15;
    if (i >= N) return;
    const int beg = rowptr[i];
    const int end = rowptr[i + 1];
    const int c = l * 8;

    float acc0[8] = {}, acc1[8] = {}, acc2[8] = {}, acc3[8] = {};
    int j = beg;
    for (; j + 3 < end; j += 4) {
        const int2 e0 = csr[j],     e1 = csr[j + 1];
        const int2 e2 = csr[j + 2], e3 = csr[j + 3];
        const uint2 u0 = *(const uint2*)(P8 + (size_t)e0.x * 128 + c);
        const uint2 u1 = *(const uint2*)(P8 + (size_t)e1.x * 128 + c);
        const uint2 u2 = *(const uint2*)(P8 + (size_t)e2.x * 128 + c);
        const uint2 u3 = *(const uint2*)(P8 + (size_t)e3.x * 128 + c);
        const float n0 = __builtin_bit_cast(float, e0.y);
        const float n1 = __builtin_bit_cast(float, e1.y);
        const float n2 = __builtin_bit_cast(float, e2.y);
        const float n3 = __builtin_bit_cast(float, e3.y);
        {
            const f32x2 p0 = up8_lo(u0.x), p1 = up8_hi(u0.x);
            const f32x2 p2 = up8_lo(u0.y), p3 = up8_hi(u0.y);
            acc0[0] = fmaf(p0.x, n0, acc0[0]); acc0[1] = fmaf(p0.y, n0, acc0[1]);
            acc0[2] = fmaf(p1.x, n0, acc0[2]); acc0[3] = fmaf(p1.y, n0, acc0[3]);
            acc0[4] = fmaf(p2.x, n0, acc0[4]); acc0[5] = fmaf(p2.y, n0, acc0[5]);
            acc0[6] = fmaf(p3.x, n0, acc0[6]); acc0[7] = fmaf(p3.y, n0, acc0[7]);
        }
        {
            const f32x2 p0 = up8_lo(u1.x), p1 = up8_hi(u1.x);
            const f32x2 p2 = up8_lo(u1.y), p3 = up8_hi(u1.y);
            acc1[0] = fmaf(p0.x, n1, acc1[0]); acc1[1] = fmaf(p0.y, n1, acc1[1]);
            acc1[2] = fmaf(p1.x, n1, acc1[2]); acc1[3] = fmaf(p1.y, n1, acc1[3]);
            acc1[4] = fmaf(p2.x, n1, acc1[4]); acc1[5] = fmaf(p2.y, n1, acc1[5]);
            acc1[6] = fmaf(p3.x, n1, acc1[6]); acc1[7] = fmaf(p3.y, n1, acc1[7]);
        }
        {
            const f32x2 p0 = up8_lo(u2.x), p1 = up8_hi(u2.x);
            const f32x2 p2 = up8_lo(u2.y), p3 = up8_hi(u2.y);
            acc2[0] = fmaf(p0.x, n2, acc2[0]); acc2[1] = fmaf(p0.y, n2, acc2[1]);
            acc2[2] = fmaf(p1.x, n2, acc2[2]); acc2[3] = fmaf(p1.y, n2, acc2[3]);
            acc2[4] = fmaf(p2.x, n2, acc2[4]); acc2[5] = fmaf(p2.y, n2, acc2[5]);
            acc2[6] = fmaf(p3.x, n2, acc2[6]); acc2[7] = fmaf(p3.y, n2, acc2[7]);
        }
        {
            const f32x2 p0 = up8_lo(u3.x), p1 = up8_hi(u3.x);
            const f32x2 p2 = up8_lo(u3.y), p3 = up8_hi(u3.y);
            acc3[0] = fmaf(p0.x, n3, acc3[0]); acc3[1] = fmaf(p0.y, n3, acc3[1]);
            acc3[2] = fmaf(p1.x, n3, acc3[2]); acc3[3] = fmaf(p1.y, n3, acc3[3]);
            acc3[4] = fmaf(p2.x, n3, acc3[4]); acc3[5] = fmaf(p2.y, n3, acc3[5]);
            acc3[6] = fmaf(p3.x, n3, acc3[6]); acc3[7] = fmaf(p3.y, n3, acc3[7]);
        }
    }
    for (; j < end; ++j) {
        const int2 e0 = csr[j];
        const uint2 u0 = *(const uint2*)(P8 + (size_t)e0.x * 128 + c);
        const float n0 = __builtin_bit_cast(float, e0.y);
        const f32x2 p0 = up8_lo(u0.x), p1 = up8_hi(u0.x);
        const f32x2 p2 = up8_lo(u0.y), p3 = up8_hi(u0.y);
        acc0[0] = fmaf(p0.x, n0, acc0[0]); acc0[1] = fmaf(p0.y, n0, acc0[1]);
        acc0[2] = fmaf(p1.x, n0, acc0[2]); acc0[3] = fmaf(p1.y, n0, acc0[3]);
        acc0[4] = fmaf(p2.x, n0, acc0[4]); acc0[5] = fmaf(p2.y, n0, acc0[5]);
        acc0[6] = fmaf(p3.x, n0, acc0[6]); acc0[7] = fmaf(p3.y, n0, acc0[7]);
    }
    const short8 rv = *(const short8*)(Rbf + (size_t)i * 128 + c);
    float s[8];
    short8 ov;
#pragma unroll
    for (int q = 0; q < 8; ++q) {
        s[q] = fmaxf((acc0[q] + acc1[q]) + (acc2[q] + acc3[q]) + b2f(rv[q]), 0.f);
        ov[q] = (short)f2bf(s[q]);
    }
    *(short8*)(hout + (size_t)i * 128 + c) = ov;
    unsigned int w0 = 0, w1 = 0;
    w0 = pk8_lo(s[0], s[1], w0); w0 = pk8_hi(s[2], s[3], w0);
    w1 = pk8_lo(s[4], s[5], w1); w1 = pk8_hi(s[6], s[7], w1);
    uint2 wv = {w0, w1};
    *(uint2*)(h8out + (size_t)i * 128 + c) = wv;
}

// ============ agg2: ah = bf16(gather(fp8 h)) ============
__global__ __launch_bounds__(256) void agg_plain(
    const unsigned char* __restrict__ H8,
    const int* __restrict__ rowptr, const int2* __restrict__ csr,
    unsigned short* __restrict__ ahout, int N)
{
    const int i = blockIdx.x * 16 + (threadIdx.x >> 4);
    const int l = threadIdx.x & 15;
    if (i >= N) return;
    const int beg = rowptr[i];
    const int end = rowptr[i + 1];
    const int c = l * 8;

    float acc0[8] = {}, acc1[8] = {}, acc2[8] = {}, acc3[8] = {};
    int j = beg;
    for (; j + 3 < end; j += 4) {
        const int2 e0 = csr[j],     e1 = csr[j + 1];
        const int2 e2 = csr[j + 2], e3 = csr[j + 3];
        const uint2 u0 = *(const uint2*)(H8 + (size_t)e0.x * 128 + c);
        const uint2 u1 = *(const uint2*)(H8 + (size_t)e1.x * 128 + c);
        const uint2 u2 = *(const uint2*)(H8 + (size_t)e2.x * 128 + c);
        const uint2 u3 = *(const uint2*)(H8 + (size_t)e3.x * 128 + c);
        const float n0 = __builtin_bit_cast(float, e0.y);
        const float n1 = __builtin_bit_cast(float, e1.y);
        const float n2 = __builtin_bit_cast(float, e2.y);
        const float n3 = __builtin_bit_cast(float, e3.y);
        {
            const f32x2 p0 = up8_lo(u0.x), p1 = up8_hi(u0.x);
            const f32x2 p2 = up8_lo(u0.y), p3 = up8_hi(u0.y);
            acc0[0] = fmaf(p0.x, n0, acc0[0]); acc0[1] = fmaf(p0.y, n0, acc0[1]);
            acc0[2] = fmaf(p1.x, n0, acc0[2]); acc0[3] = fmaf(p1.y, n0, acc0[3]);
            acc0[4] = fmaf(p2.x, n0, acc0[4]); acc0[5] = fmaf(p2.y, n0, acc0[5]);
            acc0[6] = fmaf(p3.x, n0, acc0[6]); acc0[7] = fmaf(p3.y, n0, acc0[7]);
        }
        {
            const f32x2 p0 = up8_lo(u1.x), p1 = up8_hi(u1.x);
            const f32x2 p2 = up8_lo(u1.y), p3 = up8_hi(u1.y);
            acc1[0] = fmaf(p0.x, n1, acc1[0]); acc1[1] = fmaf(p0.y, n1, acc1[1]);
            acc1[2] = fmaf(p1.x, n1, acc1[2]); acc1[3] = fmaf(p1.y, n1, acc1[3]);
            acc1[4] = fmaf(p2.x, n1, acc1[4]); acc1[5] = fmaf(p2.y, n1, acc1[5]);
            acc1[6] = fmaf(p3.x, n1, acc1[6]); acc1[7] = fmaf(p3.y, n1, acc1[7]);
        }
        {
            const f32x2 p0 = up8_lo(u2.x), p1 = up8_hi(u2.x);
            const f32x2 p2 = up8_lo(u2.y), p3 = up8_hi(u2.y);
            acc2[0] = fmaf(p0.x, n2, acc2[0]); acc2[1] = fmaf(p0.y, n2, acc2[1]);
            acc2[2] = fmaf(p1.x, n2, acc2[2]); acc2[3] = fmaf(p1.y, n2, acc2[3]);
            acc2[4] = fmaf(p2.x, n2, acc2[4]); acc2[5] = fmaf(p2.y, n2, acc2[5]);
            acc2[6] = fmaf(p3.x, n2, acc2[6]); acc2[7] = fmaf(p3.y, n2, acc2[7]);
        }
        {
            const f32x2 p0 = up8_lo(u3.x), p1 = up8_hi(u3.x);
            const f32x2 p2 = up8_lo(u3.y), p3 = up8_hi(u3.y);
            acc3[0] = fmaf(p0.x, n3, acc3[0]); acc3[1] = fmaf(p0.y, n3, acc3[1]);
            acc3[2] = fmaf(p1.x, n3, acc3[2]); acc3[3] = fmaf(p1.y, n3, acc3[3]);
            acc3[4] = fmaf(p2.x, n3, acc3[4]); acc3[5] = fmaf(p2.y, n3, acc3[5]);
            acc3[6] = fmaf(p3.x, n3, acc3[6]); acc3[7] = fmaf(p3.y, n3, acc3[7]);
        }
    }
    for (; j < end; ++j) {
        const int2 e0 = csr[j];
        const uint2 u0 = *(const uint2*)(H8 + (size_t)e0.x * 128 + c);
        const float n0 = __builtin_bit_cast(float, e0.y);
        const f32x2 p0 = up8_lo(u0.x), p1 = up8_hi(u0.x);
        const f32x2 p2 = up8_lo(u0.y), p3 = up8_hi(u0.y);
        acc0[0] = fmaf(p0.x, n0, acc0[0]); acc0[1] = fmaf(p0.y, n0, acc0[1]);
        acc0[2] = fmaf(p1.x, n0, acc0[2]); acc0[3] = fmaf(p1.y, n0, acc0[3]);
        acc0[4] = fmaf(p2.x, n0, acc0[4]); acc0[5] = fmaf(p2.y, n0, acc0[5]);
        acc0[6] = fmaf(p3.x, n0, acc0[6]); acc0[7] = fmaf(p3.y, n0, acc0[7]);
    }
    short8 ov;
#pragma unroll
    for (int q = 0; q < 8; ++q)
        ov[q] = (short)f2bf((acc0[q] + acc1[q]) + (acc2[q] + acc3[q]));
    *(short8*)(ahout + (size_t)i * 128 + c) = ov;
}

// ============ fused mean-pool (sorted batch, bf16, 4 node-streams) + MLP ============
__global__ __launch_bounds__(256) void pool_mlp(
    const unsigned short* __restrict__ nx, const int* __restrict__ batch, int N,
    const float* __restrict__ Wl1, const float* __restrict__ bl1,
    const float* __restrict__ Wl2, const float* __restrict__ bl2,
    float* __restrict__ out)
{
    __shared__ float gxp[4][128];
    __shared__ float hid[32];
    __shared__ int rng[2];
    const int g = blockIdx.x;
    const int t = threadIdx.x;
    if (t < 2) {
        const int target = g + t;
        int lo = 0, hi = N;
        while (lo < hi) {
            int mid = (lo + hi) >> 1;
            if (batch[mid] < target) lo = mid + 1; else hi = mid;
        }
        rng[t] = lo;
    }
    __syncthreads();
    const int s = rng[0], e = rng[1];
    const int pr = t & 63;
    const int strm = t >> 6;
    float a0 = 0.f, b0 = 0.f, a1 = 0.f, b1 = 0.f;
    int i = s + strm;
    for (; i + 4 < e; i += 8) {
        const unsigned int u = *(const unsigned int*)&nx[(size_t)i * 128 + pr * 2];
        const unsigned int v = *(const unsigned int*)&nx[(size_t)(i + 4) * 128 + pr * 2];
        a0 += b2f((short)(u & 0xffff)); b0 += b2f((short)(u >> 16));
        a1 += b2f((short)(v & 0xffff)); b1 += b2f((short)(v >> 16));
    }
    if (i < e) {
        const unsigned int u = *(const unsigned int*)&nx[(size_t)i * 128 + pr * 2];
        a0 += b2f((short)(u & 0xffff)); b0 += b2f((short)(u >> 16));
    }
    gxp[strm][pr * 2] = a0 + a1;
    gxp[strm][pr * 2 + 1] = b0 + b1;
    __syncthreads();
    if (t < 128) {
        gxp[0][t] = ((gxp[0][t] + gxp[1][t]) + (gxp[2][t] + gxp[3][t]))
                    / fmaxf((float)(e - s), 1.f);
    }
    __syncthreads();
    if (t < 32) {
        float a = bl1[t];
#pragma unroll 8
        for (int k = 0; k < 128; ++k) a = fmaf(gxp[0][k], Wl1[k * 32 + t], a);
        hid[t] = a > 0.f ? a : expm1f(a);
    }
    __syncthreads();
    if (t < 2) {
        float a = bl2[t];
#pragma unroll
        for (int k = 0; k < 32; ++k) a = fmaf(hid[k], Wl2[k * 2 + t], a);
        out[(size_t)g * 2 + t] = a;
    }
}

extern "C" void kernel_launch(void* const* d_in, const int* in_sizes, int n_in,
                              void* d_out, int out_size, void* d_ws, size_t ws_size,
                              hipStream_t stream)
{
    const float* x     = (const float*)d_in[0];
    const int*   ei    = (const int*)d_in[1];
    const float* ea    = (const float*)d_in[2];
    const int*   batch = (const int*)d_in[3];
    const float* W1i   = (const float*)d_in[5];
    const float* W1r   = (const float*)d_in[6];
    const float* b1    = (const float*)d_in[7];
    const float* W2i   = (const float*)d_in[8];
    const float* W2r   = (const float*)d_in[9];
    const float* b2    = (const float*)d_in[10];
    const float* Wl1   = (const float*)d_in[11];
    const float* bl1   = (const float*)d_in[12];
    const float* Wl2   = (const float*)d_in[13];
    const float* bl2   = (const float*)d_in[14];

    const int N = in_sizes[0] / 768;
    const int E = in_sizes[2];
    const int G = out_size / 2;

    char* ws = (char*)d_ws;
    size_t off = 0;
    auto alloc = [&](size_t bytes) -> char* {
        char* p = ws + off;
        off = (off + bytes + 255) & ~(size_t)255;
        return p;
    };
    unsigned long long* packed = (unsigned long long*)alloc((size_t)NC * N * 8);
    int*   rank    = (int*)alloc((size_t)E * 4);
    int*   wpb     = (int*)alloc((size_t)NC * N * 4);
    float* dinv    = (float*)alloc((size_t)N * 4);
    int*   rowptr  = (int*)alloc((size_t)(N + 1) * 4);
    int*   blksum  = (int*)alloc((size_t)256 * 4);
    int2*  csr     = (int2*)alloc((size_t)E * 8);
    unsigned char*  P8   = (unsigned char*)alloc((size_t)N * 128);
    unsigned char*  H8   = (unsigned char*)alloc((size_t)N * 128);
    unsigned short* R1   = (unsigned short*)alloc((size_t)N * 128 * 2);
    unsigned short* hbf  = (unsigned short*)alloc((size_t)N * 128 * 2);
    unsigned short* ahb  = (unsigned short*)alloc((size_t)N * 128 * 2);
    unsigned short* nxb  = (unsigned short*)alloc((size_t)N * 128 * 2);
    unsigned short* W1t  = (unsigned short*)alloc((size_t)256 * 768 * 2);
    unsigned short* W2t  = (unsigned short*)alloc((size_t)128 * 256 * 2);

    const int eBlocks = (E + 255) / 256;
    const int cBlocks = (256 * 768 + 128 * 256 + 255) / 256;
    const int nb      = (N + 1023) / 1024;     // <=256 assumed
    const int nBlocks = (N + 255) / 256;
    const int aBlocks = (N + 15) / 16;

    // ---- CSR build + weight convert (fused) ----
    (void)hipMemsetAsync(packed, 0, (size_t)NC * N * 8, stream);
    hist_conv_kernel<<<eBlocks + cBlocks, 256, 0, stream>>>(
        ei, ea, packed, rank, N, E, eBlocks, W1i, W1r, W2i, W2r, W1t, W2t);
    scan1p_kernel<<<nb, 256, 0, stream>>>(packed, rowptr, blksum, N);
    scan3_kernel<<<nBlocks, 256, 0, stream>>>(rowptr, blksum, wpb, packed, dinv, N, E, nb);
    place_kernel<<<eBlocks, 256, 0, stream>>>(ei, ea, dinv, wpb, rank, csr, N, E);

    // ---- layer 1: P8 = fp8(x@W1i), R1 = bf16(x@W1r + b1) ----
    gemm_mfma_dual<<<(N + 63) / 64, 512, 0, stream>>>(x, W1t, b1, P8, R1, N, 768);
    // h = relu(R1 + gather(P8)) -> hbf (bf16) + H8 (fp8)
    agg_bias_relu<<<aBlocks, 256, 0, stream>>>(P8, R1, rowptr, csr, hbf, H8, N);

    // ---- layer 2: ah = bf16(gather(H8)); node_x = bf16(relu([ah|h]@W2 + b2)) ----
    agg_plain<<<aBlocks, 256, 0, stream>>>(H8, rowptr, csr, ahb, N);
    gemm_mfma_single<<<(N + 127) / 128, 512, 0, stream>>>(ahb, hbf, W2t, b2, nxb, N);

    // ---- fused pool + head ----
    pool_mlp<<<G, 256, 0, stream>>>(nxb, batch, N, Wl1, bl1, Wl2, bl2, (float*)d_out);
}